// Round 7
// baseline (459.367 us; speedup 1.0000x reference)
//
#include <hip/hip_runtime.h>
#include <hip/hip_bf16.h>

constexpr int V   = 100000;
constexpr int E   = 1600000;
constexpr int NET = 10;
constexpr int KXW = 138;              // W_xi row length (2*64+10)
constexpr int NB  = (V + 255) / 256;  // 391 blocks over nodes
constexpr int GN  = 8;                // count groups (= XCDs)
constexpr float MUS   = 0.1125f;      // MU / S
constexpr float SP    = 0.025f;       // int8 P scale
constexpr float LOG2E = 1.44269504f;
constexpr float S2L   = 2.0f * SP * LOG2E;   // int8 P step in exp2 domain
constexpr float AS    = MUS / 127.0f;        // int8 A decode scale

typedef __attribute__((ext_vector_type(8))) short short8;
typedef __attribute__((ext_vector_type(4))) float float4v;

__device__ __forceinline__ float fast_tanh(float x) {
    return 1.0f - 2.0f * __builtin_amdgcn_rcpf(__expf(2.0f * x) + 1.0f);
}
__device__ __forceinline__ float bflo(unsigned u) { return __uint_as_float(u << 16); }
__device__ __forceinline__ float bfhi(unsigned u) { return __uint_as_float(u & 0xffff0000u); }
__device__ __forceinline__ short f2bf(float x) {
    union { __hip_bfloat16 b; short s; } u; u.b = __float2bfloat16(x); return u.s;
}

__device__ __forceinline__ float ub0(unsigned u) {
#if __has_builtin(__builtin_amdgcn_cvt_f32_ubyte0)
    return __builtin_amdgcn_cvt_f32_ubyte0(u);
#else
    return (float)(u & 0xff);
#endif
}
__device__ __forceinline__ float ub1(unsigned u) {
#if __has_builtin(__builtin_amdgcn_cvt_f32_ubyte1)
    return __builtin_amdgcn_cvt_f32_ubyte1(u);
#else
    return (float)((u >> 8) & 0xff);
#endif
}
__device__ __forceinline__ float ub2(unsigned u) {
#if __has_builtin(__builtin_amdgcn_cvt_f32_ubyte2)
    return __builtin_amdgcn_cvt_f32_ubyte2(u);
#else
    return (float)((u >> 16) & 0xff);
#endif
}
__device__ __forceinline__ float ub3(unsigned u) {
#if __has_builtin(__builtin_amdgcn_cvt_f32_ubyte3)
    return __builtin_amdgcn_cvt_f32_ubyte3(u);
#else
    return (float)(u >> 24);
#endif
}
__device__ __forceinline__ unsigned pku8(float f, unsigned pos, unsigned old) {
#if __has_builtin(__builtin_amdgcn_cvt_pk_u8_f32)
    return __builtin_amdgcn_cvt_pk_u8_f32(f, pos, old);
#else
    return old | ((unsigned)f << (8 * pos));
#endif
}

// int8 dot4: D = sum of 4 signed-byte products + C
__device__ __forceinline__ int dot4(unsigned a, unsigned b, int c) {
#if __has_builtin(__builtin_amdgcn_sdot4)
    return __builtin_amdgcn_sdot4((int)a, (int)b, c, false);
#else
    int r = c;
    r += ((int)(a << 24) >> 24) * ((int)(b << 24) >> 24);
    r += ((int)(a << 16) >> 24) * ((int)(b << 16) >> 24);
    r += ((int)(a <<  8) >> 24) * ((int)(b <<  8) >> 24);
    r += ((int)a >> 24) * ((int)b >> 24);
    return r;
#endif
}

// ---------------------------------------------------------------------------
// XCD-local histogram + per-edge rank within (group, node). g = blockIdx&7
// matches XCD round-robin -> each countg slice's atomic lines live in ONE
// XCD's L2. ONE atomic pass total.
// ---------------------------------------------------------------------------
__global__ __launch_bounds__(256) void histg_kernel(
    const int* __restrict__ xneis, int* __restrict__ countg,
    int* __restrict__ rank0)
{
    int e = blockIdx.x * 256 + threadIdx.x;
    if (e >= E) return;
    int g = blockIdx.x & (GN - 1);
    int nr = xneis[e];
    if (nr < V) rank0[e] = atomicAdd(&countg[g * V + nr], 1);
}

// Fold group slices (offg, cnt_tot) + blockwise-exclusive scan, fused.
__global__ __launch_bounds__(256) void scanV_kernel(
    const int* __restrict__ countg, int* __restrict__ offg,
    int* __restrict__ cnt_tot, int* __restrict__ scanned, int* __restrict__ bsum)
{
    __shared__ int s[256];
    int tid = threadIdx.x;
    int i = blockIdx.x * 256 + tid;
    int c = 0;
    if (i < V) {
        int run = 0;
        #pragma unroll
        for (int g = 0; g < GN; ++g) {
            offg[g * V + i] = run;
            run += countg[g * V + i];
        }
        cnt_tot[i] = run;
        c = run;
    }
    s[tid] = c; __syncthreads();
    #pragma unroll
    for (int off = 1; off < 256; off <<= 1) {
        int t = (tid >= off) ? s[tid - off] : 0;
        __syncthreads();
        s[tid] += t;
        __syncthreads();
    }
    if (i < V) scanned[i] = s[tid] - c;
    if (tid == 255) bsum[blockIdx.x] = s[255];
}

__global__ __launch_bounds__(512) void scan_tops_kernel(
    const int* __restrict__ blocksum, int* __restrict__ tops, int* __restrict__ rowptr)
{
    __shared__ int s[512];
    int tid = threadIdx.x;
    int v = (tid < NB) ? blocksum[tid] : 0;
    s[tid] = v; __syncthreads();
    #pragma unroll
    for (int off = 1; off < 512; off <<= 1) {
        int t = (tid >= off) ? s[tid - off] : 0;
        __syncthreads();
        s[tid] += t;
        __syncthreads();
    }
    if (tid < NB) tops[tid] = s[tid] - v;        // exclusive
    if (tid == 511) rowptr[V] = s[511];          // total kept edges
}

__global__ __launch_bounds__(256) void add_offsets_kernel(
    const int* __restrict__ scanned, const int* __restrict__ tops, int* __restrict__ rowptr)
{
    int i = blockIdx.x * 256 + threadIdx.x;
    if (i < V) rowptr[i] = scanned[i] + tops[blockIdx.x];
}

// Atomic-free scatter: slot = rowptr + group offset + within-group rank.
// meta word: src (17 b) | et (4 b) | dg-1 (6 b)
__global__ __launch_bounds__(256) void scatter_kernel(
    const int* __restrict__ xnode, const int* __restrict__ xneis,
    const int* __restrict__ etype, const float* __restrict__ dg,
    const int* __restrict__ rowptr, const int* __restrict__ offg,
    const int* __restrict__ rank0, unsigned* __restrict__ pmeta)
{
    int e = blockIdx.x * 256 + threadIdx.x;
    if (e >= E) return;
    int g = blockIdx.x & (GN - 1);
    int nr = xneis[e];
    if (nr < V) {
        int p = rowptr[nr] + offg[g * V + nr] + rank0[e];
        unsigned src = (unsigned)(xnode[e] - 1);
        unsigned et  = (unsigned)(etype[e] - 1);
        unsigned dgi = (unsigned)dg[e] - 1;        // 0..63, exact
        pmeta[p] = src | (et << 17) | (dgi << 21);
    }
}

// ---------------------------------------------------------------------------
// Per-node bias sum + quantized Hinit (Hq0: int8 row + fp32 scale in uint4).
// ---------------------------------------------------------------------------
__global__ __launch_bounds__(256) void bsum_kernel(
    const float* __restrict__ feat, const int* __restrict__ count,
    const float* __restrict__ Wrou, const float* __restrict__ brou,
    const float* __restrict__ Hinit, float* __restrict__ Bsum,
    uint4* __restrict__ Hq0)
{
    __shared__ float Wl[512];
    __shared__ float bl[8];
    int tid = threadIdx.x;
    for (int i = tid; i < 512; i += 256) Wl[i] = Wrou[i];
    if (tid < 8) bl[tid] = brou[tid];
    __syncthreads();

    int v = blockIdx.x * 256 + tid;
    if (v >= V) return;
    int c = count[v];
    float out[8] = {0, 0, 0, 0, 0, 0, 0, 0};
    if (c > 0) {                                  // c>0 implies v >= 1
        const float4* f4 = (const float4*)(feat + (size_t)(v - 1) * 64);
        float acc[8];
        #pragma unroll
        for (int s = 0; s < 8; ++s) acc[s] = bl[s];
        #pragma unroll 4
        for (int k = 0; k < 16; ++k) {
            float4 x = f4[k];
            #pragma unroll
            for (int s = 0; s < 8; ++s) {
                const float* w = &Wl[s * 64 + k * 4];
                acc[s] += x.x * w[0] + x.y * w[1] + x.z * w[2] + x.w * w[3];
            }
        }
        float fc = (float)c;
        #pragma unroll
        for (int s = 0; s < 8; ++s) out[s] = fc * fast_tanh(acc[s]);
    }
    float4* O = (float4*)(Bsum + (size_t)v * 8);
    O[0] = make_float4(out[0], out[1], out[2], out[3]);
    O[1] = make_float4(out[4], out[5], out[6], out[7]);

    // quantize Hinit row to int8 + per-node scale (for amat's fused step-1)
    const float4* Hh4 = (const float4*)(Hinit + (size_t)v * 8);
    float4 h0 = Hh4[0], h1 = Hh4[1];
    float hv[8] = {h0.x, h0.y, h0.z, h0.w, h1.x, h1.y, h1.z, h1.w};
    float mx = 0.0f;
    #pragma unroll
    for (int i = 0; i < 8; ++i) mx = fmaxf(mx, fabsf(hv[i]));
    float si = (mx > 0.0f) ? 127.0f / mx : 0.0f;
    unsigned bb[8];
    #pragma unroll
    for (int i = 0; i < 8; ++i) bb[i] = (unsigned)((int)rintf(hv[i] * si)) & 0xffu;
    uint4 o;
    o.x = bb[0] | (bb[1] << 8) | (bb[2] << 16) | (bb[3] << 24);
    o.y = bb[4] | (bb[5] << 8) | (bb[6] << 16) | (bb[7] << 24);
    o.z = __float_as_uint(mx * (1.0f / 127.0f));
    o.w = 0;
    Hq0[v] = o;
}

// ---------------------------------------------------------------------------
// PQ GEMM (MFMA): P[v] -> int8 biased (6.4 MB), Q[v] -> bf16 (12.8 MB)
// ---------------------------------------------------------------------------
__global__ __launch_bounds__(256) void pq_kernel(
    const float* __restrict__ feat, const float* __restrict__ Wxi,
    unsigned char* __restrict__ P8, ushort* __restrict__ Qb)
{
    const int lane = threadIdx.x & 63, wave = threadIdx.x >> 6;
    const int quad = lane >> 4, l16 = lane & 15;

    short8 bP[4][2], bQ[4][2];
    #pragma unroll
    for (int nt = 0; nt < 4; ++nt) {
        #pragma unroll
        for (int ks = 0; ks < 2; ++ks) {
            const float* wp = Wxi + (size_t)(nt * 16 + l16) * KXW + ks * 32 + quad * 8;
            short8 p, q;
            #pragma unroll
            for (int j = 0; j < 8; ++j) { p[j] = f2bf(wp[j]); q[j] = f2bf(wp[64 + j]); }
            bP[nt][ks] = p; bQ[nt][ks] = q;
        }
    }

    int t = blockIdx.x * 4 + wave;
    if (t >= V / 16) return;
    int v0 = t * 16;

    const float* fp = feat + (size_t)(v0 + l16) * 64 + quad * 8;
    short8 a0, a1;
    #pragma unroll
    for (int j = 0; j < 8; ++j) { a0[j] = f2bf(fp[j]); a1[j] = f2bf(fp[32 + j]); }

    float4v accP[4], accQ[4];
    #pragma unroll
    for (int nt = 0; nt < 4; ++nt) {
        float4v z = {0.f, 0.f, 0.f, 0.f};
        z = __builtin_amdgcn_mfma_f32_16x16x32_bf16(a0, bP[nt][0], z, 0, 0, 0);
        z = __builtin_amdgcn_mfma_f32_16x16x32_bf16(a1, bP[nt][1], z, 0, 0, 0);
        accP[nt] = z;
        float4v w = {0.f, 0.f, 0.f, 0.f};
        w = __builtin_amdgcn_mfma_f32_16x16x32_bf16(a0, bQ[nt][0], w, 0, 0, 0);
        w = __builtin_amdgcn_mfma_f32_16x16x32_bf16(a1, bQ[nt][1], w, 0, 0, 0);
        accQ[nt] = w;
    }

    #pragma unroll
    for (int r = 0; r < 4; ++r) {
        int row = v0 + quad * 4 + r;
        #pragma unroll
        for (int nt = 0; nt < 4; ++nt) {
            int col = nt * 16 + l16;
            int q8 = (int)rintf(accP[nt][r] * (1.0f / SP)) + 128;
            q8 = min(max(q8, 0), 255);
            P8[row * 64 + col] = (unsigned char)q8;
            Qb[row * 64 + col] = (ushort)f2bf(accQ[nt][r]);
        }
    }
}

// ---------------------------------------------------------------------------
// FUSED A materialization + STEP 1 (single-CSR, R2/R4/R6-proven structure).
// A8 stored SIGNED (byte = round(qf)-128, via XOR 0x80) for sdot4 steps.
// Fused step-1 uses the SAME sdot4 form as the steps, against Hq0.
// Output H1 is int8-per-node-scale packed in one uint4.
// ---------------------------------------------------------------------------
__global__ __launch_bounds__(256) void amat_kernel(
    const unsigned* __restrict__ pmeta, const int* __restrict__ rowptr,
    const unsigned char* __restrict__ P8, const ushort* __restrict__ Qb,
    const float* __restrict__ Wxi, const float* __restrict__ bxi,
    const uint4* __restrict__ Hq0, const float* __restrict__ Bsum,
    unsigned char* __restrict__ A8, uint4* __restrict__ HqOut)
{
    __shared__ float Wet2[NET * 64];     // 2*log2e*(Wxi[n][128+et]+bxi[n])
    __shared__ float scT[64];            // 127/dg
    int tid = threadIdx.x;
    for (int i = tid; i < NET * 64; i += 256) {
        int et = i >> 6, n = i & 63;
        Wet2[i] = 2.0f * LOG2E * (Wxi[n * KXW + 128 + et] + bxi[n]);
    }
    if (tid < 64) scT[tid] = 127.0f / (float)(tid + 1);
    __syncthreads();

    int v = blockIdx.x * 4 + (tid >> 6);
    if (v >= V) return;
    int lane = tid & 63;
    int el = lane >> 3, s = lane & 7;

    const int off = rowptr[v];
    const int deg = rowptr[v + 1] - off;

    float q0, q1, q2, q3, q4, q5, q6, q7;
    {
        uint4 qu = *(const uint4*)(Qb + v * 64 + s * 8);
        const float B = 128.0f * SP, C = 2.0f * LOG2E;
        q0 = C * (bflo(qu.x) - B); q1 = C * (bfhi(qu.x) - B);
        q2 = C * (bflo(qu.y) - B); q3 = C * (bfhi(qu.y) - B);
        q4 = C * (bflo(qu.z) - B); q5 = C * (bfhi(qu.z) - B);
        q6 = C * (bflo(qu.w) - B); q7 = C * (bfhi(qu.w) - B);
    }

    float accD = 0.0f;                    // fused step-1 accumulator

    for (int base = 0; base < deg; base += 64) {
        // phase 1: this lane resolves edge (base+lane) — fully coalesced
        unsigned m_mine = 0;
        {
            int i1 = base + lane;
            if (i1 < deg) m_mine = pmeta[off + i1];
        }
        // phase 2: 8 edges per sub-round, meta via shfl broadcast
        int nb = deg - base;
        for (int k = 0; k * 8 + el < nb && k < 8; ++k) {
            int ib = k * 8 + el;
            int i = base + ib;
            unsigned m = __shfl(m_mine, ib);
            int src = (int)(m & 0x1FFFF);
            int et  = (int)((m >> 17) & 0xF);
            float kk  = scT[m >> 21];
            float m2k = -2.0f * kk;
            float ck  = kk + 128.5f;

            // issue all loads up front so they overlap the exp chain
            uint2 pu = *(const uint2*)(P8 + src * 64 + s * 8);
            const float4* w4 = (const float4*)(&Wet2[et * 64 + s * 8]);
            float4 wa = w4[0], wb = w4[1];
            uint4 hq = Hq0[src];

            float r0 = __builtin_amdgcn_rcpf(__builtin_amdgcn_exp2f(fmaf(ub0(pu.x), S2L, q0 + wa.x)) + 1.0f);
            float r1 = __builtin_amdgcn_rcpf(__builtin_amdgcn_exp2f(fmaf(ub1(pu.x), S2L, q1 + wa.y)) + 1.0f);
            float r2 = __builtin_amdgcn_rcpf(__builtin_amdgcn_exp2f(fmaf(ub2(pu.x), S2L, q2 + wa.z)) + 1.0f);
            float r3 = __builtin_amdgcn_rcpf(__builtin_amdgcn_exp2f(fmaf(ub3(pu.x), S2L, q3 + wa.w)) + 1.0f);
            float r4 = __builtin_amdgcn_rcpf(__builtin_amdgcn_exp2f(fmaf(ub0(pu.y), S2L, q4 + wb.x)) + 1.0f);
            float r5 = __builtin_amdgcn_rcpf(__builtin_amdgcn_exp2f(fmaf(ub1(pu.y), S2L, q5 + wb.y)) + 1.0f);
            float r6 = __builtin_amdgcn_rcpf(__builtin_amdgcn_exp2f(fmaf(ub2(pu.y), S2L, q6 + wb.z)) + 1.0f);
            float r7 = __builtin_amdgcn_rcpf(__builtin_amdgcn_exp2f(fmaf(ub3(pu.y), S2L, q7 + wb.w)) + 1.0f);

            float qf0 = fmaf(r0, m2k, ck), qf1 = fmaf(r1, m2k, ck);
            float qf2 = fmaf(r2, m2k, ck), qf3 = fmaf(r3, m2k, ck);
            float qf4 = fmaf(r4, m2k, ck), qf5 = fmaf(r5, m2k, ck);
            float qf6 = fmaf(r6, m2k, ck), qf7 = fmaf(r7, m2k, ck);

            uint2 o;
            o.x = pku8(qf3, 3, pku8(qf2, 2, pku8(qf1, 1, pku8(qf0, 0, 0u)))) ^ 0x80808080u;
            o.y = pku8(qf7, 3, pku8(qf6, 2, pku8(qf5, 1, pku8(qf4, 0, 0u)))) ^ 0x80808080u;
            *(uint2*)(A8 + (unsigned)(off + i) * 64u + (unsigned)(s * 8)) = o;

            // fused step 1: same sdot4 form the steps use (A row . Hq0[src])
            int dd = dot4(o.x, hq.x, dot4(o.y, hq.y, 0));
            accD = fmaf((float)dd, __uint_as_float(hq.z), accD);
        }
    }
    // reduce over el lanes (lane = el*8 + s)
    accD += __shfl_xor(accD, 8);  accD += __shfl_xor(accD, 16); accD += __shfl_xor(accD, 32);
    float h1v = accD * AS + Bsum[v * 8 + s];

    // quantize H1 row to int8 with per-node scale, pack to uint4
    float mx = fabsf(h1v);
    mx = fmaxf(mx, __shfl_xor(mx, 1));
    mx = fmaxf(mx, __shfl_xor(mx, 2));
    mx = fmaxf(mx, __shfl_xor(mx, 4));           // max over s within el group
    float si = (mx > 0.0f) ? 127.0f / mx : 0.0f;
    unsigned b = (unsigned)((int)rintf(h1v * si)) & 0xffu;
    unsigned b1 = __shfl(b, lane + 1), b2 = __shfl(b, lane + 2), b3 = __shfl(b, lane + 3);
    unsigned b4 = __shfl(b, lane + 4), b5 = __shfl(b, lane + 5);
    unsigned b6 = __shfl(b, lane + 6), b7 = __shfl(b, lane + 7);
    if (lane == 0) {
        uint4 hq;
        hq.x = b  | (b1 << 8) | (b2 << 16) | (b3 << 24);
        hq.y = b4 | (b5 << 8) | (b6 << 16) | (b7 << 24);
        hq.z = __float_as_uint(mx * (1.0f / 127.0f));
        hq.w = 0;
        HqOut[v] = hq;
    }
}

// ---------------------------------------------------------------------------
// Light step, QUAD-PER-NODE: 4 lanes serve one node (16 nodes/wave).
// Edges iterate serially per quad: lane q reads 16B of the 64B A row
// (quad covers the full line), Hq broadcast within quad. NO inter-lane
// edge reduce (serial in-lane); epilogue = 4 shfl_xor total. No idle
// lanes from deg<16. Runs 3x.
// ---------------------------------------------------------------------------
__global__ __launch_bounds__(256) void step_kernel(
    const uint4* __restrict__ HqIn, uint4* __restrict__ HqOut,
    const unsigned* __restrict__ pmeta, const int* __restrict__ rowptr,
    const unsigned char* __restrict__ A8, const float* __restrict__ Bsum,
    const float* __restrict__ W1, const float* __restrict__ b1,
    float* __restrict__ logitsOut, float* __restrict__ HfpOut)
{
    int v = blockIdx.x * 64 + (threadIdx.x >> 2);
    if (v >= V) return;
    int q = threadIdx.x & 3;

    int p0 = rowptr[v], p1 = rowptr[v + 1];

    float accE = 0.0f, accO = 0.0f;
    for (int p = p0; p < p1; ++p) {
        unsigned m = pmeta[p];                 // broadcast within quad
        int src = (int)(m & 0x1FFFFu);
        uint4 au = *(const uint4*)(A8 + (unsigned)p * 64u + (unsigned)(q * 16));
        uint4 hq = HqIn[src];                  // broadcast within quad
        int dE = dot4(au.x, hq.x, dot4(au.y, hq.y, 0));
        int dO = dot4(au.z, hq.x, dot4(au.w, hq.y, 0));
        float sc = __uint_as_float(hq.z);
        accE = fmaf((float)dE, sc, accE);
        accO = fmaf((float)dO, sc, accO);
    }

    float hE = accE * AS + Bsum[v * 8 + q * 2];
    float hO = accO * AS + Bsum[v * 8 + q * 2 + 1];

    // quantize H row to int8 with per-node scale (reduce within quad only)
    float mx = fmaxf(fabsf(hE), fabsf(hO));
    mx = fmaxf(mx, __shfl_xor(mx, 1));
    mx = fmaxf(mx, __shfl_xor(mx, 2));
    float si = (mx > 0.0f) ? 127.0f / mx : 0.0f;
    unsigned qE = (unsigned)((int)rintf(hE * si)) & 0xffu;
    unsigned qO = (unsigned)((int)rintf(hO * si)) & 0xffu;
    unsigned hw = qE | (qO << 8);              // bytes 2q, 2q+1
    unsigned w0 = hw | (__shfl_xor(hw, 1) << 16);  // valid on even q
    unsigned w1 = __shfl_xor(w0, 2);               // q=0: gets (q2,q3) pair
    if (q == 0) {
        uint4 o;
        o.x = w0;
        o.y = w1;
        o.z = __float_as_uint(mx * (1.0f / 127.0f));
        o.w = 0;
        HqOut[v] = o;
    }
    if (HfpOut != nullptr)
        *(float2*)(HfpOut + v * 8 + q * 2) = make_float2(hE, hO);
    if (logitsOut != nullptr) {
        float t = hE * W1[q * 2] + hO * W1[q * 2 + 1];
        t += __shfl_xor(t, 1); t += __shfl_xor(t, 2);
        if (q == 0) logitsOut[v] = t + b1[0];
    }
}

// ---------------------------------------------------------------------------
// Epilogue
// ---------------------------------------------------------------------------
__global__ __launch_bounds__(256) void reduce_max_kernel(
    const float* __restrict__ logits, float* __restrict__ partial)
{
    float m = -INFINITY;
    for (int v = blockIdx.x * 256 + threadIdx.x; v < V; v += 256 * 256)
        m = fmaxf(m, logits[v]);
    #pragma unroll
    for (int o = 32; o > 0; o >>= 1) m = fmaxf(m, __shfl_down(m, o));
    __shared__ float sm[4];
    if ((threadIdx.x & 63) == 0) sm[threadIdx.x >> 6] = m;
    __syncthreads();
    if (threadIdx.x == 0)
        partial[blockIdx.x] = fmaxf(fmaxf(sm[0], sm[1]), fmaxf(sm[2], sm[3]));
}

__global__ __launch_bounds__(256) void final_max_kernel(
    const float* __restrict__ partial, float* __restrict__ M)
{
    float m = partial[threadIdx.x];
    #pragma unroll
    for (int o = 32; o > 0; o >>= 1) m = fmaxf(m, __shfl_down(m, o));
    __shared__ float sm[4];
    if ((threadIdx.x & 63) == 0) sm[threadIdx.x >> 6] = m;
    __syncthreads();
    if (threadIdx.x == 0) *M = fmaxf(fmaxf(sm[0], sm[1]), fmaxf(sm[2], sm[3]));
}

// Stage 1: 64 blocks write per-block partials (9 floats each) — no atomics.
__global__ __launch_bounds__(256) void sum_kernel(
    const float* __restrict__ H, const float* __restrict__ logits,
    const float* __restrict__ Mp, float* __restrict__ partial)
{
    const float M = *Mp;
    float se = 0.0f;
    float sh[8] = {0, 0, 0, 0, 0, 0, 0, 0};
    for (int v = blockIdx.x * 256 + threadIdx.x; v < V; v += 64 * 256) {
        float w = __expf(logits[v] - M);
        se += w;
        const float4* H4 = (const float4*)(H + (size_t)v * 8);
        float4 h0 = H4[0], h1 = H4[1];
        sh[0] += w * h0.x; sh[1] += w * h0.y; sh[2] += w * h0.z; sh[3] += w * h0.w;
        sh[4] += w * h1.x; sh[5] += w * h1.y; sh[6] += w * h1.z; sh[7] += w * h1.w;
    }
    #pragma unroll
    for (int o = 32; o > 0; o >>= 1) {
        se += __shfl_xor(se, o);
        #pragma unroll
        for (int i = 0; i < 8; ++i) sh[i] += __shfl_xor(sh[i], o);
    }
    __shared__ float sm[4][9];
    int wv = threadIdx.x >> 6;
    if ((threadIdx.x & 63) == 0) {
        sm[wv][8] = se;
        #pragma unroll
        for (int i = 0; i < 8; ++i) sm[wv][i] = sh[i];
    }
    __syncthreads();
    if (threadIdx.x == 0) {
        #pragma unroll
        for (int i = 0; i < 9; ++i)
            partial[blockIdx.x * 12 + i] = sm[0][i] + sm[1][i] + sm[2][i] + sm[3][i];
    }
}

__global__ void final_kernel(const float* __restrict__ partial, float* __restrict__ out)
{
    int lane = threadIdx.x;               // 64 threads
    float vals[9];
    #pragma unroll
    for (int i = 0; i < 9; ++i) vals[i] = partial[lane * 12 + i];
    #pragma unroll
    for (int o = 1; o < 64; o <<= 1) {
        #pragma unroll
        for (int i = 0; i < 9; ++i) vals[i] += __shfl_xor(vals[i], o);
    }
    __shared__ float res[9];
    if (lane == 0) {
        #pragma unroll
        for (int i = 0; i < 9; ++i) res[i] = vals[i];
    }
    __syncthreads();
    if (lane < 8) out[lane] = tanhf(res[lane] / res[8]);
}

// ---------------------------------------------------------------------------
extern "C" void kernel_launch(void* const* d_in, const int* in_sizes, int n_in,
                              void* d_out, int out_size, void* d_ws, size_t ws_size,
                              hipStream_t stream)
{
    const float* feat  = (const float*)d_in[0];
    const int*   xnode = (const int*)d_in[1];
    const int*   xneis = (const int*)d_in[2];
    const int*   etype = (const int*)d_in[3];
    const float* dg    = (const float*)d_in[4];
    const float* Hinit = (const float*)d_in[5];
    const float* Wxi   = (const float*)d_in[6];
    const float* bxi   = (const float*)d_in[7];
    const float* Wrou  = (const float*)d_in[8];
    const float* brou  = (const float*)d_in[9];
    const float* W1    = (const float*)d_in[10];
    const float* b1    = (const float*)d_in[11];

    char* ws = (char*)d_ws;
    auto alloc = [&](size_t bytes) -> char* {
        char* p = ws; ws += (bytes + 255) & ~(size_t)255; return p;
    };
    unsigned char* A8 = (unsigned char*)alloc((size_t)E * 64); // 102.4 MB int8 A (signed)
    unsigned char* P8 = (unsigned char*)alloc((size_t)V * 64); // 6.4 MB int8 P
    ushort*   Qb      = (ushort*)alloc((size_t)V * 64 * 2);    // 12.8 MB bf16 Q
    unsigned* pmeta   = (unsigned*)alloc((size_t)E * 4);       // 6.4 MB CSR meta
    int*      rank0   = (int*)alloc((size_t)E * 4);            // 6.4 MB per-edge rank
    int*      countg  = (int*)alloc((size_t)GN * V * 4);       // 3.2 MB XCD-local counts
    int*      offg    = (int*)alloc((size_t)GN * V * 4);       // 3.2 MB group offsets
    int*      cnt     = (int*)alloc((size_t)V * 4);            // per-node count
    int*      scanned = (int*)alloc((size_t)V * 4);
    int*      rowptr  = (int*)alloc((size_t)(V + 1) * 4);
    int*      bsumT   = (int*)alloc(512 * 4);
    int*      topsT   = (int*)alloc(512 * 4);
    uint4*    Hq0     = (uint4*)alloc((size_t)V * 16);         // quantized Hinit
    uint4*    HqA     = (uint4*)alloc((size_t)V * 16);         // int8 H + scale
    uint4*    HqB     = (uint4*)alloc((size_t)V * 16);
    float*    Hfp     = (float*)alloc((size_t)V * 8 * 4);      // fp32 H (last step)
    float*    Bsum    = (float*)alloc((size_t)V * 8 * 4);
    float*    logits  = (float*)alloc((size_t)V * 4);
    float*    pmax    = (float*)alloc(256 * 4);
    float*    Mp      = (float*)alloc(16);
    float*    spart   = (float*)alloc(64 * 12 * 4);

    hipMemsetAsync(countg, 0, (size_t)GN * V * 4, stream);
    histg_kernel<<<(E + 255) / 256, 256, 0, stream>>>(xneis, countg, rank0);
    scanV_kernel<<<NB, 256, 0, stream>>>(countg, offg, cnt, scanned, bsumT);
    scan_tops_kernel<<<1, 512, 0, stream>>>(bsumT, topsT, rowptr);
    add_offsets_kernel<<<NB, 256, 0, stream>>>(scanned, topsT, rowptr);
    scatter_kernel<<<(E + 255) / 256, 256, 0, stream>>>(xnode, xneis, etype, dg,
                                                        rowptr, offg, rank0, pmeta);
    pq_kernel<<<(V / 16 + 3) / 4, 256, 0, stream>>>(feat, Wxi, P8, Qb);
    bsum_kernel<<<NB, 256, 0, stream>>>(feat, cnt, Wrou, brou, Hinit,
                                        Bsum, Hq0);
    // amat + fused step 1: writes signed A8 and quantized H1 in one pass
    amat_kernel<<<(V + 3) / 4, 256, 0, stream>>>(pmeta, rowptr, P8, Qb, Wxi, bxi,
                                                 Hq0, Bsum, A8, HqA);

    // steps 2..4 (quad-per-node)
    const uint4* Hcur = HqA;
    uint4* bufs[2] = {HqB, HqA};
    for (int t = 0; t < 3; ++t) {
        uint4* Hn = bufs[t & 1];
        float* lg  = (t == 2) ? logits : nullptr;
        float* hf  = (t == 2) ? Hfp : nullptr;
        step_kernel<<<(V + 63) / 64, 256, 0, stream>>>(Hcur, Hn, pmeta, rowptr,
                                                       A8, Bsum, W1, b1, lg, hf);
        Hcur = Hn;
    }

    reduce_max_kernel<<<256, 256, 0, stream>>>(logits, pmax);
    final_max_kernel<<<1, 256, 0, stream>>>(pmax, Mp);
    sum_kernel<<<64, 256, 0, stream>>>(Hfp, logits, Mp, spart);
    final_kernel<<<1, 64, 0, stream>>>(spart, (float*)d_out);
}

// Round 8
// 430.092 us; speedup vs baseline: 1.0681x; 1.0681x over previous
//
#include <hip/hip_runtime.h>
#include <hip/hip_bf16.h>

constexpr int V   = 100000;
constexpr int E   = 1600000;
constexpr int NET = 10;
constexpr int KXW = 138;              // W_xi row length (2*64+10)
constexpr int NB  = (V + 255) / 256;  // 391 blocks over nodes
constexpr int GN  = 8;                // count groups (= XCDs)
constexpr float MUS   = 0.1125f;      // MU / S
constexpr float SP    = 0.025f;       // int8 P scale
constexpr float LOG2E = 1.44269504f;
constexpr float S2L   = 2.0f * SP * LOG2E;   // int8 P step in exp2 domain
constexpr float K7    = MUS / 7.0f;          // int4 A decode scale (x 1/dg per edge)

typedef __attribute__((ext_vector_type(8))) short short8;
typedef __attribute__((ext_vector_type(4))) float float4v;

__device__ __forceinline__ float fast_tanh(float x) {
    return 1.0f - 2.0f * __builtin_amdgcn_rcpf(__expf(2.0f * x) + 1.0f);
}
__device__ __forceinline__ float bflo(unsigned u) { return __uint_as_float(u << 16); }
__device__ __forceinline__ float bfhi(unsigned u) { return __uint_as_float(u & 0xffff0000u); }
__device__ __forceinline__ short f2bf(float x) {
    union { __hip_bfloat16 b; short s; } u; u.b = __float2bfloat16(x); return u.s;
}

__device__ __forceinline__ float ub0(unsigned u) {
#if __has_builtin(__builtin_amdgcn_cvt_f32_ubyte0)
    return __builtin_amdgcn_cvt_f32_ubyte0(u);
#else
    return (float)(u & 0xff);
#endif
}
__device__ __forceinline__ float ub1(unsigned u) {
#if __has_builtin(__builtin_amdgcn_cvt_f32_ubyte1)
    return __builtin_amdgcn_cvt_f32_ubyte1(u);
#else
    return (float)((u >> 8) & 0xff);
#endif
}
__device__ __forceinline__ float ub2(unsigned u) {
#if __has_builtin(__builtin_amdgcn_cvt_f32_ubyte2)
    return __builtin_amdgcn_cvt_f32_ubyte2(u);
#else
    return (float)((u >> 16) & 0xff);
#endif
}
__device__ __forceinline__ float ub3(unsigned u) {
#if __has_builtin(__builtin_amdgcn_cvt_f32_ubyte3)
    return __builtin_amdgcn_cvt_f32_ubyte3(u);
#else
    return (float)(u >> 24);
#endif
}

// int4 dot8: D = sum of 8 signed-nibble products + C (v_dot8_i32_i4)
__device__ __forceinline__ int dot8i4(unsigned a, unsigned b, int c) {
#if __has_builtin(__builtin_amdgcn_sdot8)
    return __builtin_amdgcn_sdot8((int)a, (int)b, c, false);
#else
    int r = c;
    #pragma unroll
    for (int j = 0; j < 8; ++j) {
        int av = ((int)(a << (28 - 4 * j))) >> 28;
        int bv = ((int)(b << (28 - 4 * j))) >> 28;
        r += av * bv;
    }
    return r;
#endif
}

// ---------------------------------------------------------------------------
// XCD-local histogram + per-edge rank within (group, node). g = blockIdx&7.
// ONE atomic pass total. (R6/R7 tripwire-proven build path, unchanged.)
// ---------------------------------------------------------------------------
__global__ __launch_bounds__(256) void histg_kernel(
    const int* __restrict__ xneis, int* __restrict__ countg,
    int* __restrict__ rank0)
{
    int e = blockIdx.x * 256 + threadIdx.x;
    if (e >= E) return;
    int g = blockIdx.x & (GN - 1);
    int nr = xneis[e];
    if (nr < V) rank0[e] = atomicAdd(&countg[g * V + nr], 1);
}

// Fold group slices (offg, cnt_tot) + blockwise-exclusive scan, fused.
__global__ __launch_bounds__(256) void scanV_kernel(
    const int* __restrict__ countg, int* __restrict__ offg,
    int* __restrict__ cnt_tot, int* __restrict__ scanned, int* __restrict__ bsum)
{
    __shared__ int s[256];
    int tid = threadIdx.x;
    int i = blockIdx.x * 256 + tid;
    int c = 0;
    if (i < V) {
        int run = 0;
        #pragma unroll
        for (int g = 0; g < GN; ++g) {
            offg[g * V + i] = run;
            run += countg[g * V + i];
        }
        cnt_tot[i] = run;
        c = run;
    }
    s[tid] = c; __syncthreads();
    #pragma unroll
    for (int off = 1; off < 256; off <<= 1) {
        int t = (tid >= off) ? s[tid - off] : 0;
        __syncthreads();
        s[tid] += t;
        __syncthreads();
    }
    if (i < V) scanned[i] = s[tid] - c;
    if (tid == 255) bsum[blockIdx.x] = s[255];
}

__global__ __launch_bounds__(512) void scan_tops_kernel(
    const int* __restrict__ blocksum, int* __restrict__ tops, int* __restrict__ rowptr)
{
    __shared__ int s[512];
    int tid = threadIdx.x;
    int v = (tid < NB) ? blocksum[tid] : 0;
    s[tid] = v; __syncthreads();
    #pragma unroll
    for (int off = 1; off < 512; off <<= 1) {
        int t = (tid >= off) ? s[tid - off] : 0;
        __syncthreads();
        s[tid] += t;
        __syncthreads();
    }
    if (tid < NB) tops[tid] = s[tid] - v;        // exclusive
    if (tid == 511) rowptr[V] = s[511];          // total kept edges
}

__global__ __launch_bounds__(256) void add_offsets_kernel(
    const int* __restrict__ scanned, const int* __restrict__ tops, int* __restrict__ rowptr)
{
    int i = blockIdx.x * 256 + threadIdx.x;
    if (i < V) rowptr[i] = scanned[i] + tops[blockIdx.x];
}

// Atomic-free scatter: slot = rowptr + group offset + within-group rank.
// meta word: src (17 b) | et (4 b) | dg-1 (6 b)
__global__ __launch_bounds__(256) void scatter_kernel(
    const int* __restrict__ xnode, const int* __restrict__ xneis,
    const int* __restrict__ etype, const float* __restrict__ dg,
    const int* __restrict__ rowptr, const int* __restrict__ offg,
    const int* __restrict__ rank0, unsigned* __restrict__ pmeta)
{
    int e = blockIdx.x * 256 + threadIdx.x;
    if (e >= E) return;
    int g = blockIdx.x & (GN - 1);
    int nr = xneis[e];
    if (nr < V) {
        int p = rowptr[nr] + offg[g * V + nr] + rank0[e];
        unsigned src = (unsigned)(xnode[e] - 1);
        unsigned et  = (unsigned)(etype[e] - 1);
        unsigned dgi = (unsigned)dg[e] - 1;        // 0..63, exact
        pmeta[p] = src | (et << 17) | (dgi << 21);
    }
}

// ---------------------------------------------------------------------------
// Per-node bias sum + int4-quantized Hinit (Hq0: 8 nibbles + fp32 scale).
// ---------------------------------------------------------------------------
__global__ __launch_bounds__(256) void bsum_kernel(
    const float* __restrict__ feat, const int* __restrict__ count,
    const float* __restrict__ Wrou, const float* __restrict__ brou,
    const float* __restrict__ Hinit, float* __restrict__ Bsum,
    uint2* __restrict__ Hq0)
{
    __shared__ float Wl[512];
    __shared__ float bl[8];
    int tid = threadIdx.x;
    for (int i = tid; i < 512; i += 256) Wl[i] = Wrou[i];
    if (tid < 8) bl[tid] = brou[tid];
    __syncthreads();

    int v = blockIdx.x * 256 + tid;
    if (v >= V) return;
    int c = count[v];
    float out[8] = {0, 0, 0, 0, 0, 0, 0, 0};
    if (c > 0) {                                  // c>0 implies v >= 1
        const float4* f4 = (const float4*)(feat + (size_t)(v - 1) * 64);
        float acc[8];
        #pragma unroll
        for (int s = 0; s < 8; ++s) acc[s] = bl[s];
        #pragma unroll 4
        for (int k = 0; k < 16; ++k) {
            float4 x = f4[k];
            #pragma unroll
            for (int s = 0; s < 8; ++s) {
                const float* w = &Wl[s * 64 + k * 4];
                acc[s] += x.x * w[0] + x.y * w[1] + x.z * w[2] + x.w * w[3];
            }
        }
        float fc = (float)c;
        #pragma unroll
        for (int s = 0; s < 8; ++s) out[s] = fc * fast_tanh(acc[s]);
    }
    float4* O = (float4*)(Bsum + (size_t)v * 8);
    O[0] = make_float4(out[0], out[1], out[2], out[3]);
    O[1] = make_float4(out[4], out[5], out[6], out[7]);

    // quantize Hinit row to int4 nibbles + per-node scale
    const float4* Hh4 = (const float4*)(Hinit + (size_t)v * 8);
    float4 h0 = Hh4[0], h1 = Hh4[1];
    float hv[8] = {h0.x, h0.y, h0.z, h0.w, h1.x, h1.y, h1.z, h1.w};
    float mx = 0.0f;
    #pragma unroll
    for (int i = 0; i < 8; ++i) mx = fmaxf(mx, fabsf(hv[i]));
    float si = (mx > 0.0f) ? 7.0f / mx : 0.0f;
    unsigned w = 0;
    #pragma unroll
    for (int i = 0; i < 8; ++i)
        w |= ((unsigned)((int)rintf(hv[i] * si)) & 0xFu) << (4 * i);
    Hq0[v] = make_uint2(w, __float_as_uint(mx * (1.0f / 7.0f)));
}

// ---------------------------------------------------------------------------
// PQ GEMM (MFMA): P[v] -> int8 biased (6.4 MB), Q[v] -> bf16 (12.8 MB)
// ---------------------------------------------------------------------------
__global__ __launch_bounds__(256) void pq_kernel(
    const float* __restrict__ feat, const float* __restrict__ Wxi,
    unsigned char* __restrict__ P8, ushort* __restrict__ Qb)
{
    const int lane = threadIdx.x & 63, wave = threadIdx.x >> 6;
    const int quad = lane >> 4, l16 = lane & 15;

    short8 bP[4][2], bQ[4][2];
    #pragma unroll
    for (int nt = 0; nt < 4; ++nt) {
        #pragma unroll
        for (int ks = 0; ks < 2; ++ks) {
            const float* wp = Wxi + (size_t)(nt * 16 + l16) * KXW + ks * 32 + quad * 8;
            short8 p, q;
            #pragma unroll
            for (int j = 0; j < 8; ++j) { p[j] = f2bf(wp[j]); q[j] = f2bf(wp[64 + j]); }
            bP[nt][ks] = p; bQ[nt][ks] = q;
        }
    }

    int t = blockIdx.x * 4 + wave;
    if (t >= V / 16) return;
    int v0 = t * 16;

    const float* fp = feat + (size_t)(v0 + l16) * 64 + quad * 8;
    short8 a0, a1;
    #pragma unroll
    for (int j = 0; j < 8; ++j) { a0[j] = f2bf(fp[j]); a1[j] = f2bf(fp[32 + j]); }

    float4v accP[4], accQ[4];
    #pragma unroll
    for (int nt = 0; nt < 4; ++nt) {
        float4v z = {0.f, 0.f, 0.f, 0.f};
        z = __builtin_amdgcn_mfma_f32_16x16x32_bf16(a0, bP[nt][0], z, 0, 0, 0);
        z = __builtin_amdgcn_mfma_f32_16x16x32_bf16(a1, bP[nt][1], z, 0, 0, 0);
        accP[nt] = z;
        float4v w = {0.f, 0.f, 0.f, 0.f};
        w = __builtin_amdgcn_mfma_f32_16x16x32_bf16(a0, bQ[nt][0], w, 0, 0, 0);
        w = __builtin_amdgcn_mfma_f32_16x16x32_bf16(a1, bQ[nt][1], w, 0, 0, 0);
        accQ[nt] = w;
    }

    #pragma unroll
    for (int r = 0; r < 4; ++r) {
        int row = v0 + quad * 4 + r;
        #pragma unroll
        for (int nt = 0; nt < 4; ++nt) {
            int col = nt * 16 + l16;
            int q8 = (int)rintf(accP[nt][r] * (1.0f / SP)) + 128;
            q8 = min(max(q8, 0), 255);
            P8[row * 64 + col] = (unsigned char)q8;
            Qb[row * 64 + col] = (ushort)f2bf(accQ[nt][r]);
        }
    }
}

// ---------------------------------------------------------------------------
// FUSED A materialization + STEP 1. A stored INT4: row s = 8 nibbles
// n = round(7*tanh) in one u32 at A4[edge*32 + s*4]; decode scale =
// (MUS/7)/dg applied per-edge in the steps. Fused step-1 uses the same
// sdot8 form the steps use, against Hq0. H1 out = int4 nibbles + scale.
// ---------------------------------------------------------------------------
__global__ __launch_bounds__(256) void amat_kernel(
    const unsigned* __restrict__ pmeta, const int* __restrict__ rowptr,
    const unsigned char* __restrict__ P8, const ushort* __restrict__ Qb,
    const float* __restrict__ Wxi, const float* __restrict__ bxi,
    const uint2* __restrict__ Hq0, const float* __restrict__ Bsum,
    unsigned* __restrict__ A4, uint2* __restrict__ HqOut)
{
    __shared__ float Wet2[NET * 64];     // 2*log2e*(Wxi[n][128+et]+bxi[n])
    int tid = threadIdx.x;
    for (int i = tid; i < NET * 64; i += 256) {
        int et = i >> 6, n = i & 63;
        Wet2[i] = 2.0f * LOG2E * (Wxi[n * KXW + 128 + et] + bxi[n]);
    }
    __syncthreads();

    int v = blockIdx.x * 4 + (tid >> 6);
    if (v >= V) return;
    int lane = tid & 63;
    int el = lane >> 3, s = lane & 7;

    const int off = rowptr[v];
    const int deg = rowptr[v + 1] - off;

    float q0, q1, q2, q3, q4, q5, q6, q7;
    {
        uint4 qu = *(const uint4*)(Qb + v * 64 + s * 8);
        const float B = 128.0f * SP, C = 2.0f * LOG2E;
        q0 = C * (bflo(qu.x) - B); q1 = C * (bfhi(qu.x) - B);
        q2 = C * (bflo(qu.y) - B); q3 = C * (bfhi(qu.y) - B);
        q4 = C * (bflo(qu.z) - B); q5 = C * (bfhi(qu.z) - B);
        q6 = C * (bflo(qu.w) - B); q7 = C * (bfhi(qu.w) - B);
    }

    float accD = 0.0f;                    // fused step-1 accumulator

    for (int base = 0; base < deg; base += 64) {
        // phase 1: this lane resolves edge (base+lane) — fully coalesced
        unsigned m_mine = 0;
        {
            int i1 = base + lane;
            if (i1 < deg) m_mine = pmeta[off + i1];
        }
        // phase 2: 8 edges per sub-round, meta via shfl broadcast
        int nb = deg - base;
        for (int k = 0; k * 8 + el < nb && k < 8; ++k) {
            int ib = k * 8 + el;
            int i = base + ib;
            unsigned m = __shfl(m_mine, ib);
            int src = (int)(m & 0x1FFFF);
            int et  = (int)((m >> 17) & 0xF);

            // issue all loads up front so they overlap the exp chain
            uint2 pu = *(const uint2*)(P8 + src * 64 + s * 8);
            const float4* w4 = (const float4*)(&Wet2[et * 64 + s * 8]);
            float4 wa = w4[0], wb = w4[1];
            uint2 hq = Hq0[src];

            float r0 = __builtin_amdgcn_rcpf(__builtin_amdgcn_exp2f(fmaf(ub0(pu.x), S2L, q0 + wa.x)) + 1.0f);
            float r1 = __builtin_amdgcn_rcpf(__builtin_amdgcn_exp2f(fmaf(ub1(pu.x), S2L, q1 + wa.y)) + 1.0f);
            float r2 = __builtin_amdgcn_rcpf(__builtin_amdgcn_exp2f(fmaf(ub2(pu.x), S2L, q2 + wa.z)) + 1.0f);
            float r3 = __builtin_amdgcn_rcpf(__builtin_amdgcn_exp2f(fmaf(ub3(pu.x), S2L, q3 + wa.w)) + 1.0f);
            float r4 = __builtin_amdgcn_rcpf(__builtin_amdgcn_exp2f(fmaf(ub0(pu.y), S2L, q4 + wb.x)) + 1.0f);
            float r5 = __builtin_amdgcn_rcpf(__builtin_amdgcn_exp2f(fmaf(ub1(pu.y), S2L, q5 + wb.y)) + 1.0f);
            float r6 = __builtin_amdgcn_rcpf(__builtin_amdgcn_exp2f(fmaf(ub2(pu.y), S2L, q6 + wb.z)) + 1.0f);
            float r7 = __builtin_amdgcn_rcpf(__builtin_amdgcn_exp2f(fmaf(ub3(pu.y), S2L, q7 + wb.w)) + 1.0f);

            // n = round(7*tanh) = round(7 - 14*r), in [-7,7]
            int n0 = (int)rintf(fmaf(r0, -14.0f, 7.0f));
            int n1 = (int)rintf(fmaf(r1, -14.0f, 7.0f));
            int n2 = (int)rintf(fmaf(r2, -14.0f, 7.0f));
            int n3 = (int)rintf(fmaf(r3, -14.0f, 7.0f));
            int n4 = (int)rintf(fmaf(r4, -14.0f, 7.0f));
            int n5 = (int)rintf(fmaf(r5, -14.0f, 7.0f));
            int n6 = (int)rintf(fmaf(r6, -14.0f, 7.0f));
            int n7 = (int)rintf(fmaf(r7, -14.0f, 7.0f));

            unsigned w = ((unsigned)n0 & 0xFu)        | (((unsigned)n1 & 0xFu) << 4)
                       | (((unsigned)n2 & 0xFu) << 8)  | (((unsigned)n3 & 0xFu) << 12)
                       | (((unsigned)n4 & 0xFu) << 16) | (((unsigned)n5 & 0xFu) << 20)
                       | (((unsigned)n6 & 0xFu) << 24) | (((unsigned)n7 & 0xFu) << 28);
            A4[(unsigned)(off + i) * 8u + (unsigned)s] = w;

            // fused step 1: same sdot8 form the steps use (A row . Hq0[src])
            int dd = dot8i4(w, hq.x, 0);
            float rdg = __builtin_amdgcn_rcpf((float)((int)(m >> 21) + 1));
            accD = fmaf((float)dd, __uint_as_float(hq.y) * rdg, accD);
        }
    }
    // reduce over el lanes (lane = el*8 + s)
    accD += __shfl_xor(accD, 8);  accD += __shfl_xor(accD, 16); accD += __shfl_xor(accD, 32);
    float h1v = accD * K7 + Bsum[v * 8 + s];

    // quantize H1 row to int4 with per-node scale
    float mx = fabsf(h1v);
    mx = fmaxf(mx, __shfl_xor(mx, 1));
    mx = fmaxf(mx, __shfl_xor(mx, 2));
    mx = fmaxf(mx, __shfl_xor(mx, 4));           // max over s within el group
    float si = (mx > 0.0f) ? 7.0f / mx : 0.0f;
    unsigned nib = (unsigned)((int)rintf(h1v * si)) & 0xFu;
    unsigned b1 = __shfl(nib, lane + 1), b2 = __shfl(nib, lane + 2), b3 = __shfl(nib, lane + 3);
    unsigned b4 = __shfl(nib, lane + 4), b5 = __shfl(nib, lane + 5);
    unsigned b6 = __shfl(nib, lane + 6), b7 = __shfl(nib, lane + 7);
    if (lane == 0) {
        unsigned w = nib | (b1 << 4) | (b2 << 8) | (b3 << 12)
                   | (b4 << 16) | (b5 << 20) | (b6 << 24) | (b7 << 28);
        HqOut[v] = make_uint2(w, __float_as_uint(mx * (1.0f / 7.0f)));
    }
}

// ---------------------------------------------------------------------------
// Light step, QUAD-PER-NODE, int4: per edge lane q reads uint2 (rows 2q,
// 2q+1, 8B of the 32B row-block), Hq uint2 broadcast. 2 sdot8 + rcp(dg)
// per lane-edge. Runs 3x.
// ---------------------------------------------------------------------------
__global__ __launch_bounds__(256) void step_kernel(
    const uint2* __restrict__ HqIn, uint2* __restrict__ HqOut,
    const unsigned* __restrict__ pmeta, const int* __restrict__ rowptr,
    const unsigned* __restrict__ A4, const float* __restrict__ Bsum,
    const float* __restrict__ W1, const float* __restrict__ b1,
    float* __restrict__ logitsOut, float* __restrict__ HfpOut)
{
    int v = blockIdx.x * 64 + (threadIdx.x >> 2);
    if (v >= V) return;
    int q = threadIdx.x & 3;

    int p0 = rowptr[v], p1 = rowptr[v + 1];

    float accE = 0.0f, accO = 0.0f;
    for (int p = p0; p < p1; ++p) {
        unsigned m = pmeta[p];                 // broadcast within quad
        int src = (int)(m & 0x1FFFFu);
        uint2 au = *(const uint2*)(A4 + (unsigned)p * 8u + (unsigned)(q * 2));
        uint2 hq = HqIn[src];                  // broadcast within quad
        int dE = dot8i4(au.x, hq.x, 0);
        int dO = dot8i4(au.y, hq.x, 0);
        float rdg = __builtin_amdgcn_rcpf((float)((int)(m >> 21) + 1));
        float sc = __uint_as_float(hq.y) * rdg;
        accE = fmaf((float)dE, sc, accE);
        accO = fmaf((float)dO, sc, accO);
    }

    float hE = accE * K7 + Bsum[v * 8 + q * 2];
    float hO = accO * K7 + Bsum[v * 8 + q * 2 + 1];

    // quantize H row to int4 with per-node scale (reduce within quad only)
    float mx = fmaxf(fabsf(hE), fabsf(hO));
    mx = fmaxf(mx, __shfl_xor(mx, 1));
    mx = fmaxf(mx, __shfl_xor(mx, 2));
    float si = (mx > 0.0f) ? 7.0f / mx : 0.0f;
    unsigned nE = (unsigned)((int)rintf(hE * si)) & 0xFu;
    unsigned nO = (unsigned)((int)rintf(hO * si)) & 0xFu;
    unsigned wq = (nE | (nO << 4)) << (8 * q); // nibbles 2q, 2q+1
    wq |= __shfl_xor(wq, 1);
    wq |= __shfl_xor(wq, 2);
    if (q == 0)
        HqOut[v] = make_uint2(wq, __float_as_uint(mx * (1.0f / 7.0f)));
    if (HfpOut != nullptr)
        *(float2*)(HfpOut + v * 8 + q * 2) = make_float2(hE, hO);
    if (logitsOut != nullptr) {
        float t = hE * W1[q * 2] + hO * W1[q * 2 + 1];
        t += __shfl_xor(t, 1); t += __shfl_xor(t, 2);
        if (q == 0) logitsOut[v] = t + b1[0];
    }
}

// ---------------------------------------------------------------------------
// Epilogue
// ---------------------------------------------------------------------------
__global__ __launch_bounds__(256) void reduce_max_kernel(
    const float* __restrict__ logits, float* __restrict__ partial)
{
    float m = -INFINITY;
    for (int v = blockIdx.x * 256 + threadIdx.x; v < V; v += 256 * 256)
        m = fmaxf(m, logits[v]);
    #pragma unroll
    for (int o = 32; o > 0; o >>= 1) m = fmaxf(m, __shfl_down(m, o));
    __shared__ float sm[4];
    if ((threadIdx.x & 63) == 0) sm[threadIdx.x >> 6] = m;
    __syncthreads();
    if (threadIdx.x == 0)
        partial[blockIdx.x] = fmaxf(fmaxf(sm[0], sm[1]), fmaxf(sm[2], sm[3]));
}

__global__ __launch_bounds__(256) void final_max_kernel(
    const float* __restrict__ partial, float* __restrict__ M)
{
    float m = partial[threadIdx.x];
    #pragma unroll
    for (int o = 32; o > 0; o >>= 1) m = fmaxf(m, __shfl_down(m, o));
    __shared__ float sm[4];
    if ((threadIdx.x & 63) == 0) sm[threadIdx.x >> 6] = m;
    __syncthreads();
    if (threadIdx.x == 0) *M = fmaxf(fmaxf(sm[0], sm[1]), fmaxf(sm[2], sm[3]));
}

// Stage 1: 64 blocks write per-block partials (9 floats each) — no atomics.
__global__ __launch_bounds__(256) void sum_kernel(
    const float* __restrict__ H, const float* __restrict__ logits,
    const float* __restrict__ Mp, float* __restrict__ partial)
{
    const float M = *Mp;
    float se = 0.0f;
    float sh[8] = {0, 0, 0, 0, 0, 0, 0, 0};
    for (int v = blockIdx.x * 256 + threadIdx.x; v < V; v += 64 * 256) {
        float w = __expf(logits[v] - M);
        se += w;
        const float4* H4 = (const float4*)(H + (size_t)v * 8);
        float4 h0 = H4[0], h1 = H4[1];
        sh[0] += w * h0.x; sh[1] += w * h0.y; sh[2] += w * h0.z; sh[3] += w * h0.w;
        sh[4] += w * h1.x; sh[5] += w * h1.y; sh[6] += w * h1.z; sh[7] += w * h1.w;
    }
    #pragma unroll
    for (int o = 32; o > 0; o >>= 1) {
        se += __shfl_xor(se, o);
        #pragma unroll
        for (int i = 0; i < 8; ++i) sh[i] += __shfl_xor(sh[i], o);
    }
    __shared__ float sm[4][9];
    int wv = threadIdx.x >> 6;
    if ((threadIdx.x & 63) == 0) {
        sm[wv][8] = se;
        #pragma unroll
        for (int i = 0; i < 8; ++i) sm[wv][i] = sh[i];
    }
    __syncthreads();
    if (threadIdx.x == 0) {
        #pragma unroll
        for (int i = 0; i < 9; ++i)
            partial[blockIdx.x * 12 + i] = sm[0][i] + sm[1][i] + sm[2][i] + sm[3][i];
    }
}

__global__ void final_kernel(const float* __restrict__ partial, float* __restrict__ out)
{
    int lane = threadIdx.x;               // 64 threads
    float vals[9];
    #pragma unroll
    for (int i = 0; i < 9; ++i) vals[i] = partial[lane * 12 + i];
    #pragma unroll
    for (int o = 1; o < 64; o <<= 1) {
        #pragma unroll
        for (int i = 0; i < 9; ++i) vals[i] += __shfl_xor(vals[i], o);
    }
    __shared__ float res[9];
    if (lane == 0) {
        #pragma unroll
        for (int i = 0; i < 9; ++i) res[i] = vals[i];
    }
    __syncthreads();
    if (lane < 8) out[lane] = tanhf(res[lane] / res[8]);
}

// ---------------------------------------------------------------------------
extern "C" void kernel_launch(void* const* d_in, const int* in_sizes, int n_in,
                              void* d_out, int out_size, void* d_ws, size_t ws_size,
                              hipStream_t stream)
{
    const float* feat  = (const float*)d_in[0];
    const int*   xnode = (const int*)d_in[1];
    const int*   xneis = (const int*)d_in[2];
    const int*   etype = (const int*)d_in[3];
    const float* dg    = (const float*)d_in[4];
    const float* Hinit = (const float*)d_in[5];
    const float* Wxi   = (const float*)d_in[6];
    const float* bxi   = (const float*)d_in[7];
    const float* Wrou  = (const float*)d_in[8];
    const float* brou  = (const float*)d_in[9];
    const float* W1    = (const float*)d_in[10];
    const float* b1    = (const float*)d_in[11];

    char* ws = (char*)d_ws;
    auto alloc = [&](size_t bytes) -> char* {
        char* p = ws; ws += (bytes + 255) & ~(size_t)255; return p;
    };
    unsigned* A4      = (unsigned*)alloc((size_t)E * 32);      // 51.2 MB int4 A
    unsigned char* P8 = (unsigned char*)alloc((size_t)V * 64); // 6.4 MB int8 P
    ushort*   Qb      = (ushort*)alloc((size_t)V * 64 * 2);    // 12.8 MB bf16 Q
    unsigned* pmeta   = (unsigned*)alloc((size_t)E * 4);       // 6.4 MB CSR meta
    int*      rank0   = (int*)alloc((size_t)E * 4);            // 6.4 MB per-edge rank
    int*      countg  = (int*)alloc((size_t)GN * V * 4);       // 3.2 MB XCD-local counts
    int*      offg    = (int*)alloc((size_t)GN * V * 4);       // 3.2 MB group offsets
    int*      cnt     = (int*)alloc((size_t)V * 4);            // per-node count
    int*      scanned = (int*)alloc((size_t)V * 4);
    int*      rowptr  = (int*)alloc((size_t)(V + 1) * 4);
    int*      bsumT   = (int*)alloc(512 * 4);
    int*      topsT   = (int*)alloc(512 * 4);
    uint2*    Hq0     = (uint2*)alloc((size_t)V * 8);          // int4 Hinit + scale
    uint2*    HqA     = (uint2*)alloc((size_t)V * 8);
    uint2*    HqB     = (uint2*)alloc((size_t)V * 8);
    float*    Hfp     = (float*)alloc((size_t)V * 8 * 4);      // fp32 H (last step)
    float*    Bsum    = (float*)alloc((size_t)V * 8 * 4);
    float*    logits  = (float*)alloc((size_t)V * 4);
    float*    pmax    = (float*)alloc(256 * 4);
    float*    Mp      = (float*)alloc(16);
    float*    spart   = (float*)alloc(64 * 12 * 4);

    hipMemsetAsync(countg, 0, (size_t)GN * V * 4, stream);
    histg_kernel<<<(E + 255) / 256, 256, 0, stream>>>(xneis, countg, rank0);
    scanV_kernel<<<NB, 256, 0, stream>>>(countg, offg, cnt, scanned, bsumT);
    scan_tops_kernel<<<1, 512, 0, stream>>>(bsumT, topsT, rowptr);
    add_offsets_kernel<<<NB, 256, 0, stream>>>(scanned, topsT, rowptr);
    scatter_kernel<<<(E + 255) / 256, 256, 0, stream>>>(xnode, xneis, etype, dg,
                                                        rowptr, offg, rank0, pmeta);
    pq_kernel<<<(V / 16 + 3) / 4, 256, 0, stream>>>(feat, Wxi, P8, Qb);
    bsum_kernel<<<NB, 256, 0, stream>>>(feat, cnt, Wrou, brou, Hinit,
                                        Bsum, Hq0);
    // amat + fused step 1: writes int4 A and int4 H1 in one pass
    amat_kernel<<<(V + 3) / 4, 256, 0, stream>>>(pmeta, rowptr, P8, Qb, Wxi, bxi,
                                                 Hq0, Bsum, A4, HqA);

    // steps 2..4 (quad-per-node, int4)
    const uint2* Hcur = HqA;
    uint2* bufs[2] = {HqB, HqA};
    for (int t = 0; t < 3; ++t) {
        uint2* Hn = bufs[t & 1];
        float* lg  = (t == 2) ? logits : nullptr;
        float* hf  = (t == 2) ? Hfp : nullptr;
        step_kernel<<<(V + 63) / 64, 256, 0, stream>>>(Hcur, Hn, pmeta, rowptr,
                                                       A4, Bsum, W1, b1, lg, hf);
        Hcur = Hn;
    }

    reduce_max_kernel<<<256, 256, 0, stream>>>(logits, pmax);
    final_max_kernel<<<1, 256, 0, stream>>>(pmax, Mp);
    sum_kernel<<<64, 256, 0, stream>>>(Hfp, logits, Mp, spart);
    final_kernel<<<1, 64, 0, stream>>>(spart, (float*)d_out);
}

// Round 9
// 427.681 us; speedup vs baseline: 1.0741x; 1.0056x over previous
//
#include <hip/hip_runtime.h>
#include <hip/hip_bf16.h>

constexpr int V   = 100000;
constexpr int E   = 1600000;
constexpr int NET = 10;
constexpr int KXW = 138;              // W_xi row length (2*64+10)
constexpr int NB  = (V + 255) / 256;  // 391 blocks over nodes
constexpr int GN  = 8;                // count groups (= XCDs)
constexpr int NEB = E / 256;          // 6250 edge blocks (exact)
constexpr float MUS   = 0.1125f;      // MU / S
constexpr float SP    = 0.025f;       // int8 P scale
constexpr float LOG2E = 1.44269504f;
constexpr float S2L   = 2.0f * SP * LOG2E;   // int8 P step in exp2 domain
constexpr float K7    = MUS / 7.0f;          // int4 A decode scale (x 1/dg per edge)

typedef __attribute__((ext_vector_type(8))) short short8;
typedef __attribute__((ext_vector_type(4))) float float4v;

__device__ __forceinline__ float fast_tanh(float x) {
    return 1.0f - 2.0f * __builtin_amdgcn_rcpf(__expf(2.0f * x) + 1.0f);
}
__device__ __forceinline__ float bflo(unsigned u) { return __uint_as_float(u << 16); }
__device__ __forceinline__ float bfhi(unsigned u) { return __uint_as_float(u & 0xffff0000u); }
__device__ __forceinline__ short f2bf(float x) {
    union { __hip_bfloat16 b; short s; } u; u.b = __float2bfloat16(x); return u.s;
}

__device__ __forceinline__ float ub0(unsigned u) {
#if __has_builtin(__builtin_amdgcn_cvt_f32_ubyte0)
    return __builtin_amdgcn_cvt_f32_ubyte0(u);
#else
    return (float)(u & 0xff);
#endif
}
__device__ __forceinline__ float ub1(unsigned u) {
#if __has_builtin(__builtin_amdgcn_cvt_f32_ubyte1)
    return __builtin_amdgcn_cvt_f32_ubyte1(u);
#else
    return (float)((u >> 8) & 0xff);
#endif
}
__device__ __forceinline__ float ub2(unsigned u) {
#if __has_builtin(__builtin_amdgcn_cvt_f32_ubyte2)
    return __builtin_amdgcn_cvt_f32_ubyte2(u);
#else
    return (float)((u >> 16) & 0xff);
#endif
}
__device__ __forceinline__ float ub3(unsigned u) {
#if __has_builtin(__builtin_amdgcn_cvt_f32_ubyte3)
    return __builtin_amdgcn_cvt_f32_ubyte3(u);
#else
    return (float)(u >> 24);
#endif
}

// int4 dot8: D = sum of 8 signed-nibble products + C (v_dot8_i32_i4)
__device__ __forceinline__ int dot8i4(unsigned a, unsigned b, int c) {
#if __has_builtin(__builtin_amdgcn_sdot8)
    return __builtin_amdgcn_sdot8((int)a, (int)b, c, false);
#else
    int r = c;
    #pragma unroll
    for (int j = 0; j < 8; ++j) {
        int av = ((int)(a << (28 - 4 * j))) >> 28;
        int bv = ((int)(b << (28 - 4 * j))) >> 28;
        r += av * bv;
    }
    return r;
#endif
}

// ---------------------------------------------------------------------------
// XCD-local histogram + per-edge rank within (group, node). g = blockIdx&7.
// ONE atomic pass total. (R6-R8 tripwire-proven build path, unchanged.)
// ---------------------------------------------------------------------------
__global__ __launch_bounds__(256) void histg_kernel(
    const int* __restrict__ xneis, int* __restrict__ countg,
    int* __restrict__ rank0)
{
    int e = blockIdx.x * 256 + threadIdx.x;
    if (e >= E) return;
    int g = blockIdx.x & (GN - 1);
    int nr = xneis[e];
    if (nr < V) rank0[e] = atomicAdd(&countg[g * V + nr], 1);
}

// Fold group slices (offg, cnt_tot) + blockwise-exclusive scan, fused.
__global__ __launch_bounds__(256) void scanV_kernel(
    const int* __restrict__ countg, int* __restrict__ offg,
    int* __restrict__ cnt_tot, int* __restrict__ scanned, int* __restrict__ bsum)
{
    __shared__ int s[256];
    int tid = threadIdx.x;
    int i = blockIdx.x * 256 + tid;
    int c = 0;
    if (i < V) {
        int run = 0;
        #pragma unroll
        for (int g = 0; g < GN; ++g) {
            offg[g * V + i] = run;
            run += countg[g * V + i];
        }
        cnt_tot[i] = run;
        c = run;
    }
    s[tid] = c; __syncthreads();
    #pragma unroll
    for (int off = 1; off < 256; off <<= 1) {
        int t = (tid >= off) ? s[tid - off] : 0;
        __syncthreads();
        s[tid] += t;
        __syncthreads();
    }
    if (i < V) scanned[i] = s[tid] - c;
    if (tid == 255) bsum[blockIdx.x] = s[255];
}

__global__ __launch_bounds__(512) void scan_tops_kernel(
    const int* __restrict__ blocksum, int* __restrict__ tops, int* __restrict__ rowptr)
{
    __shared__ int s[512];
    int tid = threadIdx.x;
    int v = (tid < NB) ? blocksum[tid] : 0;
    s[tid] = v; __syncthreads();
    #pragma unroll
    for (int off = 1; off < 512; off <<= 1) {
        int t = (tid >= off) ? s[tid - off] : 0;
        __syncthreads();
        s[tid] += t;
        __syncthreads();
    }
    if (tid < NB) tops[tid] = s[tid] - v;        // exclusive
    if (tid == 511) rowptr[V] = s[511];          // total kept edges
}

__global__ __launch_bounds__(256) void add_offsets_kernel(
    const int* __restrict__ scanned, const int* __restrict__ tops, int* __restrict__ rowptr)
{
    int i = blockIdx.x * 256 + threadIdx.x;
    if (i < V) rowptr[i] = scanned[i] + tops[blockIdx.x];
}

// ---------------------------------------------------------------------------
// Two-hop scatter, deterministic, no global atomics.
// Hop A: compute final slot p (rowptr+offg+rank0, same as R8), bucket the
// (p, meta) pair by p-range r = p>>18. In-block placement: in-wave rank via
// ballot prefix + per-block per-range LDS scan (all deterministic). Writes
// are dense bursts. Per-(block,range) capacity 256 is structurally safe.
// meta word: src (17 b) | et (4 b) | dg-1 (6 b)
// ---------------------------------------------------------------------------
__global__ __launch_bounds__(256) void scatterA_kernel(
    const int* __restrict__ xnode, const int* __restrict__ xneis,
    const int* __restrict__ etype, const float* __restrict__ dg,
    const int* __restrict__ rowptr, const int* __restrict__ offg,
    const int* __restrict__ rank0, uint2* __restrict__ buc,
    int* __restrict__ bcnt)
{
    __shared__ int wcnt[4][8];
    __shared__ int woff[4][8];
    int tid = threadIdx.x;
    int lane = tid & 63, wv = tid >> 6;
    int e = blockIdx.x * 256 + tid;              // E = 6250*256 exact
    int g = blockIdx.x & (GN - 1);

    int nr = xneis[e];
    bool keep = (nr < V);
    int p = -1, r = 0;
    if (keep) {
        p = rowptr[nr] + offg[g * V + nr] + rank0[e];
        r = p >> 18;                             // 0..7 since kept edges < 2^21
    }

    // in-wave rank among same-range lanes (deterministic)
    unsigned rnk = 0;
    #pragma unroll
    for (int r8 = 0; r8 < 8; ++r8) {
        unsigned long long m = __ballot(keep && (r == r8));
        if (keep && r == r8)
            rnk = (unsigned)__popcll(m & ((1ull << lane) - 1ull));
        if (lane == 0) wcnt[wv][r8] = (int)__popcll(m);
    }
    __syncthreads();
    if (tid < 8) {
        int run = 0;
        #pragma unroll
        for (int w = 0; w < 4; ++w) { woff[w][tid] = run; run += wcnt[w][tid]; }
        bcnt[blockIdx.x * 8 + tid] = run;
    }
    __syncthreads();

    if (keep) {
        unsigned src = (unsigned)(xnode[e] - 1);
        unsigned et  = (unsigned)(etype[e] - 1);
        unsigned dgi = (unsigned)dg[e] - 1;      // 0..63, exact
        unsigned meta = src | (et << 17) | (dgi << 21);
        int slot = blockIdx.x * 2048 + r * 256 + woff[wv][r] + (int)rnk;
        buc[slot] = make_uint2((unsigned)p, meta);
    }
}

// Hop B: blocks with blockIdx&7==r drain range r (XCD-local pmeta window ->
// full-line L2 assembly, ~6.4 MB writeback instead of ~100 MB). Output is
// order-independent: pmeta[p] = meta with unique p.
__global__ __launch_bounds__(256) void drain_kernel(
    const uint2* __restrict__ buc, const int* __restrict__ bcnt,
    unsigned* __restrict__ pmeta)
{
    int r = blockIdx.x & 7;
    int nstride = (int)(gridDim.x >> 3);
    for (int sb = (int)(blockIdx.x >> 3); sb < NEB; sb += nstride) {
        int c = bcnt[sb * 8 + r];
        const uint2* seg = buc + (size_t)sb * 2048 + r * 256;
        for (int i = threadIdx.x; i < c; i += 256) {
            uint2 t = seg[i];
            pmeta[t.x] = t.y;
        }
    }
}

// ---------------------------------------------------------------------------
// Per-node bias sum + int4-quantized Hinit (Hq0: 8 nibbles + fp32 scale).
// ---------------------------------------------------------------------------
__global__ __launch_bounds__(256) void bsum_kernel(
    const float* __restrict__ feat, const int* __restrict__ count,
    const float* __restrict__ Wrou, const float* __restrict__ brou,
    const float* __restrict__ Hinit, float* __restrict__ Bsum,
    uint2* __restrict__ Hq0)
{
    __shared__ float Wl[512];
    __shared__ float bl[8];
    int tid = threadIdx.x;
    for (int i = tid; i < 512; i += 256) Wl[i] = Wrou[i];
    if (tid < 8) bl[tid] = brou[tid];
    __syncthreads();

    int v = blockIdx.x * 256 + tid;
    if (v >= V) return;
    int c = count[v];
    float out[8] = {0, 0, 0, 0, 0, 0, 0, 0};
    if (c > 0) {                                  // c>0 implies v >= 1
        const float4* f4 = (const float4*)(feat + (size_t)(v - 1) * 64);
        float acc[8];
        #pragma unroll
        for (int s = 0; s < 8; ++s) acc[s] = bl[s];
        #pragma unroll 4
        for (int k = 0; k < 16; ++k) {
            float4 x = f4[k];
            #pragma unroll
            for (int s = 0; s < 8; ++s) {
                const float* w = &Wl[s * 64 + k * 4];
                acc[s] += x.x * w[0] + x.y * w[1] + x.z * w[2] + x.w * w[3];
            }
        }
        float fc = (float)c;
        #pragma unroll
        for (int s = 0; s < 8; ++s) out[s] = fc * fast_tanh(acc[s]);
    }
    float4* O = (float4*)(Bsum + (size_t)v * 8);
    O[0] = make_float4(out[0], out[1], out[2], out[3]);
    O[1] = make_float4(out[4], out[5], out[6], out[7]);

    // quantize Hinit row to int4 nibbles + per-node scale
    const float4* Hh4 = (const float4*)(Hinit + (size_t)v * 8);
    float4 h0 = Hh4[0], h1 = Hh4[1];
    float hv[8] = {h0.x, h0.y, h0.z, h0.w, h1.x, h1.y, h1.z, h1.w};
    float mx = 0.0f;
    #pragma unroll
    for (int i = 0; i < 8; ++i) mx = fmaxf(mx, fabsf(hv[i]));
    float si = (mx > 0.0f) ? 7.0f / mx : 0.0f;
    unsigned w = 0;
    #pragma unroll
    for (int i = 0; i < 8; ++i)
        w |= ((unsigned)((int)rintf(hv[i] * si)) & 0xFu) << (4 * i);
    Hq0[v] = make_uint2(w, __float_as_uint(mx * (1.0f / 7.0f)));
}

// ---------------------------------------------------------------------------
// PQ GEMM (MFMA): P[v] -> int8 biased (6.4 MB), Q[v] -> bf16 (12.8 MB)
// ---------------------------------------------------------------------------
__global__ __launch_bounds__(256) void pq_kernel(
    const float* __restrict__ feat, const float* __restrict__ Wxi,
    unsigned char* __restrict__ P8, ushort* __restrict__ Qb)
{
    const int lane = threadIdx.x & 63, wave = threadIdx.x >> 6;
    const int quad = lane >> 4, l16 = lane & 15;

    short8 bP[4][2], bQ[4][2];
    #pragma unroll
    for (int nt = 0; nt < 4; ++nt) {
        #pragma unroll
        for (int ks = 0; ks < 2; ++ks) {
            const float* wp = Wxi + (size_t)(nt * 16 + l16) * KXW + ks * 32 + quad * 8;
            short8 p, q;
            #pragma unroll
            for (int j = 0; j < 8; ++j) { p[j] = f2bf(wp[j]); q[j] = f2bf(wp[64 + j]); }
            bP[nt][ks] = p; bQ[nt][ks] = q;
        }
    }

    int t = blockIdx.x * 4 + wave;
    if (t >= V / 16) return;
    int v0 = t * 16;

    const float* fp = feat + (size_t)(v0 + l16) * 64 + quad * 8;
    short8 a0, a1;
    #pragma unroll
    for (int j = 0; j < 8; ++j) { a0[j] = f2bf(fp[j]); a1[j] = f2bf(fp[32 + j]); }

    float4v accP[4], accQ[4];
    #pragma unroll
    for (int nt = 0; nt < 4; ++nt) {
        float4v z = {0.f, 0.f, 0.f, 0.f};
        z = __builtin_amdgcn_mfma_f32_16x16x32_bf16(a0, bP[nt][0], z, 0, 0, 0);
        z = __builtin_amdgcn_mfma_f32_16x16x32_bf16(a1, bP[nt][1], z, 0, 0, 0);
        accP[nt] = z;
        float4v w = {0.f, 0.f, 0.f, 0.f};
        w = __builtin_amdgcn_mfma_f32_16x16x32_bf16(a0, bQ[nt][0], w, 0, 0, 0);
        w = __builtin_amdgcn_mfma_f32_16x16x32_bf16(a1, bQ[nt][1], w, 0, 0, 0);
        accQ[nt] = w;
    }

    #pragma unroll
    for (int r = 0; r < 4; ++r) {
        int row = v0 + quad * 4 + r;
        #pragma unroll
        for (int nt = 0; nt < 4; ++nt) {
            int col = nt * 16 + l16;
            int q8 = (int)rintf(accP[nt][r] * (1.0f / SP)) + 128;
            q8 = min(max(q8, 0), 255);
            P8[row * 64 + col] = (unsigned char)q8;
            Qb[row * 64 + col] = (ushort)f2bf(accQ[nt][r]);
        }
    }
}

// ---------------------------------------------------------------------------
// FUSED A materialization + STEP 1. A stored INT4 (R8-proven).
// ---------------------------------------------------------------------------
__global__ __launch_bounds__(256) void amat_kernel(
    const unsigned* __restrict__ pmeta, const int* __restrict__ rowptr,
    const unsigned char* __restrict__ P8, const ushort* __restrict__ Qb,
    const float* __restrict__ Wxi, const float* __restrict__ bxi,
    const uint2* __restrict__ Hq0, const float* __restrict__ Bsum,
    unsigned* __restrict__ A4, uint2* __restrict__ HqOut)
{
    __shared__ float Wet2[NET * 64];     // 2*log2e*(Wxi[n][128+et]+bxi[n])
    int tid = threadIdx.x;
    for (int i = tid; i < NET * 64; i += 256) {
        int et = i >> 6, n = i & 63;
        Wet2[i] = 2.0f * LOG2E * (Wxi[n * KXW + 128 + et] + bxi[n]);
    }
    __syncthreads();

    int v = blockIdx.x * 4 + (tid >> 6);
    if (v >= V) return;
    int lane = tid & 63;
    int el = lane >> 3, s = lane & 7;

    const int off = rowptr[v];
    const int deg = rowptr[v + 1] - off;

    float q0, q1, q2, q3, q4, q5, q6, q7;
    {
        uint4 qu = *(const uint4*)(Qb + v * 64 + s * 8);
        const float B = 128.0f * SP, C = 2.0f * LOG2E;
        q0 = C * (bflo(qu.x) - B); q1 = C * (bfhi(qu.x) - B);
        q2 = C * (bflo(qu.y) - B); q3 = C * (bfhi(qu.y) - B);
        q4 = C * (bflo(qu.z) - B); q5 = C * (bfhi(qu.z) - B);
        q6 = C * (bflo(qu.w) - B); q7 = C * (bfhi(qu.w) - B);
    }

    float accD = 0.0f;                    // fused step-1 accumulator

    for (int base = 0; base < deg; base += 64) {
        // phase 1: this lane resolves edge (base+lane) — fully coalesced
        unsigned m_mine = 0;
        {
            int i1 = base + lane;
            if (i1 < deg) m_mine = pmeta[off + i1];
        }
        // phase 2: 8 edges per sub-round, meta via shfl broadcast
        int nb = deg - base;
        for (int k = 0; k * 8 + el < nb && k < 8; ++k) {
            int ib = k * 8 + el;
            int i = base + ib;
            unsigned m = __shfl(m_mine, ib);
            int src = (int)(m & 0x1FFFF);
            int et  = (int)((m >> 17) & 0xF);

            // issue all loads up front so they overlap the exp chain
            uint2 pu = *(const uint2*)(P8 + src * 64 + s * 8);
            const float4* w4 = (const float4*)(&Wet2[et * 64 + s * 8]);
            float4 wa = w4[0], wb = w4[1];
            uint2 hq = Hq0[src];

            float r0 = __builtin_amdgcn_rcpf(__builtin_amdgcn_exp2f(fmaf(ub0(pu.x), S2L, q0 + wa.x)) + 1.0f);
            float r1 = __builtin_amdgcn_rcpf(__builtin_amdgcn_exp2f(fmaf(ub1(pu.x), S2L, q1 + wa.y)) + 1.0f);
            float r2 = __builtin_amdgcn_rcpf(__builtin_amdgcn_exp2f(fmaf(ub2(pu.x), S2L, q2 + wa.z)) + 1.0f);
            float r3 = __builtin_amdgcn_rcpf(__builtin_amdgcn_exp2f(fmaf(ub3(pu.x), S2L, q3 + wa.w)) + 1.0f);
            float r4 = __builtin_amdgcn_rcpf(__builtin_amdgcn_exp2f(fmaf(ub0(pu.y), S2L, q4 + wb.x)) + 1.0f);
            float r5 = __builtin_amdgcn_rcpf(__builtin_amdgcn_exp2f(fmaf(ub1(pu.y), S2L, q5 + wb.y)) + 1.0f);
            float r6 = __builtin_amdgcn_rcpf(__builtin_amdgcn_exp2f(fmaf(ub2(pu.y), S2L, q6 + wb.z)) + 1.0f);
            float r7 = __builtin_amdgcn_rcpf(__builtin_amdgcn_exp2f(fmaf(ub3(pu.y), S2L, q7 + wb.w)) + 1.0f);

            // n = round(7*tanh) = round(7 - 14*r), in [-7,7]
            int n0 = (int)rintf(fmaf(r0, -14.0f, 7.0f));
            int n1 = (int)rintf(fmaf(r1, -14.0f, 7.0f));
            int n2 = (int)rintf(fmaf(r2, -14.0f, 7.0f));
            int n3 = (int)rintf(fmaf(r3, -14.0f, 7.0f));
            int n4 = (int)rintf(fmaf(r4, -14.0f, 7.0f));
            int n5 = (int)rintf(fmaf(r5, -14.0f, 7.0f));
            int n6 = (int)rintf(fmaf(r6, -14.0f, 7.0f));
            int n7 = (int)rintf(fmaf(r7, -14.0f, 7.0f));

            unsigned w = ((unsigned)n0 & 0xFu)        | (((unsigned)n1 & 0xFu) << 4)
                       | (((unsigned)n2 & 0xFu) << 8)  | (((unsigned)n3 & 0xFu) << 12)
                       | (((unsigned)n4 & 0xFu) << 16) | (((unsigned)n5 & 0xFu) << 20)
                       | (((unsigned)n6 & 0xFu) << 24) | (((unsigned)n7 & 0xFu) << 28);
            A4[(unsigned)(off + i) * 8u + (unsigned)s] = w;

            // fused step 1: same sdot8 form the steps use (A row . Hq0[src])
            int dd = dot8i4(w, hq.x, 0);
            float rdg = __builtin_amdgcn_rcpf((float)((int)(m >> 21) + 1));
            accD = fmaf((float)dd, __uint_as_float(hq.y) * rdg, accD);
        }
    }
    // reduce over el lanes (lane = el*8 + s)
    accD += __shfl_xor(accD, 8);  accD += __shfl_xor(accD, 16); accD += __shfl_xor(accD, 32);
    float h1v = accD * K7 + Bsum[v * 8 + s];

    // quantize H1 row to int4 with per-node scale
    float mx = fabsf(h1v);
    mx = fmaxf(mx, __shfl_xor(mx, 1));
    mx = fmaxf(mx, __shfl_xor(mx, 2));
    mx = fmaxf(mx, __shfl_xor(mx, 4));           // max over s within el group
    float si = (mx > 0.0f) ? 7.0f / mx : 0.0f;
    unsigned nib = (unsigned)((int)rintf(h1v * si)) & 0xFu;
    unsigned b1 = __shfl(nib, lane + 1), b2 = __shfl(nib, lane + 2), b3 = __shfl(nib, lane + 3);
    unsigned b4 = __shfl(nib, lane + 4), b5 = __shfl(nib, lane + 5);
    unsigned b6 = __shfl(nib, lane + 6), b7 = __shfl(nib, lane + 7);
    if (lane == 0) {
        unsigned w = nib | (b1 << 4) | (b2 << 8) | (b3 << 12)
                   | (b4 << 16) | (b5 << 20) | (b6 << 24) | (b7 << 28);
        HqOut[v] = make_uint2(w, __float_as_uint(mx * (1.0f / 7.0f)));
    }
}

// ---------------------------------------------------------------------------
// Light step, QUAD-PER-NODE, int4 (R8-proven). Runs 3x.
// ---------------------------------------------------------------------------
__global__ __launch_bounds__(256) void step_kernel(
    const uint2* __restrict__ HqIn, uint2* __restrict__ HqOut,
    const unsigned* __restrict__ pmeta, const int* __restrict__ rowptr,
    const unsigned* __restrict__ A4, const float* __restrict__ Bsum,
    const float* __restrict__ W1, const float* __restrict__ b1,
    float* __restrict__ logitsOut, float* __restrict__ HfpOut)
{
    int v = blockIdx.x * 64 + (threadIdx.x >> 2);
    if (v >= V) return;
    int q = threadIdx.x & 3;

    int p0 = rowptr[v], p1 = rowptr[v + 1];

    float accE = 0.0f, accO = 0.0f;
    for (int p = p0; p < p1; ++p) {
        unsigned m = pmeta[p];                 // broadcast within quad
        int src = (int)(m & 0x1FFFFu);
        uint2 au = *(const uint2*)(A4 + (unsigned)p * 8u + (unsigned)(q * 2));
        uint2 hq = HqIn[src];                  // broadcast within quad
        int dE = dot8i4(au.x, hq.x, 0);
        int dO = dot8i4(au.y, hq.x, 0);
        float rdg = __builtin_amdgcn_rcpf((float)((int)(m >> 21) + 1));
        float sc = __uint_as_float(hq.y) * rdg;
        accE = fmaf((float)dE, sc, accE);
        accO = fmaf((float)dO, sc, accO);
    }

    float hE = accE * K7 + Bsum[v * 8 + q * 2];
    float hO = accO * K7 + Bsum[v * 8 + q * 2 + 1];

    // quantize H row to int4 with per-node scale (reduce within quad only)
    float mx = fmaxf(fabsf(hE), fabsf(hO));
    mx = fmaxf(mx, __shfl_xor(mx, 1));
    mx = fmaxf(mx, __shfl_xor(mx, 2));
    float si = (mx > 0.0f) ? 7.0f / mx : 0.0f;
    unsigned nE = (unsigned)((int)rintf(hE * si)) & 0xFu;
    unsigned nO = (unsigned)((int)rintf(hO * si)) & 0xFu;
    unsigned wq = (nE | (nO << 4)) << (8 * q); // nibbles 2q, 2q+1
    wq |= __shfl_xor(wq, 1);
    wq |= __shfl_xor(wq, 2);
    if (q == 0)
        HqOut[v] = make_uint2(wq, __float_as_uint(mx * (1.0f / 7.0f)));
    if (HfpOut != nullptr)
        *(float2*)(HfpOut + v * 8 + q * 2) = make_float2(hE, hO);
    if (logitsOut != nullptr) {
        float t = hE * W1[q * 2] + hO * W1[q * 2 + 1];
        t += __shfl_xor(t, 1); t += __shfl_xor(t, 2);
        if (q == 0) logitsOut[v] = t + b1[0];
    }
}

// ---------------------------------------------------------------------------
// Epilogue
// ---------------------------------------------------------------------------
__global__ __launch_bounds__(256) void reduce_max_kernel(
    const float* __restrict__ logits, float* __restrict__ partial)
{
    float m = -INFINITY;
    for (int v = blockIdx.x * 256 + threadIdx.x; v < V; v += 256 * 256)
        m = fmaxf(m, logits[v]);
    #pragma unroll
    for (int o = 32; o > 0; o >>= 1) m = fmaxf(m, __shfl_down(m, o));
    __shared__ float sm[4];
    if ((threadIdx.x & 63) == 0) sm[threadIdx.x >> 6] = m;
    __syncthreads();
    if (threadIdx.x == 0)
        partial[blockIdx.x] = fmaxf(fmaxf(sm[0], sm[1]), fmaxf(sm[2], sm[3]));
}

__global__ __launch_bounds__(256) void final_max_kernel(
    const float* __restrict__ partial, float* __restrict__ M)
{
    float m = partial[threadIdx.x];
    #pragma unroll
    for (int o = 32; o > 0; o >>= 1) m = fmaxf(m, __shfl_down(m, o));
    __shared__ float sm[4];
    if ((threadIdx.x & 63) == 0) sm[threadIdx.x >> 6] = m;
    __syncthreads();
    if (threadIdx.x == 0) *M = fmaxf(fmaxf(sm[0], sm[1]), fmaxf(sm[2], sm[3]));
}

// Stage 1: 64 blocks write per-block partials (9 floats each) — no atomics.
__global__ __launch_bounds__(256) void sum_kernel(
    const float* __restrict__ H, const float* __restrict__ logits,
    const float* __restrict__ Mp, float* __restrict__ partial)
{
    const float M = *Mp;
    float se = 0.0f;
    float sh[8] = {0, 0, 0, 0, 0, 0, 0, 0};
    for (int v = blockIdx.x * 256 + threadIdx.x; v < V; v += 64 * 256) {
        float w = __expf(logits[v] - M);
        se += w;
        const float4* H4 = (const float4*)(H + (size_t)v * 8);
        float4 h0 = H4[0], h1 = H4[1];
        sh[0] += w * h0.x; sh[1] += w * h0.y; sh[2] += w * h0.z; sh[3] += w * h0.w;
        sh[4] += w * h1.x; sh[5] += w * h1.y; sh[6] += w * h1.z; sh[7] += w * h1.w;
    }
    #pragma unroll
    for (int o = 32; o > 0; o >>= 1) {
        se += __shfl_xor(se, o);
        #pragma unroll
        for (int i = 0; i < 8; ++i) sh[i] += __shfl_xor(sh[i], o);
    }
    __shared__ float sm[4][9];
    int wv = threadIdx.x >> 6;
    if ((threadIdx.x & 63) == 0) {
        sm[wv][8] = se;
        #pragma unroll
        for (int i = 0; i < 8; ++i) sm[wv][i] = sh[i];
    }
    __syncthreads();
    if (threadIdx.x == 0) {
        #pragma unroll
        for (int i = 0; i < 9; ++i)
            partial[blockIdx.x * 12 + i] = sm[0][i] + sm[1][i] + sm[2][i] + sm[3][i];
    }
}

__global__ void final_kernel(const float* __restrict__ partial, float* __restrict__ out)
{
    int lane = threadIdx.x;               // 64 threads
    float vals[9];
    #pragma unroll
    for (int i = 0; i < 9; ++i) vals[i] = partial[lane * 12 + i];
    #pragma unroll
    for (int o = 1; o < 64; o <<= 1) {
        #pragma unroll
        for (int i = 0; i < 9; ++i) vals[i] += __shfl_xor(vals[i], o);
    }
    __shared__ float res[9];
    if (lane == 0) {
        #pragma unroll
        for (int i = 0; i < 9; ++i) res[i] = vals[i];
    }
    __syncthreads();
    if (lane < 8) out[lane] = tanhf(res[lane] / res[8]);
}

// ---------------------------------------------------------------------------
extern "C" void kernel_launch(void* const* d_in, const int* in_sizes, int n_in,
                              void* d_out, int out_size, void* d_ws, size_t ws_size,
                              hipStream_t stream)
{
    const float* feat  = (const float*)d_in[0];
    const int*   xnode = (const int*)d_in[1];
    const int*   xneis = (const int*)d_in[2];
    const int*   etype = (const int*)d_in[3];
    const float* dg    = (const float*)d_in[4];
    const float* Hinit = (const float*)d_in[5];
    const float* Wxi   = (const float*)d_in[6];
    const float* bxi   = (const float*)d_in[7];
    const float* Wrou  = (const float*)d_in[8];
    const float* brou  = (const float*)d_in[9];
    const float* W1    = (const float*)d_in[10];
    const float* b1    = (const float*)d_in[11];

    char* ws = (char*)d_ws;
    auto alloc = [&](size_t bytes) -> char* {
        char* p = ws; ws += (bytes + 255) & ~(size_t)255; return p;
    };
    unsigned* A4      = (unsigned*)alloc((size_t)E * 32);      // 51.2 MB int4 A
    uint2*    buc     = (uint2*)alloc((size_t)NEB * 2048 * 8); // 102.4 MB scatter buckets
    unsigned char* P8 = (unsigned char*)alloc((size_t)V * 64); // 6.4 MB int8 P
    ushort*   Qb      = (ushort*)alloc((size_t)V * 64 * 2);    // 12.8 MB bf16 Q
    unsigned* pmeta   = (unsigned*)alloc((size_t)E * 4);       // 6.4 MB CSR meta
    int*      rank0   = (int*)alloc((size_t)E * 4);            // 6.4 MB per-edge rank
    int*      countg  = (int*)alloc((size_t)GN * V * 4);       // 3.2 MB XCD-local counts
    int*      offg    = (int*)alloc((size_t)GN * V * 4);       // 3.2 MB group offsets
    int*      bcnt    = (int*)alloc((size_t)NEB * 8 * 4);      // 0.2 MB bucket counts
    int*      cnt     = (int*)alloc((size_t)V * 4);            // per-node count
    int*      scanned = (int*)alloc((size_t)V * 4);
    int*      rowptr  = (int*)alloc((size_t)(V + 1) * 4);
    int*      bsumT   = (int*)alloc(512 * 4);
    int*      topsT   = (int*)alloc(512 * 4);
    uint2*    Hq0     = (uint2*)alloc((size_t)V * 8);          // int4 Hinit + scale
    uint2*    HqA     = (uint2*)alloc((size_t)V * 8);
    uint2*    HqB     = (uint2*)alloc((size_t)V * 8);
    float*    Hfp     = (float*)alloc((size_t)V * 8 * 4);      // fp32 H (last step)
    float*    Bsum    = (float*)alloc((size_t)V * 8 * 4);
    float*    logits  = (float*)alloc((size_t)V * 4);
    float*    pmax    = (float*)alloc(256 * 4);
    float*    Mp      = (float*)alloc(16);
    float*    spart   = (float*)alloc(64 * 12 * 4);

    hipMemsetAsync(countg, 0, (size_t)GN * V * 4, stream);
    histg_kernel<<<NEB, 256, 0, stream>>>(xneis, countg, rank0);
    scanV_kernel<<<NB, 256, 0, stream>>>(countg, offg, cnt, scanned, bsumT);
    scan_tops_kernel<<<1, 512, 0, stream>>>(bsumT, topsT, rowptr);
    add_offsets_kernel<<<NB, 256, 0, stream>>>(scanned, topsT, rowptr);
    scatterA_kernel<<<NEB, 256, 0, stream>>>(xnode, xneis, etype, dg,
                                             rowptr, offg, rank0, buc, bcnt);
    drain_kernel<<<2048, 256, 0, stream>>>(buc, bcnt, pmeta);
    pq_kernel<<<(V / 16 + 3) / 4, 256, 0, stream>>>(feat, Wxi, P8, Qb);
    bsum_kernel<<<NB, 256, 0, stream>>>(feat, cnt, Wrou, brou, Hinit,
                                        Bsum, Hq0);
    // amat + fused step 1: writes int4 A and int4 H1 in one pass
    amat_kernel<<<(V + 3) / 4, 256, 0, stream>>>(pmeta, rowptr, P8, Qb, Wxi, bxi,
                                                 Hq0, Bsum, A4, HqA);

    // steps 2..4 (quad-per-node, int4)
    const uint2* Hcur = HqA;
    uint2* bufs[2] = {HqB, HqA};
    for (int t = 0; t < 3; ++t) {
        uint2* Hn = bufs[t & 1];
        float* lg  = (t == 2) ? logits : nullptr;
        float* hf  = (t == 2) ? Hfp : nullptr;
        step_kernel<<<(V + 63) / 64, 256, 0, stream>>>(Hcur, Hn, pmeta, rowptr,
                                                       A4, Bsum, W1, b1, lg, hf);
        Hcur = Hn;
    }

    reduce_max_kernel<<<256, 256, 0, stream>>>(logits, pmax);
    final_max_kernel<<<1, 256, 0, stream>>>(pmax, Mp);
    sum_kernel<<<64, 256, 0, stream>>>(Hfp, logits, Mp, spart);
    final_kernel<<<1, 64, 0, stream>>>(spart, (float*)d_out);
}

// Round 10
// 404.743 us; speedup vs baseline: 1.1350x; 1.0567x over previous
//
#include <hip/hip_runtime.h>
#include <hip/hip_bf16.h>

constexpr int V   = 100000;
constexpr int E   = 1600000;
constexpr int NET = 10;
constexpr int KXW = 138;              // W_xi row length (2*64+10)
constexpr int NB  = (V + 255) / 256;  // 391 blocks over nodes
constexpr int GN  = 8;                // count groups (= XCDs)
constexpr int NEB = E / 256;          // 6250 edge blocks (exact)
constexpr float MUS   = 0.1125f;      // MU / S
constexpr float SP    = 0.025f;       // int8 P scale
constexpr float LOG2E = 1.44269504f;
constexpr float S2L   = 2.0f * SP * LOG2E;   // int8 P step in exp2 domain
constexpr float K7    = MUS / 7.0f;          // int4 A decode scale (x 1/dg per edge)

typedef __attribute__((ext_vector_type(8))) short short8;
typedef __attribute__((ext_vector_type(4))) float float4v;

__device__ __forceinline__ float fast_tanh(float x) {
    return 1.0f - 2.0f * __builtin_amdgcn_rcpf(__expf(2.0f * x) + 1.0f);
}
__device__ __forceinline__ float bflo(unsigned u) { return __uint_as_float(u << 16); }
__device__ __forceinline__ float bfhi(unsigned u) { return __uint_as_float(u & 0xffff0000u); }
__device__ __forceinline__ short f2bf(float x) {
    union { __hip_bfloat16 b; short s; } u; u.b = __float2bfloat16(x); return u.s;
}

__device__ __forceinline__ float ub0(unsigned u) {
#if __has_builtin(__builtin_amdgcn_cvt_f32_ubyte0)
    return __builtin_amdgcn_cvt_f32_ubyte0(u);
#else
    return (float)(u & 0xff);
#endif
}
__device__ __forceinline__ float ub1(unsigned u) {
#if __has_builtin(__builtin_amdgcn_cvt_f32_ubyte1)
    return __builtin_amdgcn_cvt_f32_ubyte1(u);
#else
    return (float)((u >> 8) & 0xff);
#endif
}
__device__ __forceinline__ float ub2(unsigned u) {
#if __has_builtin(__builtin_amdgcn_cvt_f32_ubyte2)
    return __builtin_amdgcn_cvt_f32_ubyte2(u);
#else
    return (float)((u >> 16) & 0xff);
#endif
}
__device__ __forceinline__ float ub3(unsigned u) {
#if __has_builtin(__builtin_amdgcn_cvt_f32_ubyte3)
    return __builtin_amdgcn_cvt_f32_ubyte3(u);
#else
    return (float)(u >> 24);
#endif
}

// int4 dot8: D = sum of 8 signed-nibble products + C (v_dot8_i32_i4)
__device__ __forceinline__ int dot8i4(unsigned a, unsigned b, int c) {
#if __has_builtin(__builtin_amdgcn_sdot8)
    return __builtin_amdgcn_sdot8((int)a, (int)b, c, false);
#else
    int r = c;
    #pragma unroll
    for (int j = 0; j < 8; ++j) {
        int av = ((int)(a << (28 - 4 * j))) >> 28;
        int bv = ((int)(b << (28 - 4 * j))) >> 28;
        r += av * bv;
    }
    return r;
#endif
}

// ---------------------------------------------------------------------------
// XCD-local histogram + per-edge rank within (group, node). g = blockIdx&7.
// ONE atomic pass total. (R6-R9 tripwire-proven build path, unchanged.)
// ---------------------------------------------------------------------------
__global__ __launch_bounds__(256) void histg_kernel(
    const int* __restrict__ xneis, int* __restrict__ countg,
    int* __restrict__ rank0)
{
    int e = blockIdx.x * 256 + threadIdx.x;
    if (e >= E) return;
    int g = blockIdx.x & (GN - 1);
    int nr = xneis[e];
    if (nr < V) rank0[e] = atomicAdd(&countg[g * V + nr], 1);
}

// Fold group slices (offg, cnt_tot) + blockwise-exclusive scan, fused.
__global__ __launch_bounds__(256) void scanV_kernel(
    const int* __restrict__ countg, int* __restrict__ offg,
    int* __restrict__ cnt_tot, int* __restrict__ scanned, int* __restrict__ bsum)
{
    __shared__ int s[256];
    int tid = threadIdx.x;
    int i = blockIdx.x * 256 + tid;
    int c = 0;
    if (i < V) {
        int run = 0;
        #pragma unroll
        for (int g = 0; g < GN; ++g) {
            offg[g * V + i] = run;
            run += countg[g * V + i];
        }
        cnt_tot[i] = run;
        c = run;
    }
    s[tid] = c; __syncthreads();
    #pragma unroll
    for (int off = 1; off < 256; off <<= 1) {
        int t = (tid >= off) ? s[tid - off] : 0;
        __syncthreads();
        s[tid] += t;
        __syncthreads();
    }
    if (i < V) scanned[i] = s[tid] - c;
    if (tid == 255) bsum[blockIdx.x] = s[255];
}

__global__ __launch_bounds__(512) void scan_tops_kernel(
    const int* __restrict__ blocksum, int* __restrict__ tops, int* __restrict__ rowptr)
{
    __shared__ int s[512];
    int tid = threadIdx.x;
    int v = (tid < NB) ? blocksum[tid] : 0;
    s[tid] = v; __syncthreads();
    #pragma unroll
    for (int off = 1; off < 512; off <<= 1) {
        int t = (tid >= off) ? s[tid - off] : 0;
        __syncthreads();
        s[tid] += t;
        __syncthreads();
    }
    if (tid < NB) tops[tid] = s[tid] - v;        // exclusive
    if (tid == 511) rowptr[V] = s[511];          // total kept edges
}

__global__ __launch_bounds__(256) void add_offsets_kernel(
    const int* __restrict__ scanned, const int* __restrict__ tops, int* __restrict__ rowptr)
{
    int i = blockIdx.x * 256 + threadIdx.x;
    if (i < V) rowptr[i] = scanned[i] + tops[blockIdx.x];
}

// ---------------------------------------------------------------------------
// Two-hop scatter (R9, tripwire-proven).
// ---------------------------------------------------------------------------
__global__ __launch_bounds__(256) void scatterA_kernel(
    const int* __restrict__ xnode, const int* __restrict__ xneis,
    const int* __restrict__ etype, const float* __restrict__ dg,
    const int* __restrict__ rowptr, const int* __restrict__ offg,
    const int* __restrict__ rank0, uint2* __restrict__ buc,
    int* __restrict__ bcnt)
{
    __shared__ int wcnt[4][8];
    __shared__ int woff[4][8];
    int tid = threadIdx.x;
    int lane = tid & 63, wv = tid >> 6;
    int e = blockIdx.x * 256 + tid;              // E = 6250*256 exact
    int g = blockIdx.x & (GN - 1);

    int nr = xneis[e];
    bool keep = (nr < V);
    int p = -1, r = 0;
    if (keep) {
        p = rowptr[nr] + offg[g * V + nr] + rank0[e];
        r = p >> 18;                             // 0..7 since kept edges < 2^21
    }

    // in-wave rank among same-range lanes (deterministic)
    unsigned rnk = 0;
    #pragma unroll
    for (int r8 = 0; r8 < 8; ++r8) {
        unsigned long long m = __ballot(keep && (r == r8));
        if (keep && r == r8)
            rnk = (unsigned)__popcll(m & ((1ull << lane) - 1ull));
        if (lane == 0) wcnt[wv][r8] = (int)__popcll(m);
    }
    __syncthreads();
    if (tid < 8) {
        int run = 0;
        #pragma unroll
        for (int w = 0; w < 4; ++w) { woff[w][tid] = run; run += wcnt[w][tid]; }
        bcnt[blockIdx.x * 8 + tid] = run;
    }
    __syncthreads();

    if (keep) {
        unsigned src = (unsigned)(xnode[e] - 1);
        unsigned et  = (unsigned)(etype[e] - 1);
        unsigned dgi = (unsigned)dg[e] - 1;      // 0..63, exact
        unsigned meta = src | (et << 17) | (dgi << 21);
        int slot = blockIdx.x * 2048 + r * 256 + woff[wv][r] + (int)rnk;
        buc[slot] = make_uint2((unsigned)p, meta);
    }
}

// Hop B: blocks with blockIdx&7==r drain range r (XCD-local pmeta window).
__global__ __launch_bounds__(256) void drain_kernel(
    const uint2* __restrict__ buc, const int* __restrict__ bcnt,
    unsigned* __restrict__ pmeta)
{
    int r = blockIdx.x & 7;
    int nstride = (int)(gridDim.x >> 3);
    for (int sb = (int)(blockIdx.x >> 3); sb < NEB; sb += nstride) {
        int c = bcnt[sb * 8 + r];
        const uint2* seg = buc + (size_t)sb * 2048 + r * 256;
        for (int i = threadIdx.x; i < c; i += 256) {
            uint2 t = seg[i];
            pmeta[t.x] = t.y;
        }
    }
}

// ---------------------------------------------------------------------------
// Per-node bias sum + int4-quantized Hinit (Hq0: 8 nibbles + fp32 scale).
// ---------------------------------------------------------------------------
__global__ __launch_bounds__(256) void bsum_kernel(
    const float* __restrict__ feat, const int* __restrict__ count,
    const float* __restrict__ Wrou, const float* __restrict__ brou,
    const float* __restrict__ Hinit, float* __restrict__ Bsum,
    uint2* __restrict__ Hq0)
{
    __shared__ float Wl[512];
    __shared__ float bl[8];
    int tid = threadIdx.x;
    for (int i = tid; i < 512; i += 256) Wl[i] = Wrou[i];
    if (tid < 8) bl[tid] = brou[tid];
    __syncthreads();

    int v = blockIdx.x * 256 + tid;
    if (v >= V) return;
    int c = count[v];
    float out[8] = {0, 0, 0, 0, 0, 0, 0, 0};
    if (c > 0) {                                  // c>0 implies v >= 1
        const float4* f4 = (const float4*)(feat + (size_t)(v - 1) * 64);
        float acc[8];
        #pragma unroll
        for (int s = 0; s < 8; ++s) acc[s] = bl[s];
        #pragma unroll 4
        for (int k = 0; k < 16; ++k) {
            float4 x = f4[k];
            #pragma unroll
            for (int s = 0; s < 8; ++s) {
                const float* w = &Wl[s * 64 + k * 4];
                acc[s] += x.x * w[0] + x.y * w[1] + x.z * w[2] + x.w * w[3];
            }
        }
        float fc = (float)c;
        #pragma unroll
        for (int s = 0; s < 8; ++s) out[s] = fc * fast_tanh(acc[s]);
    }
    float4* O = (float4*)(Bsum + (size_t)v * 8);
    O[0] = make_float4(out[0], out[1], out[2], out[3]);
    O[1] = make_float4(out[4], out[5], out[6], out[7]);

    // quantize Hinit row to int4 nibbles + per-node scale
    const float4* Hh4 = (const float4*)(Hinit + (size_t)v * 8);
    float4 h0 = Hh4[0], h1 = Hh4[1];
    float hv[8] = {h0.x, h0.y, h0.z, h0.w, h1.x, h1.y, h1.z, h1.w};
    float mx = 0.0f;
    #pragma unroll
    for (int i = 0; i < 8; ++i) mx = fmaxf(mx, fabsf(hv[i]));
    float si = (mx > 0.0f) ? 7.0f / mx : 0.0f;
    unsigned w = 0;
    #pragma unroll
    for (int i = 0; i < 8; ++i)
        w |= ((unsigned)((int)rintf(hv[i] * si)) & 0xFu) << (4 * i);
    Hq0[v] = make_uint2(w, __float_as_uint(mx * (1.0f / 7.0f)));
}

// ---------------------------------------------------------------------------
// PQ GEMM (MFMA): P[v] -> int8 biased (6.4 MB), Q[v] -> bf16 (12.8 MB)
// ---------------------------------------------------------------------------
__global__ __launch_bounds__(256) void pq_kernel(
    const float* __restrict__ feat, const float* __restrict__ Wxi,
    unsigned char* __restrict__ P8, ushort* __restrict__ Qb)
{
    const int lane = threadIdx.x & 63, wave = threadIdx.x >> 6;
    const int quad = lane >> 4, l16 = lane & 15;

    short8 bP[4][2], bQ[4][2];
    #pragma unroll
    for (int nt = 0; nt < 4; ++nt) {
        #pragma unroll
        for (int ks = 0; ks < 2; ++ks) {
            const float* wp = Wxi + (size_t)(nt * 16 + l16) * KXW + ks * 32 + quad * 8;
            short8 p, q;
            #pragma unroll
            for (int j = 0; j < 8; ++j) { p[j] = f2bf(wp[j]); q[j] = f2bf(wp[64 + j]); }
            bP[nt][ks] = p; bQ[nt][ks] = q;
        }
    }

    int t = blockIdx.x * 4 + wave;
    if (t >= V / 16) return;
    int v0 = t * 16;

    const float* fp = feat + (size_t)(v0 + l16) * 64 + quad * 8;
    short8 a0, a1;
    #pragma unroll
    for (int j = 0; j < 8; ++j) { a0[j] = f2bf(fp[j]); a1[j] = f2bf(fp[32 + j]); }

    float4v accP[4], accQ[4];
    #pragma unroll
    for (int nt = 0; nt < 4; ++nt) {
        float4v z = {0.f, 0.f, 0.f, 0.f};
        z = __builtin_amdgcn_mfma_f32_16x16x32_bf16(a0, bP[nt][0], z, 0, 0, 0);
        z = __builtin_amdgcn_mfma_f32_16x16x32_bf16(a1, bP[nt][1], z, 0, 0, 0);
        accP[nt] = z;
        float4v w = {0.f, 0.f, 0.f, 0.f};
        w = __builtin_amdgcn_mfma_f32_16x16x32_bf16(a0, bQ[nt][0], w, 0, 0, 0);
        w = __builtin_amdgcn_mfma_f32_16x16x32_bf16(a1, bQ[nt][1], w, 0, 0, 0);
        accQ[nt] = w;
    }

    #pragma unroll
    for (int r = 0; r < 4; ++r) {
        int row = v0 + quad * 4 + r;
        #pragma unroll
        for (int nt = 0; nt < 4; ++nt) {
            int col = nt * 16 + l16;
            int q8 = (int)rintf(accP[nt][r] * (1.0f / SP)) + 128;
            q8 = min(max(q8, 0), 255);
            P8[row * 64 + col] = (unsigned char)q8;
            Qb[row * 64 + col] = (ushort)f2bf(accQ[nt][r]);
        }
    }
}

// ---------------------------------------------------------------------------
// FUSED A materialization + STEP 1. A stored INT4 (R8/R9-proven).
// ---------------------------------------------------------------------------
__global__ __launch_bounds__(256) void amat_kernel(
    const unsigned* __restrict__ pmeta, const int* __restrict__ rowptr,
    const unsigned char* __restrict__ P8, const ushort* __restrict__ Qb,
    const float* __restrict__ Wxi, const float* __restrict__ bxi,
    const uint2* __restrict__ Hq0, const float* __restrict__ Bsum,
    unsigned* __restrict__ A4, uint2* __restrict__ HqOut)
{
    __shared__ float Wet2[NET * 64];     // 2*log2e*(Wxi[n][128+et]+bxi[n])
    int tid = threadIdx.x;
    for (int i = tid; i < NET * 64; i += 256) {
        int et = i >> 6, n = i & 63;
        Wet2[i] = 2.0f * LOG2E * (Wxi[n * KXW + 128 + et] + bxi[n]);
    }
    __syncthreads();

    int v = blockIdx.x * 4 + (tid >> 6);
    if (v >= V) return;
    int lane = tid & 63;
    int el = lane >> 3, s = lane & 7;

    const int off = rowptr[v];
    const int deg = rowptr[v + 1] - off;

    float q0, q1, q2, q3, q4, q5, q6, q7;
    {
        uint4 qu = *(const uint4*)(Qb + v * 64 + s * 8);
        const float B = 128.0f * SP, C = 2.0f * LOG2E;
        q0 = C * (bflo(qu.x) - B); q1 = C * (bfhi(qu.x) - B);
        q2 = C * (bflo(qu.y) - B); q3 = C * (bfhi(qu.y) - B);
        q4 = C * (bflo(qu.z) - B); q5 = C * (bfhi(qu.z) - B);
        q6 = C * (bflo(qu.w) - B); q7 = C * (bfhi(qu.w) - B);
    }

    float accD = 0.0f;                    // fused step-1 accumulator

    for (int base = 0; base < deg; base += 64) {
        // phase 1: this lane resolves edge (base+lane) — fully coalesced
        unsigned m_mine = 0;
        {
            int i1 = base + lane;
            if (i1 < deg) m_mine = pmeta[off + i1];
        }
        // phase 2: 8 edges per sub-round, meta via shfl broadcast
        int nb = deg - base;
        for (int k = 0; k * 8 + el < nb && k < 8; ++k) {
            int ib = k * 8 + el;
            int i = base + ib;
            unsigned m = __shfl(m_mine, ib);
            int src = (int)(m & 0x1FFFF);
            int et  = (int)((m >> 17) & 0xF);

            // issue all loads up front so they overlap the exp chain
            uint2 pu = *(const uint2*)(P8 + src * 64 + s * 8);
            const float4* w4 = (const float4*)(&Wet2[et * 64 + s * 8]);
            float4 wa = w4[0], wb = w4[1];
            uint2 hq = Hq0[src];

            float r0 = __builtin_amdgcn_rcpf(__builtin_amdgcn_exp2f(fmaf(ub0(pu.x), S2L, q0 + wa.x)) + 1.0f);
            float r1 = __builtin_amdgcn_rcpf(__builtin_amdgcn_exp2f(fmaf(ub1(pu.x), S2L, q1 + wa.y)) + 1.0f);
            float r2 = __builtin_amdgcn_rcpf(__builtin_amdgcn_exp2f(fmaf(ub2(pu.x), S2L, q2 + wa.z)) + 1.0f);
            float r3 = __builtin_amdgcn_rcpf(__builtin_amdgcn_exp2f(fmaf(ub3(pu.x), S2L, q3 + wa.w)) + 1.0f);
            float r4 = __builtin_amdgcn_rcpf(__builtin_amdgcn_exp2f(fmaf(ub0(pu.y), S2L, q4 + wb.x)) + 1.0f);
            float r5 = __builtin_amdgcn_rcpf(__builtin_amdgcn_exp2f(fmaf(ub1(pu.y), S2L, q5 + wb.y)) + 1.0f);
            float r6 = __builtin_amdgcn_rcpf(__builtin_amdgcn_exp2f(fmaf(ub2(pu.y), S2L, q6 + wb.z)) + 1.0f);
            float r7 = __builtin_amdgcn_rcpf(__builtin_amdgcn_exp2f(fmaf(ub3(pu.y), S2L, q7 + wb.w)) + 1.0f);

            // n = round(7*tanh) = round(7 - 14*r), in [-7,7]
            int n0 = (int)rintf(fmaf(r0, -14.0f, 7.0f));
            int n1 = (int)rintf(fmaf(r1, -14.0f, 7.0f));
            int n2 = (int)rintf(fmaf(r2, -14.0f, 7.0f));
            int n3 = (int)rintf(fmaf(r3, -14.0f, 7.0f));
            int n4 = (int)rintf(fmaf(r4, -14.0f, 7.0f));
            int n5 = (int)rintf(fmaf(r5, -14.0f, 7.0f));
            int n6 = (int)rintf(fmaf(r6, -14.0f, 7.0f));
            int n7 = (int)rintf(fmaf(r7, -14.0f, 7.0f));

            unsigned w = ((unsigned)n0 & 0xFu)        | (((unsigned)n1 & 0xFu) << 4)
                       | (((unsigned)n2 & 0xFu) << 8)  | (((unsigned)n3 & 0xFu) << 12)
                       | (((unsigned)n4 & 0xFu) << 16) | (((unsigned)n5 & 0xFu) << 20)
                       | (((unsigned)n6 & 0xFu) << 24) | (((unsigned)n7 & 0xFu) << 28);
            A4[(unsigned)(off + i) * 8u + (unsigned)s] = w;

            // fused step 1: same sdot8 form the steps use (A row . Hq0[src])
            int dd = dot8i4(w, hq.x, 0);
            float rdg = __builtin_amdgcn_rcpf((float)((int)(m >> 21) + 1));
            accD = fmaf((float)dd, __uint_as_float(hq.y) * rdg, accD);
        }
    }
    // reduce over el lanes (lane = el*8 + s)
    accD += __shfl_xor(accD, 8);  accD += __shfl_xor(accD, 16); accD += __shfl_xor(accD, 32);
    float h1v = accD * K7 + Bsum[v * 8 + s];

    // quantize H1 row to int4 with per-node scale
    float mx = fabsf(h1v);
    mx = fmaxf(mx, __shfl_xor(mx, 1));
    mx = fmaxf(mx, __shfl_xor(mx, 2));
    mx = fmaxf(mx, __shfl_xor(mx, 4));           // max over s within el group
    float si = (mx > 0.0f) ? 7.0f / mx : 0.0f;
    unsigned nib = (unsigned)((int)rintf(h1v * si)) & 0xFu;
    unsigned b1 = __shfl(nib, lane + 1), b2 = __shfl(nib, lane + 2), b3 = __shfl(nib, lane + 3);
    unsigned b4 = __shfl(nib, lane + 4), b5 = __shfl(nib, lane + 5);
    unsigned b6 = __shfl(nib, lane + 6), b7 = __shfl(nib, lane + 7);
    if (lane == 0) {
        unsigned w = nib | (b1 << 4) | (b2 << 8) | (b3 << 12)
                   | (b4 << 16) | (b5 << 20) | (b6 << 24) | (b7 << 28);
        HqOut[v] = make_uint2(w, __float_as_uint(mx * (1.0f / 7.0f)));
    }
}

// ---------------------------------------------------------------------------
// Light step, QUAD-PER-NODE, int4, 2x-UNROLLED: edge pairs with independent
// load batches + separate accumulator chains -> 2x memory-level parallelism,
// halved loop-carried latency exposure. Runs 3x.
// ---------------------------------------------------------------------------
__global__ __launch_bounds__(256) void step_kernel(
    const uint2* __restrict__ HqIn, uint2* __restrict__ HqOut,
    const unsigned* __restrict__ pmeta, const int* __restrict__ rowptr,
    const unsigned* __restrict__ A4, const float* __restrict__ Bsum,
    const float* __restrict__ W1, const float* __restrict__ b1,
    float* __restrict__ logitsOut, float* __restrict__ HfpOut)
{
    int v = blockIdx.x * 64 + (threadIdx.x >> 2);
    if (v >= V) return;
    int q = threadIdx.x & 3;

    int p0 = rowptr[v], p1 = rowptr[v + 1];

    float accE0 = 0.0f, accO0 = 0.0f, accE1 = 0.0f, accO1 = 0.0f;
    int p = p0;
    for (; p + 1 < p1; p += 2) {
        // batch all 6 loads before any use (2x MLP)
        unsigned m0 = pmeta[p], m1 = pmeta[p + 1];
        uint2 au0 = *(const uint2*)(A4 + (unsigned)p * 8u + (unsigned)(q * 2));
        uint2 au1 = *(const uint2*)(A4 + (unsigned)(p + 1) * 8u + (unsigned)(q * 2));
        uint2 hq0 = HqIn[m0 & 0x1FFFFu];
        uint2 hq1 = HqIn[m1 & 0x1FFFFu];

        int dE0 = dot8i4(au0.x, hq0.x, 0);
        int dO0 = dot8i4(au0.y, hq0.x, 0);
        float rdg0 = __builtin_amdgcn_rcpf((float)((int)(m0 >> 21) + 1));
        float sc0 = __uint_as_float(hq0.y) * rdg0;
        accE0 = fmaf((float)dE0, sc0, accE0);
        accO0 = fmaf((float)dO0, sc0, accO0);

        int dE1 = dot8i4(au1.x, hq1.x, 0);
        int dO1 = dot8i4(au1.y, hq1.x, 0);
        float rdg1 = __builtin_amdgcn_rcpf((float)((int)(m1 >> 21) + 1));
        float sc1 = __uint_as_float(hq1.y) * rdg1;
        accE1 = fmaf((float)dE1, sc1, accE1);
        accO1 = fmaf((float)dO1, sc1, accO1);
    }
    if (p < p1) {
        unsigned m = pmeta[p];
        uint2 au = *(const uint2*)(A4 + (unsigned)p * 8u + (unsigned)(q * 2));
        uint2 hq = HqIn[m & 0x1FFFFu];
        int dE = dot8i4(au.x, hq.x, 0);
        int dO = dot8i4(au.y, hq.x, 0);
        float rdg = __builtin_amdgcn_rcpf((float)((int)(m >> 21) + 1));
        float sc = __uint_as_float(hq.y) * rdg;
        accE0 = fmaf((float)dE, sc, accE0);
        accO0 = fmaf((float)dO, sc, accO0);
    }
    float accE = accE0 + accE1;
    float accO = accO0 + accO1;

    float hE = accE * K7 + Bsum[v * 8 + q * 2];
    float hO = accO * K7 + Bsum[v * 8 + q * 2 + 1];

    // quantize H row to int4 with per-node scale (reduce within quad only)
    float mx = fmaxf(fabsf(hE), fabsf(hO));
    mx = fmaxf(mx, __shfl_xor(mx, 1));
    mx = fmaxf(mx, __shfl_xor(mx, 2));
    float si = (mx > 0.0f) ? 7.0f / mx : 0.0f;
    unsigned nE = (unsigned)((int)rintf(hE * si)) & 0xFu;
    unsigned nO = (unsigned)((int)rintf(hO * si)) & 0xFu;
    unsigned wq = (nE | (nO << 4)) << (8 * q); // nibbles 2q, 2q+1
    wq |= __shfl_xor(wq, 1);
    wq |= __shfl_xor(wq, 2);
    if (q == 0)
        HqOut[v] = make_uint2(wq, __float_as_uint(mx * (1.0f / 7.0f)));
    if (HfpOut != nullptr)
        *(float2*)(HfpOut + v * 8 + q * 2) = make_float2(hE, hO);
    if (logitsOut != nullptr) {
        float t = hE * W1[q * 2] + hO * W1[q * 2 + 1];
        t += __shfl_xor(t, 1); t += __shfl_xor(t, 2);
        if (q == 0) logitsOut[v] = t + b1[0];
    }
}

// ---------------------------------------------------------------------------
// Epilogue: ONLINE-SOFTMAX weighted sum (no separate max pass).
// Stage 1: 64 blocks, each emits (m, se, sh[8]) with running-max rescaling
// (fixed iteration order -> deterministic).
// ---------------------------------------------------------------------------
__global__ __launch_bounds__(256) void sum_kernel(
    const float* __restrict__ H, const float* __restrict__ logits,
    float* __restrict__ partial)
{
    float m = -INFINITY, se = 0.0f;
    float sh[8] = {0, 0, 0, 0, 0, 0, 0, 0};
    for (int v = blockIdx.x * 256 + threadIdx.x; v < V; v += 64 * 256) {
        float l = logits[v];
        float mn = fmaxf(m, l);
        float a = __expf(m - mn);          // 0 when m == -inf
        float w = __expf(l - mn);
        se = se * a + w;
        const float4* H4 = (const float4*)(H + (size_t)v * 8);
        float4 h0 = H4[0], h1 = H4[1];
        sh[0] = sh[0] * a + w * h0.x; sh[1] = sh[1] * a + w * h0.y;
        sh[2] = sh[2] * a + w * h0.z; sh[3] = sh[3] * a + w * h0.w;
        sh[4] = sh[4] * a + w * h1.x; sh[5] = sh[5] * a + w * h1.y;
        sh[6] = sh[6] * a + w * h1.z; sh[7] = sh[7] * a + w * h1.w;
        m = mn;
    }
    // butterfly combine across 64 lanes
    #pragma unroll
    for (int o = 1; o < 64; o <<= 1) {
        float mo = __shfl_xor(m, o), seo = __shfl_xor(se, o);
        float sho[8];
        #pragma unroll
        for (int i = 0; i < 8; ++i) sho[i] = __shfl_xor(sh[i], o);
        float mn = fmaxf(m, mo);
        float a = __expf(m - mn), b = __expf(mo - mn);
        se = se * a + seo * b;
        #pragma unroll
        for (int i = 0; i < 8; ++i) sh[i] = sh[i] * a + sho[i] * b;
        m = mn;
    }
    // cross-wave combine via LDS (4 waves)
    __shared__ float sm[4][10];
    int wv = threadIdx.x >> 6;
    if ((threadIdx.x & 63) == 0) {
        sm[wv][0] = m; sm[wv][9] = se;
        #pragma unroll
        for (int i = 0; i < 8; ++i) sm[wv][1 + i] = sh[i];
    }
    __syncthreads();
    if (threadIdx.x == 0) {
        float M = sm[0][0], SE = 0.0f, SH[8] = {0, 0, 0, 0, 0, 0, 0, 0};
        #pragma unroll
        for (int w2 = 1; w2 < 4; ++w2) M = fmaxf(M, sm[w2][0]);
        #pragma unroll
        for (int w2 = 0; w2 < 4; ++w2) {
            float a = __expf(sm[w2][0] - M);
            SE += sm[w2][9] * a;
            #pragma unroll
            for (int i = 0; i < 8; ++i) SH[i] += sm[w2][1 + i] * a;
        }
        partial[blockIdx.x * 12 + 0] = M;
        partial[blockIdx.x * 12 + 9] = SE;
        #pragma unroll
        for (int i = 0; i < 8; ++i) partial[blockIdx.x * 12 + 1 + i] = SH[i];
    }
}

__global__ void final_kernel(const float* __restrict__ partial, float* __restrict__ out)
{
    int lane = threadIdx.x;               // 64 threads
    float m = partial[lane * 12 + 0];
    float se = partial[lane * 12 + 9];
    float sh[8];
    #pragma unroll
    for (int i = 0; i < 8; ++i) sh[i] = partial[lane * 12 + 1 + i];
    #pragma unroll
    for (int o = 1; o < 64; o <<= 1) {
        float mo = __shfl_xor(m, o), seo = __shfl_xor(se, o);
        float sho[8];
        #pragma unroll
        for (int i = 0; i < 8; ++i) sho[i] = __shfl_xor(sh[i], o);
        float mn = fmaxf(m, mo);
        float a = __expf(m - mn), b = __expf(mo - mn);
        se = se * a + seo * b;
        #pragma unroll
        for (int i = 0; i < 8; ++i) sh[i] = sh[i] * a + sho[i] * b;
        m = mn;
    }
    if (lane < 8) out[lane] = tanhf(sh[lane] / se);
}

// ---------------------------------------------------------------------------
extern "C" void kernel_launch(void* const* d_in, const int* in_sizes, int n_in,
                              void* d_out, int out_size, void* d_ws, size_t ws_size,
                              hipStream_t stream)
{
    const float* feat  = (const float*)d_in[0];
    const int*   xnode = (const int*)d_in[1];
    const int*   xneis = (const int*)d_in[2];
    const int*   etype = (const int*)d_in[3];
    const float* dg    = (const float*)d_in[4];
    const float* Hinit = (const float*)d_in[5];
    const float* Wxi   = (const float*)d_in[6];
    const float* bxi   = (const float*)d_in[7];
    const float* Wrou  = (const float*)d_in[8];
    const float* brou  = (const float*)d_in[9];
    const float* W1    = (const float*)d_in[10];
    const float* b1    = (const float*)d_in[11];

    char* ws = (char*)d_ws;
    auto alloc = [&](size_t bytes) -> char* {
        char* p = ws; ws += (bytes + 255) & ~(size_t)255; return p;
    };
    unsigned* A4      = (unsigned*)alloc((size_t)E * 32);      // 51.2 MB int4 A
    uint2*    buc     = (uint2*)alloc((size_t)NEB * 2048 * 8); // 102.4 MB scatter buckets
    unsigned char* P8 = (unsigned char*)alloc((size_t)V * 64); // 6.4 MB int8 P
    ushort*   Qb      = (ushort*)alloc((size_t)V * 64 * 2);    // 12.8 MB bf16 Q
    unsigned* pmeta   = (unsigned*)alloc((size_t)E * 4);       // 6.4 MB CSR meta
    int*      rank0   = (int*)alloc((size_t)E * 4);            // 6.4 MB per-edge rank
    int*      countg  = (int*)alloc((size_t)GN * V * 4);       // 3.2 MB XCD-local counts
    int*      offg    = (int*)alloc((size_t)GN * V * 4);       // 3.2 MB group offsets
    int*      bcnt    = (int*)alloc((size_t)NEB * 8 * 4);      // 0.2 MB bucket counts
    int*      cnt     = (int*)alloc((size_t)V * 4);            // per-node count
    int*      scanned = (int*)alloc((size_t)V * 4);
    int*      rowptr  = (int*)alloc((size_t)(V + 1) * 4);
    int*      bsumT   = (int*)alloc(512 * 4);
    int*      topsT   = (int*)alloc(512 * 4);
    uint2*    Hq0     = (uint2*)alloc((size_t)V * 8);          // int4 Hinit + scale
    uint2*    HqA     = (uint2*)alloc((size_t)V * 8);
    uint2*    HqB     = (uint2*)alloc((size_t)V * 8);
    float*    Hfp     = (float*)alloc((size_t)V * 8 * 4);      // fp32 H (last step)
    float*    Bsum    = (float*)alloc((size_t)V * 8 * 4);
    float*    logits  = (float*)alloc((size_t)V * 4);
    float*    spart   = (float*)alloc(64 * 12 * 4);

    hipMemsetAsync(countg, 0, (size_t)GN * V * 4, stream);
    histg_kernel<<<NEB, 256, 0, stream>>>(xneis, countg, rank0);
    scanV_kernel<<<NB, 256, 0, stream>>>(countg, offg, cnt, scanned, bsumT);
    scan_tops_kernel<<<1, 512, 0, stream>>>(bsumT, topsT, rowptr);
    add_offsets_kernel<<<NB, 256, 0, stream>>>(scanned, topsT, rowptr);
    scatterA_kernel<<<NEB, 256, 0, stream>>>(xnode, xneis, etype, dg,
                                             rowptr, offg, rank0, buc, bcnt);
    drain_kernel<<<2048, 256, 0, stream>>>(buc, bcnt, pmeta);
    pq_kernel<<<(V / 16 + 3) / 4, 256, 0, stream>>>(feat, Wxi, P8, Qb);
    bsum_kernel<<<NB, 256, 0, stream>>>(feat, cnt, Wrou, brou, Hinit,
                                        Bsum, Hq0);
    // amat + fused step 1: writes int4 A and int4 H1 in one pass
    amat_kernel<<<(V + 3) / 4, 256, 0, stream>>>(pmeta, rowptr, P8, Qb, Wxi, bxi,
                                                 Hq0, Bsum, A4, HqA);

    // steps 2..4 (quad-per-node, int4, 2x-unrolled)
    const uint2* Hcur = HqA;
    uint2* bufs[2] = {HqB, HqA};
    for (int t = 0; t < 3; ++t) {
        uint2* Hn = bufs[t & 1];
        float* lg  = (t == 2) ? logits : nullptr;
        float* hf  = (t == 2) ? Hfp : nullptr;
        step_kernel<<<(V + 63) / 64, 256, 0, stream>>>(Hcur, Hn, pmeta, rowptr,
                                                       A4, Bsum, W1, b1, lg, hf);
        Hcur = Hn;
    }

    sum_kernel<<<64, 256, 0, stream>>>(Hfp, logits, spart);
    final_kernel<<<1, 64, 0, stream>>>(spart, (float*)d_out);
}

// Round 11
// 394.911 us; speedup vs baseline: 1.1632x; 1.0249x over previous
//
#include <hip/hip_runtime.h>
#include <hip/hip_bf16.h>

constexpr int V   = 100000;
constexpr int E   = 1600000;
constexpr int NET = 10;
constexpr int KXW = 138;              // W_xi row length (2*64+10)
constexpr int NB  = (V + 255) / 256;  // 391 blocks over nodes
constexpr int GN  = 8;                // count groups (= XCDs)
constexpr int NEB = E / 256;          // 6250 edge blocks (exact)
constexpr int NPQ = (V / 16 + 3) / 4; // 1563 pq blocks
constexpr float MUS   = 0.1125f;      // MU / S
constexpr float SP    = 0.025f;       // int8 P scale
constexpr float LOG2E = 1.44269504f;
constexpr float S2L   = 2.0f * SP * LOG2E;   // int8 P step in exp2 domain
constexpr float K7    = MUS / 7.0f;          // int4 A decode scale (x 1/dg per edge)

typedef __attribute__((ext_vector_type(8))) short short8;
typedef __attribute__((ext_vector_type(4))) float float4v;

__device__ __forceinline__ float fast_tanh(float x) {
    return 1.0f - 2.0f * __builtin_amdgcn_rcpf(__expf(2.0f * x) + 1.0f);
}
__device__ __forceinline__ float bflo(unsigned u) { return __uint_as_float(u << 16); }
__device__ __forceinline__ float bfhi(unsigned u) { return __uint_as_float(u & 0xffff0000u); }
__device__ __forceinline__ short f2bf(float x) {
    union { __hip_bfloat16 b; short s; } u; u.b = __float2bfloat16(x); return u.s;
}

__device__ __forceinline__ float ub0(unsigned u) {
#if __has_builtin(__builtin_amdgcn_cvt_f32_ubyte0)
    return __builtin_amdgcn_cvt_f32_ubyte0(u);
#else
    return (float)(u & 0xff);
#endif
}
__device__ __forceinline__ float ub1(unsigned u) {
#if __has_builtin(__builtin_amdgcn_cvt_f32_ubyte1)
    return __builtin_amdgcn_cvt_f32_ubyte1(u);
#else
    return (float)((u >> 8) & 0xff);
#endif
}
__device__ __forceinline__ float ub2(unsigned u) {
#if __has_builtin(__builtin_amdgcn_cvt_f32_ubyte2)
    return __builtin_amdgcn_cvt_f32_ubyte2(u);
#else
    return (float)((u >> 16) & 0xff);
#endif
}
__device__ __forceinline__ float ub3(unsigned u) {
#if __has_builtin(__builtin_amdgcn_cvt_f32_ubyte3)
    return __builtin_amdgcn_cvt_f32_ubyte3(u);
#else
    return (float)(u >> 24);
#endif
}

// int4 dot8: D = sum of 8 signed-nibble products + C (v_dot8_i32_i4)
__device__ __forceinline__ int dot8i4(unsigned a, unsigned b, int c) {
#if __has_builtin(__builtin_amdgcn_sdot8)
    return __builtin_amdgcn_sdot8((int)a, (int)b, c, false);
#else
    int r = c;
    #pragma unroll
    for (int j = 0; j < 8; ++j) {
        int av = ((int)(a << (28 - 4 * j))) >> 28;
        int bv = ((int)(b << (28 - 4 * j))) >> 28;
        r += av * bv;
    }
    return r;
#endif
}

// ---------------------------------------------------------------------------
// FUSED histg + pq: blocks < NEB do the XCD-local histogram+rank (atomic-
// latency bound); remaining blocks run the independent PQ MFMA GEMM in the
// latency shadow. histg portion keeps g = blockIdx&7 (R6-R10 determinism
// class, 4x tripwire-proven).
// ---------------------------------------------------------------------------
__global__ __launch_bounds__(256) void histg_pq_kernel(
    const int* __restrict__ xneis, int* __restrict__ countg,
    int* __restrict__ rank0,
    const float* __restrict__ feat, const float* __restrict__ Wxi,
    unsigned char* __restrict__ P8, ushort* __restrict__ Qb)
{
    if (blockIdx.x < NEB) {
        int e = blockIdx.x * 256 + threadIdx.x;   // E = NEB*256 exact
        int g = blockIdx.x & (GN - 1);
        int nr = xneis[e];
        if (nr < V) rank0[e] = atomicAdd(&countg[g * V + nr], 1);
        return;
    }
    // ---- PQ part ----
    int bid = blockIdx.x - NEB;
    const int lane = threadIdx.x & 63, wave = threadIdx.x >> 6;
    const int quad = lane >> 4, l16 = lane & 15;

    short8 bP[4][2], bQ[4][2];
    #pragma unroll
    for (int nt = 0; nt < 4; ++nt) {
        #pragma unroll
        for (int ks = 0; ks < 2; ++ks) {
            const float* wp = Wxi + (size_t)(nt * 16 + l16) * KXW + ks * 32 + quad * 8;
            short8 p, q;
            #pragma unroll
            for (int j = 0; j < 8; ++j) { p[j] = f2bf(wp[j]); q[j] = f2bf(wp[64 + j]); }
            bP[nt][ks] = p; bQ[nt][ks] = q;
        }
    }

    int t = bid * 4 + wave;
    if (t >= V / 16) return;
    int v0 = t * 16;

    const float* fp = feat + (size_t)(v0 + l16) * 64 + quad * 8;
    short8 a0, a1;
    #pragma unroll
    for (int j = 0; j < 8; ++j) { a0[j] = f2bf(fp[j]); a1[j] = f2bf(fp[32 + j]); }

    float4v accP[4], accQ[4];
    #pragma unroll
    for (int nt = 0; nt < 4; ++nt) {
        float4v z = {0.f, 0.f, 0.f, 0.f};
        z = __builtin_amdgcn_mfma_f32_16x16x32_bf16(a0, bP[nt][0], z, 0, 0, 0);
        z = __builtin_amdgcn_mfma_f32_16x16x32_bf16(a1, bP[nt][1], z, 0, 0, 0);
        accP[nt] = z;
        float4v w = {0.f, 0.f, 0.f, 0.f};
        w = __builtin_amdgcn_mfma_f32_16x16x32_bf16(a0, bQ[nt][0], w, 0, 0, 0);
        w = __builtin_amdgcn_mfma_f32_16x16x32_bf16(a1, bQ[nt][1], w, 0, 0, 0);
        accQ[nt] = w;
    }

    #pragma unroll
    for (int r = 0; r < 4; ++r) {
        int row = v0 + quad * 4 + r;
        #pragma unroll
        for (int nt = 0; nt < 4; ++nt) {
            int col = nt * 16 + l16;
            int q8 = (int)rintf(accP[nt][r] * (1.0f / SP)) + 128;
            q8 = min(max(q8, 0), 255);
            P8[row * 64 + col] = (unsigned char)q8;
            Qb[row * 64 + col] = (ushort)f2bf(accQ[nt][r]);
        }
    }
}

// ---------------------------------------------------------------------------
// FUSED scanV + bsum: fold group slices (offg) + blockwise-exclusive scan,
// then (per node, degree already in register) the bias-sum + Hq0 quantize.
// ---------------------------------------------------------------------------
__global__ __launch_bounds__(256) void scanV_bsum_kernel(
    const int* __restrict__ countg, int* __restrict__ offg,
    int* __restrict__ scanned, int* __restrict__ bsumT,
    const float* __restrict__ feat, const float* __restrict__ Wrou,
    const float* __restrict__ brou, const float* __restrict__ Hinit,
    float* __restrict__ Bsum, uint2* __restrict__ Hq0)
{
    __shared__ int s[256];
    __shared__ float Wl[512];
    __shared__ float bl[8];
    int tid = threadIdx.x;
    for (int i = tid; i < 512; i += 256) Wl[i] = Wrou[i];
    if (tid < 8) bl[tid] = brou[tid];

    int v = blockIdx.x * 256 + tid;
    int c = 0;
    if (v < V) {
        int run = 0;
        #pragma unroll
        for (int g = 0; g < GN; ++g) {
            offg[g * V + v] = run;
            run += countg[g * V + v];
        }
        c = run;
    }
    s[tid] = c; __syncthreads();
    #pragma unroll
    for (int off = 1; off < 256; off <<= 1) {
        int t = (tid >= off) ? s[tid - off] : 0;
        __syncthreads();
        s[tid] += t;
        __syncthreads();
    }
    if (v < V) scanned[v] = s[tid] - c;
    if (tid == 255) bsumT[blockIdx.x] = s[255];

    // ---- bsum part (Wl/bl ready via the scan's syncthreads) ----
    if (v >= V) return;
    float out[8] = {0, 0, 0, 0, 0, 0, 0, 0};
    if (c > 0) {                                  // c>0 implies v >= 1
        const float4* f4 = (const float4*)(feat + (size_t)(v - 1) * 64);
        float acc[8];
        #pragma unroll
        for (int ss = 0; ss < 8; ++ss) acc[ss] = bl[ss];
        #pragma unroll 4
        for (int k = 0; k < 16; ++k) {
            float4 x = f4[k];
            #pragma unroll
            for (int ss = 0; ss < 8; ++ss) {
                const float* w = &Wl[ss * 64 + k * 4];
                acc[ss] += x.x * w[0] + x.y * w[1] + x.z * w[2] + x.w * w[3];
            }
        }
        float fc = (float)c;
        #pragma unroll
        for (int ss = 0; ss < 8; ++ss) out[ss] = fc * fast_tanh(acc[ss]);
    }
    float4* O = (float4*)(Bsum + (size_t)v * 8);
    O[0] = make_float4(out[0], out[1], out[2], out[3]);
    O[1] = make_float4(out[4], out[5], out[6], out[7]);

    // quantize Hinit row to int4 nibbles + per-node scale
    const float4* Hh4 = (const float4*)(Hinit + (size_t)v * 8);
    float4 h0 = Hh4[0], h1 = Hh4[1];
    float hv[8] = {h0.x, h0.y, h0.z, h0.w, h1.x, h1.y, h1.z, h1.w};
    float mx = 0.0f;
    #pragma unroll
    for (int i = 0; i < 8; ++i) mx = fmaxf(mx, fabsf(hv[i]));
    float si = (mx > 0.0f) ? 7.0f / mx : 0.0f;
    unsigned w = 0;
    #pragma unroll
    for (int i = 0; i < 8; ++i)
        w |= ((unsigned)((int)rintf(hv[i] * si)) & 0xFu) << (4 * i);
    Hq0[v] = make_uint2(w, __float_as_uint(mx * (1.0f / 7.0f)));
}

__global__ __launch_bounds__(512) void scan_tops_kernel(
    const int* __restrict__ blocksum, int* __restrict__ tops, int* __restrict__ rowptr)
{
    __shared__ int s[512];
    int tid = threadIdx.x;
    int v = (tid < NB) ? blocksum[tid] : 0;
    s[tid] = v; __syncthreads();
    #pragma unroll
    for (int off = 1; off < 512; off <<= 1) {
        int t = (tid >= off) ? s[tid - off] : 0;
        __syncthreads();
        s[tid] += t;
        __syncthreads();
    }
    if (tid < NB) tops[tid] = s[tid] - v;        // exclusive
    if (tid == 511) rowptr[V] = s[511];          // total kept edges
}

__global__ __launch_bounds__(256) void add_offsets_kernel(
    const int* __restrict__ scanned, const int* __restrict__ tops, int* __restrict__ rowptr)
{
    int i = blockIdx.x * 256 + threadIdx.x;
    if (i < V) rowptr[i] = scanned[i] + tops[blockIdx.x];
}

// ---------------------------------------------------------------------------
// Two-hop scatter (R9/R10, tripwire-proven).
// ---------------------------------------------------------------------------
__global__ __launch_bounds__(256) void scatterA_kernel(
    const int* __restrict__ xnode, const int* __restrict__ xneis,
    const int* __restrict__ etype, const float* __restrict__ dg,
    const int* __restrict__ rowptr, const int* __restrict__ offg,
    const int* __restrict__ rank0, uint2* __restrict__ buc,
    int* __restrict__ bcnt)
{
    __shared__ int wcnt[4][8];
    __shared__ int woff[4][8];
    int tid = threadIdx.x;
    int lane = tid & 63, wv = tid >> 6;
    int e = blockIdx.x * 256 + tid;              // E = 6250*256 exact
    int g = blockIdx.x & (GN - 1);

    int nr = xneis[e];
    bool keep = (nr < V);
    int p = -1, r = 0;
    if (keep) {
        p = rowptr[nr] + offg[g * V + nr] + rank0[e];
        r = p >> 18;                             // 0..7 since kept edges < 2^21
    }

    // in-wave rank among same-range lanes (deterministic)
    unsigned rnk = 0;
    #pragma unroll
    for (int r8 = 0; r8 < 8; ++r8) {
        unsigned long long m = __ballot(keep && (r == r8));
        if (keep && r == r8)
            rnk = (unsigned)__popcll(m & ((1ull << lane) - 1ull));
        if (lane == 0) wcnt[wv][r8] = (int)__popcll(m);
    }
    __syncthreads();
    if (tid < 8) {
        int run = 0;
        #pragma unroll
        for (int w = 0; w < 4; ++w) { woff[w][tid] = run; run += wcnt[w][tid]; }
        bcnt[blockIdx.x * 8 + tid] = run;
    }
    __syncthreads();

    if (keep) {
        unsigned src = (unsigned)(xnode[e] - 1);
        unsigned et  = (unsigned)(etype[e] - 1);
        unsigned dgi = (unsigned)dg[e] - 1;      // 0..63, exact
        unsigned meta = src | (et << 17) | (dgi << 21);
        int slot = blockIdx.x * 2048 + r * 256 + woff[wv][r] + (int)rnk;
        buc[slot] = make_uint2((unsigned)p, meta);
    }
}

// Hop B: blocks with blockIdx&7==r drain range r (XCD-local pmeta window).
__global__ __launch_bounds__(256) void drain_kernel(
    const uint2* __restrict__ buc, const int* __restrict__ bcnt,
    unsigned* __restrict__ pmeta)
{
    int r = blockIdx.x & 7;
    int nstride = (int)(gridDim.x >> 3);
    for (int sb = (int)(blockIdx.x >> 3); sb < NEB; sb += nstride) {
        int c = bcnt[sb * 8 + r];
        const uint2* seg = buc + (size_t)sb * 2048 + r * 256;
        for (int i = threadIdx.x; i < c; i += 256) {
            uint2 t = seg[i];
            pmeta[t.x] = t.y;
        }
    }
}

// ---------------------------------------------------------------------------
// FUSED A materialization + STEP 1. A stored INT4 (R8-R10 proven).
// ---------------------------------------------------------------------------
__global__ __launch_bounds__(256) void amat_kernel(
    const unsigned* __restrict__ pmeta, const int* __restrict__ rowptr,
    const unsigned char* __restrict__ P8, const ushort* __restrict__ Qb,
    const float* __restrict__ Wxi, const float* __restrict__ bxi,
    const uint2* __restrict__ Hq0, const float* __restrict__ Bsum,
    unsigned* __restrict__ A4, uint2* __restrict__ HqOut)
{
    __shared__ float Wet2[NET * 64];     // 2*log2e*(Wxi[n][128+et]+bxi[n])
    int tid = threadIdx.x;
    for (int i = tid; i < NET * 64; i += 256) {
        int et = i >> 6, n = i & 63;
        Wet2[i] = 2.0f * LOG2E * (Wxi[n * KXW + 128 + et] + bxi[n]);
    }
    __syncthreads();

    int v = blockIdx.x * 4 + (tid >> 6);
    if (v >= V) return;
    int lane = tid & 63;
    int el = lane >> 3, s = lane & 7;

    const int off = rowptr[v];
    const int deg = rowptr[v + 1] - off;

    float q0, q1, q2, q3, q4, q5, q6, q7;
    {
        uint4 qu = *(const uint4*)(Qb + v * 64 + s * 8);
        const float B = 128.0f * SP, C = 2.0f * LOG2E;
        q0 = C * (bflo(qu.x) - B); q1 = C * (bfhi(qu.x) - B);
        q2 = C * (bflo(qu.y) - B); q3 = C * (bfhi(qu.y) - B);
        q4 = C * (bflo(qu.z) - B); q5 = C * (bfhi(qu.z) - B);
        q6 = C * (bflo(qu.w) - B); q7 = C * (bfhi(qu.w) - B);
    }

    float accD = 0.0f;                    // fused step-1 accumulator

    for (int base = 0; base < deg; base += 64) {
        // phase 1: this lane resolves edge (base+lane) — fully coalesced
        unsigned m_mine = 0;
        {
            int i1 = base + lane;
            if (i1 < deg) m_mine = pmeta[off + i1];
        }
        // phase 2: 8 edges per sub-round, meta via shfl broadcast
        int nb = deg - base;
        for (int k = 0; k * 8 + el < nb && k < 8; ++k) {
            int ib = k * 8 + el;
            int i = base + ib;
            unsigned m = __shfl(m_mine, ib);
            int src = (int)(m & 0x1FFFF);
            int et  = (int)((m >> 17) & 0xF);

            // issue all loads up front so they overlap the exp chain
            uint2 pu = *(const uint2*)(P8 + src * 64 + s * 8);
            const float4* w4 = (const float4*)(&Wet2[et * 64 + s * 8]);
            float4 wa = w4[0], wb = w4[1];
            uint2 hq = Hq0[src];

            float r0 = __builtin_amdgcn_rcpf(__builtin_amdgcn_exp2f(fmaf(ub0(pu.x), S2L, q0 + wa.x)) + 1.0f);
            float r1 = __builtin_amdgcn_rcpf(__builtin_amdgcn_exp2f(fmaf(ub1(pu.x), S2L, q1 + wa.y)) + 1.0f);
            float r2 = __builtin_amdgcn_rcpf(__builtin_amdgcn_exp2f(fmaf(ub2(pu.x), S2L, q2 + wa.z)) + 1.0f);
            float r3 = __builtin_amdgcn_rcpf(__builtin_amdgcn_exp2f(fmaf(ub3(pu.x), S2L, q3 + wa.w)) + 1.0f);
            float r4 = __builtin_amdgcn_rcpf(__builtin_amdgcn_exp2f(fmaf(ub0(pu.y), S2L, q4 + wb.x)) + 1.0f);
            float r5 = __builtin_amdgcn_rcpf(__builtin_amdgcn_exp2f(fmaf(ub1(pu.y), S2L, q5 + wb.y)) + 1.0f);
            float r6 = __builtin_amdgcn_rcpf(__builtin_amdgcn_exp2f(fmaf(ub2(pu.y), S2L, q6 + wb.z)) + 1.0f);
            float r7 = __builtin_amdgcn_rcpf(__builtin_amdgcn_exp2f(fmaf(ub3(pu.y), S2L, q7 + wb.w)) + 1.0f);

            // n = round(7*tanh) = round(7 - 14*r), in [-7,7]
            int n0 = (int)rintf(fmaf(r0, -14.0f, 7.0f));
            int n1 = (int)rintf(fmaf(r1, -14.0f, 7.0f));
            int n2 = (int)rintf(fmaf(r2, -14.0f, 7.0f));
            int n3 = (int)rintf(fmaf(r3, -14.0f, 7.0f));
            int n4 = (int)rintf(fmaf(r4, -14.0f, 7.0f));
            int n5 = (int)rintf(fmaf(r5, -14.0f, 7.0f));
            int n6 = (int)rintf(fmaf(r6, -14.0f, 7.0f));
            int n7 = (int)rintf(fmaf(r7, -14.0f, 7.0f));

            unsigned w = ((unsigned)n0 & 0xFu)        | (((unsigned)n1 & 0xFu) << 4)
                       | (((unsigned)n2 & 0xFu) << 8)  | (((unsigned)n3 & 0xFu) << 12)
                       | (((unsigned)n4 & 0xFu) << 16) | (((unsigned)n5 & 0xFu) << 20)
                       | (((unsigned)n6 & 0xFu) << 24) | (((unsigned)n7 & 0xFu) << 28);
            A4[(unsigned)(off + i) * 8u + (unsigned)s] = w;

            // fused step 1: same sdot8 form the steps use (A row . Hq0[src])
            int dd = dot8i4(w, hq.x, 0);
            float rdg = __builtin_amdgcn_rcpf((float)((int)(m >> 21) + 1));
            accD = fmaf((float)dd, __uint_as_float(hq.y) * rdg, accD);
        }
    }
    // reduce over el lanes (lane = el*8 + s)
    accD += __shfl_xor(accD, 8);  accD += __shfl_xor(accD, 16); accD += __shfl_xor(accD, 32);
    float h1v = accD * K7 + Bsum[v * 8 + s];

    // quantize H1 row to int4 with per-node scale
    float mx = fabsf(h1v);
    mx = fmaxf(mx, __shfl_xor(mx, 1));
    mx = fmaxf(mx, __shfl_xor(mx, 2));
    mx = fmaxf(mx, __shfl_xor(mx, 4));           // max over s within el group
    float si = (mx > 0.0f) ? 7.0f / mx : 0.0f;
    unsigned nib = (unsigned)((int)rintf(h1v * si)) & 0xFu;
    unsigned b1 = __shfl(nib, lane + 1), b2 = __shfl(nib, lane + 2), b3 = __shfl(nib, lane + 3);
    unsigned b4 = __shfl(nib, lane + 4), b5 = __shfl(nib, lane + 5);
    unsigned b6 = __shfl(nib, lane + 6), b7 = __shfl(nib, lane + 7);
    if (lane == 0) {
        unsigned w = nib | (b1 << 4) | (b2 << 8) | (b3 << 12)
                   | (b4 << 16) | (b5 << 20) | (b6 << 24) | (b7 << 28);
        HqOut[v] = make_uint2(w, __float_as_uint(mx * (1.0f / 7.0f)));
    }
}

// ---------------------------------------------------------------------------
// Light step, QUAD-PER-NODE, int4, 4x-UNROLLED: edge quads with independent
// load batches (12 loads in flight) + 4 accumulator chains. Runs 3x.
// ---------------------------------------------------------------------------
__global__ __launch_bounds__(256) void step_kernel(
    const uint2* __restrict__ HqIn, uint2* __restrict__ HqOut,
    const unsigned* __restrict__ pmeta, const int* __restrict__ rowptr,
    const unsigned* __restrict__ A4, const float* __restrict__ Bsum,
    const float* __restrict__ W1, const float* __restrict__ b1,
    float* __restrict__ logitsOut, float* __restrict__ HfpOut)
{
    int v = blockIdx.x * 64 + (threadIdx.x >> 2);
    if (v >= V) return;
    int q = threadIdx.x & 3;

    int p0 = rowptr[v], p1 = rowptr[v + 1];

    float aE0 = 0.f, aO0 = 0.f, aE1 = 0.f, aO1 = 0.f;
    float aE2 = 0.f, aO2 = 0.f, aE3 = 0.f, aO3 = 0.f;
    int p = p0;
    for (; p + 3 < p1; p += 4) {
        unsigned m0 = pmeta[p],     m1 = pmeta[p + 1];
        unsigned m2 = pmeta[p + 2], m3 = pmeta[p + 3];
        uint2 au0 = *(const uint2*)(A4 + (unsigned)p * 8u + (unsigned)(q * 2));
        uint2 au1 = *(const uint2*)(A4 + (unsigned)(p + 1) * 8u + (unsigned)(q * 2));
        uint2 au2 = *(const uint2*)(A4 + (unsigned)(p + 2) * 8u + (unsigned)(q * 2));
        uint2 au3 = *(const uint2*)(A4 + (unsigned)(p + 3) * 8u + (unsigned)(q * 2));
        uint2 hq0 = HqIn[m0 & 0x1FFFFu];
        uint2 hq1 = HqIn[m1 & 0x1FFFFu];
        uint2 hq2 = HqIn[m2 & 0x1FFFFu];
        uint2 hq3 = HqIn[m3 & 0x1FFFFu];

        float sc0 = __uint_as_float(hq0.y) * __builtin_amdgcn_rcpf((float)((int)(m0 >> 21) + 1));
        aE0 = fmaf((float)dot8i4(au0.x, hq0.x, 0), sc0, aE0);
        aO0 = fmaf((float)dot8i4(au0.y, hq0.x, 0), sc0, aO0);
        float sc1 = __uint_as_float(hq1.y) * __builtin_amdgcn_rcpf((float)((int)(m1 >> 21) + 1));
        aE1 = fmaf((float)dot8i4(au1.x, hq1.x, 0), sc1, aE1);
        aO1 = fmaf((float)dot8i4(au1.y, hq1.x, 0), sc1, aO1);
        float sc2 = __uint_as_float(hq2.y) * __builtin_amdgcn_rcpf((float)((int)(m2 >> 21) + 1));
        aE2 = fmaf((float)dot8i4(au2.x, hq2.x, 0), sc2, aE2);
        aO2 = fmaf((float)dot8i4(au2.y, hq2.x, 0), sc2, aO2);
        float sc3 = __uint_as_float(hq3.y) * __builtin_amdgcn_rcpf((float)((int)(m3 >> 21) + 1));
        aE3 = fmaf((float)dot8i4(au3.x, hq3.x, 0), sc3, aE3);
        aO3 = fmaf((float)dot8i4(au3.y, hq3.x, 0), sc3, aO3);
    }
    for (; p + 1 < p1; p += 2) {
        unsigned m0 = pmeta[p], m1 = pmeta[p + 1];
        uint2 au0 = *(const uint2*)(A4 + (unsigned)p * 8u + (unsigned)(q * 2));
        uint2 au1 = *(const uint2*)(A4 + (unsigned)(p + 1) * 8u + (unsigned)(q * 2));
        uint2 hq0 = HqIn[m0 & 0x1FFFFu];
        uint2 hq1 = HqIn[m1 & 0x1FFFFu];
        float sc0 = __uint_as_float(hq0.y) * __builtin_amdgcn_rcpf((float)((int)(m0 >> 21) + 1));
        aE0 = fmaf((float)dot8i4(au0.x, hq0.x, 0), sc0, aE0);
        aO0 = fmaf((float)dot8i4(au0.y, hq0.x, 0), sc0, aO0);
        float sc1 = __uint_as_float(hq1.y) * __builtin_amdgcn_rcpf((float)((int)(m1 >> 21) + 1));
        aE1 = fmaf((float)dot8i4(au1.x, hq1.x, 0), sc1, aE1);
        aO1 = fmaf((float)dot8i4(au1.y, hq1.x, 0), sc1, aO1);
    }
    if (p < p1) {
        unsigned m = pmeta[p];
        uint2 au = *(const uint2*)(A4 + (unsigned)p * 8u + (unsigned)(q * 2));
        uint2 hq = HqIn[m & 0x1FFFFu];
        float sc = __uint_as_float(hq.y) * __builtin_amdgcn_rcpf((float)((int)(m >> 21) + 1));
        aE0 = fmaf((float)dot8i4(au.x, hq.x, 0), sc, aE0);
        aO0 = fmaf((float)dot8i4(au.y, hq.x, 0), sc, aO0);
    }
    float accE = (aE0 + aE1) + (aE2 + aE3);
    float accO = (aO0 + aO1) + (aO2 + aO3);

    float2 bs = *(const float2*)(Bsum + v * 8 + q * 2);
    float hE = accE * K7 + bs.x;
    float hO = accO * K7 + bs.y;

    // quantize H row to int4 with per-node scale (reduce within quad only)
    float mx = fmaxf(fabsf(hE), fabsf(hO));
    mx = fmaxf(mx, __shfl_xor(mx, 1));
    mx = fmaxf(mx, __shfl_xor(mx, 2));
    float si = (mx > 0.0f) ? 7.0f / mx : 0.0f;
    unsigned nE = (unsigned)((int)rintf(hE * si)) & 0xFu;
    unsigned nO = (unsigned)((int)rintf(hO * si)) & 0xFu;
    unsigned wq = (nE | (nO << 4)) << (8 * q); // nibbles 2q, 2q+1
    wq |= __shfl_xor(wq, 1);
    wq |= __shfl_xor(wq, 2);
    if (q == 0)
        HqOut[v] = make_uint2(wq, __float_as_uint(mx * (1.0f / 7.0f)));
    if (HfpOut != nullptr)
        *(float2*)(HfpOut + v * 8 + q * 2) = make_float2(hE, hO);
    if (logitsOut != nullptr) {
        float t = hE * W1[q * 2] + hO * W1[q * 2 + 1];
        t += __shfl_xor(t, 1); t += __shfl_xor(t, 2);
        if (q == 0) logitsOut[v] = t + b1[0];
    }
}

// ---------------------------------------------------------------------------
// Epilogue: ONLINE-SOFTMAX weighted sum (R10-proven).
// ---------------------------------------------------------------------------
__global__ __launch_bounds__(256) void sum_kernel(
    const float* __restrict__ H, const float* __restrict__ logits,
    float* __restrict__ partial)
{
    float m = -INFINITY, se = 0.0f;
    float sh[8] = {0, 0, 0, 0, 0, 0, 0, 0};
    for (int v = blockIdx.x * 256 + threadIdx.x; v < V; v += 64 * 256) {
        float l = logits[v];
        float mn = fmaxf(m, l);
        float a = __expf(m - mn);          // 0 when m == -inf
        float w = __expf(l - mn);
        se = se * a + w;
        const float4* H4 = (const float4*)(H + (size_t)v * 8);
        float4 h0 = H4[0], h1 = H4[1];
        sh[0] = sh[0] * a + w * h0.x; sh[1] = sh[1] * a + w * h0.y;
        sh[2] = sh[2] * a + w * h0.z; sh[3] = sh[3] * a + w * h0.w;
        sh[4] = sh[4] * a + w * h1.x; sh[5] = sh[5] * a + w * h1.y;
        sh[6] = sh[6] * a + w * h1.z; sh[7] = sh[7] * a + w * h1.w;
        m = mn;
    }
    // butterfly combine across 64 lanes
    #pragma unroll
    for (int o = 1; o < 64; o <<= 1) {
        float mo = __shfl_xor(m, o), seo = __shfl_xor(se, o);
        float sho[8];
        #pragma unroll
        for (int i = 0; i < 8; ++i) sho[i] = __shfl_xor(sh[i], o);
        float mn = fmaxf(m, mo);
        float a = __expf(m - mn), b = __expf(mo - mn);
        se = se * a + seo * b;
        #pragma unroll
        for (int i = 0; i < 8; ++i) sh[i] = sh[i] * a + sho[i] * b;
        m = mn;
    }
    // cross-wave combine via LDS (4 waves)
    __shared__ float sm[4][10];
    int wv = threadIdx.x >> 6;
    if ((threadIdx.x & 63) == 0) {
        sm[wv][0] = m; sm[wv][9] = se;
        #pragma unroll
        for (int i = 0; i < 8; ++i) sm[wv][1 + i] = sh[i];
    }
    __syncthreads();
    if (threadIdx.x == 0) {
        float M = sm[0][0], SE = 0.0f, SH[8] = {0, 0, 0, 0, 0, 0, 0, 0};
        #pragma unroll
        for (int w2 = 1; w2 < 4; ++w2) M = fmaxf(M, sm[w2][0]);
        #pragma unroll
        for (int w2 = 0; w2 < 4; ++w2) {
            float a = __expf(sm[w2][0] - M);
            SE += sm[w2][9] * a;
            #pragma unroll
            for (int i = 0; i < 8; ++i) SH[i] += sm[w2][1 + i] * a;
        }
        partial[blockIdx.x * 12 + 0] = M;
        partial[blockIdx.x * 12 + 9] = SE;
        #pragma unroll
        for (int i = 0; i < 8; ++i) partial[blockIdx.x * 12 + 1 + i] = SH[i];
    }
}

__global__ void final_kernel(const float* __restrict__ partial, float* __restrict__ out)
{
    int lane = threadIdx.x;               // 64 threads
    float m = partial[lane * 12 + 0];
    float se = partial[lane * 12 + 9];
    float sh[8];
    #pragma unroll
    for (int i = 0; i < 8; ++i) sh[i] = partial[lane * 12 + 1 + i];
    #pragma unroll
    for (int o = 1; o < 64; o <<= 1) {
        float mo = __shfl_xor(m, o), seo = __shfl_xor(se, o);
        float sho[8];
        #pragma unroll
        for (int i = 0; i < 8; ++i) sho[i] = __shfl_xor(sh[i], o);
        float mn = fmaxf(m, mo);
        float a = __expf(m - mn), b = __expf(mo - mn);
        se = se * a + seo * b;
        #pragma unroll
        for (int i = 0; i < 8; ++i) sh[i] = sh[i] * a + sho[i] * b;
        m = mn;
    }
    if (lane < 8) out[lane] = tanhf(sh[lane] / se);
}

// ---------------------------------------------------------------------------
extern "C" void kernel_launch(void* const* d_in, const int* in_sizes, int n_in,
                              void* d_out, int out_size, void* d_ws, size_t ws_size,
                              hipStream_t stream)
{
    const float* feat  = (const float*)d_in[0];
    const int*   xnode = (const int*)d_in[1];
    const int*   xneis = (const int*)d_in[2];
    const int*   etype = (const int*)d_in[3];
    const float* dg    = (const float*)d_in[4];
    const float* Hinit = (const float*)d_in[5];
    const float* Wxi   = (const float*)d_in[6];
    const float* bxi   = (const float*)d_in[7];
    const float* Wrou  = (const float*)d_in[8];
    const float* brou  = (const float*)d_in[9];
    const float* W1    = (const float*)d_in[10];
    const float* b1    = (const float*)d_in[11];

    char* ws = (char*)d_ws;
    auto alloc = [&](size_t bytes) -> char* {
        char* p = ws; ws += (bytes + 255) & ~(size_t)255; return p;
    };
    unsigned* A4      = (unsigned*)alloc((size_t)E * 32);      // 51.2 MB int4 A
    uint2*    buc     = (uint2*)alloc((size_t)NEB * 2048 * 8); // 102.4 MB scatter buckets
    unsigned char* P8 = (unsigned char*)alloc((size_t)V * 64); // 6.4 MB int8 P
    ushort*   Qb      = (ushort*)alloc((size_t)V * 64 * 2);    // 12.8 MB bf16 Q
    unsigned* pmeta   = (unsigned*)alloc((size_t)E * 4);       // 6.4 MB CSR meta
    int*      rank0   = (int*)alloc((size_t)E * 4);            // 6.4 MB per-edge rank
    int*      countg  = (int*)alloc((size_t)GN * V * 4);       // 3.2 MB XCD-local counts
    int*      offg    = (int*)alloc((size_t)GN * V * 4);       // 3.2 MB group offsets
    int*      bcnt    = (int*)alloc((size_t)NEB * 8 * 4);      // 0.2 MB bucket counts
    int*      scanned = (int*)alloc((size_t)V * 4);
    int*      rowptr  = (int*)alloc((size_t)(V + 1) * 4);
    int*      bsumT   = (int*)alloc(512 * 4);
    int*      topsT   = (int*)alloc(512 * 4);
    uint2*    Hq0     = (uint2*)alloc((size_t)V * 8);          // int4 Hinit + scale
    uint2*    HqA     = (uint2*)alloc((size_t)V * 8);
    uint2*    HqB     = (uint2*)alloc((size_t)V * 8);
    float*    Hfp     = (float*)alloc((size_t)V * 8 * 4);      // fp32 H (last step)
    float*    Bsum    = (float*)alloc((size_t)V * 8 * 4);
    float*    logits  = (float*)alloc((size_t)V * 4);
    float*    spart   = (float*)alloc(64 * 12 * 4);

    hipMemsetAsync(countg, 0, (size_t)GN * V * 4, stream);
    // fused: histogram+rank (blocks < NEB) overlapped with PQ GEMM
    histg_pq_kernel<<<NEB + NPQ, 256, 0, stream>>>(xneis, countg, rank0,
                                                   feat, Wxi, P8, Qb);
    // fused: offg fold + scan + bias-sum + Hq0 quantize
    scanV_bsum_kernel<<<NB, 256, 0, stream>>>(countg, offg, scanned, bsumT,
                                              feat, Wrou, brou, Hinit,
                                              Bsum, Hq0);
    scan_tops_kernel<<<1, 512, 0, stream>>>(bsumT, topsT, rowptr);
    add_offsets_kernel<<<NB, 256, 0, stream>>>(scanned, topsT, rowptr);
    scatterA_kernel<<<NEB, 256, 0, stream>>>(xnode, xneis, etype, dg,
                                             rowptr, offg, rank0, buc, bcnt);
    drain_kernel<<<2048, 256, 0, stream>>>(buc, bcnt, pmeta);
    // amat + fused step 1: writes int4 A and int4 H1 in one pass
    amat_kernel<<<(V + 3) / 4, 256, 0, stream>>>(pmeta, rowptr, P8, Qb, Wxi, bxi,
                                                 Hq0, Bsum, A4, HqA);

    // steps 2..4 (quad-per-node, int4, 4x-unrolled)
    const uint2* Hcur = HqA;
    uint2* bufs[2] = {HqB, HqA};
    for (int t = 0; t < 3; ++t) {
        uint2* Hn = bufs[t & 1];
        float* lg  = (t == 2) ? logits : nullptr;
        float* hf  = (t == 2) ? Hfp : nullptr;
        step_kernel<<<(V + 63) / 64, 256, 0, stream>>>(Hcur, Hn, pmeta, rowptr,
                                                       A4, Bsum, W1, b1, lg, hf);
        Hcur = Hn;
    }

    sum_kernel<<<64, 256, 0, stream>>>(Hfp, logits, spart);
    final_kernel<<<1, 64, 0, stream>>>(spart, (float*)d_out);
}

// Round 12
// 389.407 us; speedup vs baseline: 1.1797x; 1.0141x over previous
//
#include <hip/hip_runtime.h>
#include <hip/hip_bf16.h>

constexpr int V   = 100000;
constexpr int E   = 1600000;
constexpr int NET = 10;
constexpr int KXW = 138;              // W_xi row length (2*64+10)
constexpr int NB  = (V + 255) / 256;  // 391 blocks over nodes
constexpr int GN  = 8;                // count groups (= XCDs)
constexpr int NEB = E / 256;          // 6250 edge blocks (exact)
constexpr int NPQ = (V / 16 + 3) / 4; // 1563 pq blocks
constexpr float MUS   = 0.1125f;      // MU / S
constexpr float SP    = 0.025f;       // int8 P scale
constexpr float LOG2E = 1.44269504f;
constexpr float S2L   = 2.0f * SP * LOG2E;   // int8 P step in exp2 domain
constexpr float K7    = MUS / 7.0f;          // int4 A decode scale (x 1/dg per edge)

typedef __attribute__((ext_vector_type(8))) short short8;
typedef __attribute__((ext_vector_type(4))) float float4v;

__device__ __forceinline__ float fast_tanh(float x) {
    return 1.0f - 2.0f * __builtin_amdgcn_rcpf(__expf(2.0f * x) + 1.0f);
}
__device__ __forceinline__ float bflo(unsigned u) { return __uint_as_float(u << 16); }
__device__ __forceinline__ float bfhi(unsigned u) { return __uint_as_float(u & 0xffff0000u); }
__device__ __forceinline__ short f2bf(float x) {
    union { __hip_bfloat16 b; short s; } u; u.b = __float2bfloat16(x); return u.s;
}

__device__ __forceinline__ float ub0(unsigned u) {
#if __has_builtin(__builtin_amdgcn_cvt_f32_ubyte0)
    return __builtin_amdgcn_cvt_f32_ubyte0(u);
#else
    return (float)(u & 0xff);
#endif
}
__device__ __forceinline__ float ub1(unsigned u) {
#if __has_builtin(__builtin_amdgcn_cvt_f32_ubyte1)
    return __builtin_amdgcn_cvt_f32_ubyte1(u);
#else
    return (float)((u >> 8) & 0xff);
#endif
}
__device__ __forceinline__ float ub2(unsigned u) {
#if __has_builtin(__builtin_amdgcn_cvt_f32_ubyte2)
    return __builtin_amdgcn_cvt_f32_ubyte2(u);
#else
    return (float)((u >> 16) & 0xff);
#endif
}
__device__ __forceinline__ float ub3(unsigned u) {
#if __has_builtin(__builtin_amdgcn_cvt_f32_ubyte3)
    return __builtin_amdgcn_cvt_f32_ubyte3(u);
#else
    return (float)(u >> 24);
#endif
}

// int4 dot8: D = sum of 8 signed-nibble products + C (v_dot8_i32_i4)
__device__ __forceinline__ int dot8i4(unsigned a, unsigned b, int c) {
#if __has_builtin(__builtin_amdgcn_sdot8)
    return __builtin_amdgcn_sdot8((int)a, (int)b, c, false);
#else
    int r = c;
    #pragma unroll
    for (int j = 0; j < 8; ++j) {
        int av = ((int)(a << (28 - 4 * j))) >> 28;
        int bv = ((int)(b << (28 - 4 * j))) >> 28;
        r += av * bv;
    }
    return r;
#endif
}

// ---------------------------------------------------------------------------
// SHADOW kernel: three independent block ranges.
//  [0, NEB):        XCD-local histogram + rank (atomic-throughput bound,
//                   g = blockIdx&7, R6-R11 determinism class)
//  [NEB, NEB+NPQ):  PQ MFMA GEMM (rides in the atomic latency shadow)
//  [NEB+NPQ, +NB):  T8[v] = tanh(Wrou.feat+brou) (count-independent part of
//                   Bsum) + int4 Hq0 quantize of Hinit.
// ---------------------------------------------------------------------------
__global__ __launch_bounds__(256) void shadow_kernel(
    const int* __restrict__ xneis, int* __restrict__ countg,
    int* __restrict__ rank0,
    const float* __restrict__ feat, const float* __restrict__ Wxi,
    unsigned char* __restrict__ P8, ushort* __restrict__ Qb,
    const float* __restrict__ Wrou, const float* __restrict__ brou,
    const float* __restrict__ Hinit, float* __restrict__ T8,
    uint2* __restrict__ Hq0)
{
    if (blockIdx.x < NEB) {
        int e = blockIdx.x * 256 + threadIdx.x;   // E = NEB*256 exact
        int g = blockIdx.x & (GN - 1);
        int nr = xneis[e];
        if (nr < V) rank0[e] = atomicAdd(&countg[g * V + nr], 1);
        return;
    }
    if (blockIdx.x < NEB + NPQ) {
        // ---- PQ part ----
        int bid = blockIdx.x - NEB;
        const int lane = threadIdx.x & 63, wave = threadIdx.x >> 6;
        const int quad = lane >> 4, l16 = lane & 15;

        short8 bP[4][2], bQ[4][2];
        #pragma unroll
        for (int nt = 0; nt < 4; ++nt) {
            #pragma unroll
            for (int ks = 0; ks < 2; ++ks) {
                const float* wp = Wxi + (size_t)(nt * 16 + l16) * KXW + ks * 32 + quad * 8;
                short8 p, q;
                #pragma unroll
                for (int j = 0; j < 8; ++j) { p[j] = f2bf(wp[j]); q[j] = f2bf(wp[64 + j]); }
                bP[nt][ks] = p; bQ[nt][ks] = q;
            }
        }

        int t = bid * 4 + wave;
        if (t >= V / 16) return;
        int v0 = t * 16;

        const float* fp = feat + (size_t)(v0 + l16) * 64 + quad * 8;
        short8 a0, a1;
        #pragma unroll
        for (int j = 0; j < 8; ++j) { a0[j] = f2bf(fp[j]); a1[j] = f2bf(fp[32 + j]); }

        float4v accP[4], accQ[4];
        #pragma unroll
        for (int nt = 0; nt < 4; ++nt) {
            float4v z = {0.f, 0.f, 0.f, 0.f};
            z = __builtin_amdgcn_mfma_f32_16x16x32_bf16(a0, bP[nt][0], z, 0, 0, 0);
            z = __builtin_amdgcn_mfma_f32_16x16x32_bf16(a1, bP[nt][1], z, 0, 0, 0);
            accP[nt] = z;
            float4v w = {0.f, 0.f, 0.f, 0.f};
            w = __builtin_amdgcn_mfma_f32_16x16x32_bf16(a0, bQ[nt][0], w, 0, 0, 0);
            w = __builtin_amdgcn_mfma_f32_16x16x32_bf16(a1, bQ[nt][1], w, 0, 0, 0);
            accQ[nt] = w;
        }

        #pragma unroll
        for (int r = 0; r < 4; ++r) {
            int row = v0 + quad * 4 + r;
            #pragma unroll
            for (int nt = 0; nt < 4; ++nt) {
                int col = nt * 16 + l16;
                int q8 = (int)rintf(accP[nt][r] * (1.0f / SP)) + 128;
                q8 = min(max(q8, 0), 255);
                P8[row * 64 + col] = (unsigned char)q8;
                Qb[row * 64 + col] = (ushort)f2bf(accQ[nt][r]);
            }
        }
        return;
    }
    // ---- T8 + Hq0 part ----
    {
        __shared__ float Wl[512];
        __shared__ float bl[8];
        int tid = threadIdx.x;
        for (int i = tid; i < 512; i += 256) Wl[i] = Wrou[i];
        if (tid < 8) bl[tid] = brou[tid];
        __syncthreads();

        int v = (blockIdx.x - NEB - NPQ) * 256 + tid;
        if (v >= V) return;

        float out[8] = {0, 0, 0, 0, 0, 0, 0, 0};
        if (v >= 1) {                             // node 0 never has edges
            const float4* f4 = (const float4*)(feat + (size_t)(v - 1) * 64);
            float acc[8];
            #pragma unroll
            for (int ss = 0; ss < 8; ++ss) acc[ss] = bl[ss];
            #pragma unroll 4
            for (int k = 0; k < 16; ++k) {
                float4 x = f4[k];
                #pragma unroll
                for (int ss = 0; ss < 8; ++ss) {
                    const float* w = &Wl[ss * 64 + k * 4];
                    acc[ss] += x.x * w[0] + x.y * w[1] + x.z * w[2] + x.w * w[3];
                }
            }
            #pragma unroll
            for (int ss = 0; ss < 8; ++ss) out[ss] = fast_tanh(acc[ss]);
        }
        float4* O = (float4*)(T8 + (size_t)v * 8);
        O[0] = make_float4(out[0], out[1], out[2], out[3]);
        O[1] = make_float4(out[4], out[5], out[6], out[7]);

        // quantize Hinit row to int4 nibbles + per-node scale
        const float4* Hh4 = (const float4*)(Hinit + (size_t)v * 8);
        float4 h0 = Hh4[0], h1 = Hh4[1];
        float hv[8] = {h0.x, h0.y, h0.z, h0.w, h1.x, h1.y, h1.z, h1.w};
        float mx = 0.0f;
        #pragma unroll
        for (int i = 0; i < 8; ++i) mx = fmaxf(mx, fabsf(hv[i]));
        float si = (mx > 0.0f) ? 7.0f / mx : 0.0f;
        unsigned w = 0;
        #pragma unroll
        for (int i = 0; i < 8; ++i)
            w |= ((unsigned)((int)rintf(hv[i] * si)) & 0xFu) << (4 * i);
        Hq0[v] = make_uint2(w, __float_as_uint(mx * (1.0f / 7.0f)));
    }
}

// ---------------------------------------------------------------------------
// scanV: fold group slices (offg) + blockwise-exclusive scan + Bsum = cnt*T8.
// ---------------------------------------------------------------------------
__global__ __launch_bounds__(256) void scanV_kernel(
    const int* __restrict__ countg, int* __restrict__ offg,
    int* __restrict__ scanned, int* __restrict__ bsumT,
    const float* __restrict__ T8, float* __restrict__ Bsum)
{
    __shared__ int s[256];
    int tid = threadIdx.x;
    int v = blockIdx.x * 256 + tid;
    int c = 0;
    if (v < V) {
        int run = 0;
        #pragma unroll
        for (int g = 0; g < GN; ++g) {
            offg[g * V + v] = run;
            run += countg[g * V + v];
        }
        c = run;
    }
    s[tid] = c; __syncthreads();
    #pragma unroll
    for (int off = 1; off < 256; off <<= 1) {
        int t = (tid >= off) ? s[tid - off] : 0;
        __syncthreads();
        s[tid] += t;
        __syncthreads();
    }
    if (v < V) scanned[v] = s[tid] - c;
    if (tid == 255) bsumT[blockIdx.x] = s[255];

    if (v < V) {
        float fc = (float)c;
        const float4* T4 = (const float4*)(T8 + (size_t)v * 8);
        float4 t0 = T4[0], t1 = T4[1];
        float4* O = (float4*)(Bsum + (size_t)v * 8);
        O[0] = make_float4(fc * t0.x, fc * t0.y, fc * t0.z, fc * t0.w);
        O[1] = make_float4(fc * t1.x, fc * t1.y, fc * t1.z, fc * t1.w);
    }
}

// rowptr: each block redundantly scans the NB block-sums in LDS, then writes
// its 256-node rowptr slice (replaces scan_tops + add_offsets, one launch).
__global__ __launch_bounds__(512) void rowptr_kernel(
    const int* __restrict__ bsumT, const int* __restrict__ scanned,
    int* __restrict__ rowptr)
{
    __shared__ int s[512];
    __shared__ int tot;
    int tid = threadIdx.x;
    int val = (tid < NB) ? bsumT[tid] : 0;
    s[tid] = val; __syncthreads();
    #pragma unroll
    for (int off = 1; off < 512; off <<= 1) {
        int t = (tid >= off) ? s[tid - off] : 0;
        __syncthreads();
        s[tid] += t;
        __syncthreads();
    }
    if (tid == NB - 1) tot = s[tid];             // inclusive total
    __syncthreads();
    int top = s[blockIdx.x] - bsumT[blockIdx.x]; // exclusive prefix for my block
    if (tid < 256) {
        int i = blockIdx.x * 256 + tid;
        if (i < V) rowptr[i] = scanned[i] + top;
    }
    if (blockIdx.x == 0 && tid == 0) rowptr[V] = tot;
}

// ---------------------------------------------------------------------------
// Two-hop scatter (R9-R11, tripwire-proven).
// ---------------------------------------------------------------------------
__global__ __launch_bounds__(256) void scatterA_kernel(
    const int* __restrict__ xnode, const int* __restrict__ xneis,
    const int* __restrict__ etype, const float* __restrict__ dg,
    const int* __restrict__ rowptr, const int* __restrict__ offg,
    const int* __restrict__ rank0, uint2* __restrict__ buc,
    int* __restrict__ bcnt)
{
    __shared__ int wcnt[4][8];
    __shared__ int woff[4][8];
    int tid = threadIdx.x;
    int lane = tid & 63, wv = tid >> 6;
    int e = blockIdx.x * 256 + tid;              // E = 6250*256 exact
    int g = blockIdx.x & (GN - 1);

    int nr = xneis[e];
    bool keep = (nr < V);
    int p = -1, r = 0;
    if (keep) {
        p = rowptr[nr] + offg[g * V + nr] + rank0[e];
        r = p >> 18;                             // 0..7 since kept edges < 2^21
    }

    // in-wave rank among same-range lanes (deterministic)
    unsigned rnk = 0;
    #pragma unroll
    for (int r8 = 0; r8 < 8; ++r8) {
        unsigned long long m = __ballot(keep && (r == r8));
        if (keep && r == r8)
            rnk = (unsigned)__popcll(m & ((1ull << lane) - 1ull));
        if (lane == 0) wcnt[wv][r8] = (int)__popcll(m);
    }
    __syncthreads();
    if (tid < 8) {
        int run = 0;
        #pragma unroll
        for (int w = 0; w < 4; ++w) { woff[w][tid] = run; run += wcnt[w][tid]; }
        bcnt[blockIdx.x * 8 + tid] = run;
    }
    __syncthreads();

    if (keep) {
        unsigned src = (unsigned)(xnode[e] - 1);
        unsigned et  = (unsigned)(etype[e] - 1);
        unsigned dgi = (unsigned)dg[e] - 1;      // 0..63, exact
        unsigned meta = src | (et << 17) | (dgi << 21);
        int slot = blockIdx.x * 2048 + r * 256 + woff[wv][r] + (int)rnk;
        buc[slot] = make_uint2((unsigned)p, meta);
    }
}

// Hop B: blocks with blockIdx&7==r drain range r (XCD-local pmeta window).
__global__ __launch_bounds__(256) void drain_kernel(
    const uint2* __restrict__ buc, const int* __restrict__ bcnt,
    unsigned* __restrict__ pmeta)
{
    int r = blockIdx.x & 7;
    int nstride = (int)(gridDim.x >> 3);
    for (int sb = (int)(blockIdx.x >> 3); sb < NEB; sb += nstride) {
        int c = bcnt[sb * 8 + r];
        const uint2* seg = buc + (size_t)sb * 2048 + r * 256;
        for (int i = threadIdx.x; i < c; i += 256) {
            uint2 t = seg[i];
            pmeta[t.x] = t.y;
        }
    }
}

// ---------------------------------------------------------------------------
// FUSED A materialization + STEP 1. A stored INT4 (R8-R11 proven).
// ---------------------------------------------------------------------------
__global__ __launch_bounds__(256) void amat_kernel(
    const unsigned* __restrict__ pmeta, const int* __restrict__ rowptr,
    const unsigned char* __restrict__ P8, const ushort* __restrict__ Qb,
    const float* __restrict__ Wxi, const float* __restrict__ bxi,
    const uint2* __restrict__ Hq0, const float* __restrict__ Bsum,
    unsigned* __restrict__ A4, uint2* __restrict__ HqOut)
{
    __shared__ float Wet2[NET * 64];     // 2*log2e*(Wxi[n][128+et]+bxi[n])
    int tid = threadIdx.x;
    for (int i = tid; i < NET * 64; i += 256) {
        int et = i >> 6, n = i & 63;
        Wet2[i] = 2.0f * LOG2E * (Wxi[n * KXW + 128 + et] + bxi[n]);
    }
    __syncthreads();

    int v = blockIdx.x * 4 + (tid >> 6);
    if (v >= V) return;
    int lane = tid & 63;
    int el = lane >> 3, s = lane & 7;

    const int off = rowptr[v];
    const int deg = rowptr[v + 1] - off;

    float q0, q1, q2, q3, q4, q5, q6, q7;
    {
        uint4 qu = *(const uint4*)(Qb + v * 64 + s * 8);
        const float B = 128.0f * SP, C = 2.0f * LOG2E;
        q0 = C * (bflo(qu.x) - B); q1 = C * (bfhi(qu.x) - B);
        q2 = C * (bflo(qu.y) - B); q3 = C * (bfhi(qu.y) - B);
        q4 = C * (bflo(qu.z) - B); q5 = C * (bfhi(qu.z) - B);
        q6 = C * (bflo(qu.w) - B); q7 = C * (bfhi(qu.w) - B);
    }

    float accD = 0.0f;                    // fused step-1 accumulator

    for (int base = 0; base < deg; base += 64) {
        // phase 1: this lane resolves edge (base+lane) — fully coalesced
        unsigned m_mine = 0;
        {
            int i1 = base + lane;
            if (i1 < deg) m_mine = pmeta[off + i1];
        }
        // phase 2: 8 edges per sub-round, meta via shfl broadcast
        int nb = deg - base;
        for (int k = 0; k * 8 + el < nb && k < 8; ++k) {
            int ib = k * 8 + el;
            int i = base + ib;
            unsigned m = __shfl(m_mine, ib);
            int src = (int)(m & 0x1FFFF);
            int et  = (int)((m >> 17) & 0xF);

            // issue all loads up front so they overlap the exp chain
            uint2 pu = *(const uint2*)(P8 + src * 64 + s * 8);
            const float4* w4 = (const float4*)(&Wet2[et * 64 + s * 8]);
            float4 wa = w4[0], wb = w4[1];
            uint2 hq = Hq0[src];

            float r0 = __builtin_amdgcn_rcpf(__builtin_amdgcn_exp2f(fmaf(ub0(pu.x), S2L, q0 + wa.x)) + 1.0f);
            float r1 = __builtin_amdgcn_rcpf(__builtin_amdgcn_exp2f(fmaf(ub1(pu.x), S2L, q1 + wa.y)) + 1.0f);
            float r2 = __builtin_amdgcn_rcpf(__builtin_amdgcn_exp2f(fmaf(ub2(pu.x), S2L, q2 + wa.z)) + 1.0f);
            float r3 = __builtin_amdgcn_rcpf(__builtin_amdgcn_exp2f(fmaf(ub3(pu.x), S2L, q3 + wa.w)) + 1.0f);
            float r4 = __builtin_amdgcn_rcpf(__builtin_amdgcn_exp2f(fmaf(ub0(pu.y), S2L, q4 + wb.x)) + 1.0f);
            float r5 = __builtin_amdgcn_rcpf(__builtin_amdgcn_exp2f(fmaf(ub1(pu.y), S2L, q5 + wb.y)) + 1.0f);
            float r6 = __builtin_amdgcn_rcpf(__builtin_amdgcn_exp2f(fmaf(ub2(pu.y), S2L, q6 + wb.z)) + 1.0f);
            float r7 = __builtin_amdgcn_rcpf(__builtin_amdgcn_exp2f(fmaf(ub3(pu.y), S2L, q7 + wb.w)) + 1.0f);

            // n = round(7*tanh) = round(7 - 14*r), in [-7,7]
            int n0 = (int)rintf(fmaf(r0, -14.0f, 7.0f));
            int n1 = (int)rintf(fmaf(r1, -14.0f, 7.0f));
            int n2 = (int)rintf(fmaf(r2, -14.0f, 7.0f));
            int n3 = (int)rintf(fmaf(r3, -14.0f, 7.0f));
            int n4 = (int)rintf(fmaf(r4, -14.0f, 7.0f));
            int n5 = (int)rintf(fmaf(r5, -14.0f, 7.0f));
            int n6 = (int)rintf(fmaf(r6, -14.0f, 7.0f));
            int n7 = (int)rintf(fmaf(r7, -14.0f, 7.0f));

            unsigned w = ((unsigned)n0 & 0xFu)        | (((unsigned)n1 & 0xFu) << 4)
                       | (((unsigned)n2 & 0xFu) << 8)  | (((unsigned)n3 & 0xFu) << 12)
                       | (((unsigned)n4 & 0xFu) << 16) | (((unsigned)n5 & 0xFu) << 20)
                       | (((unsigned)n6 & 0xFu) << 24) | (((unsigned)n7 & 0xFu) << 28);
            A4[(unsigned)(off + i) * 8u + (unsigned)s] = w;

            // fused step 1: same sdot8 form the steps use (A row . Hq0[src])
            int dd = dot8i4(w, hq.x, 0);
            float rdg = __builtin_amdgcn_rcpf((float)((int)(m >> 21) + 1));
            accD = fmaf((float)dd, __uint_as_float(hq.y) * rdg, accD);
        }
    }
    // reduce over el lanes (lane = el*8 + s)
    accD += __shfl_xor(accD, 8);  accD += __shfl_xor(accD, 16); accD += __shfl_xor(accD, 32);
    float h1v = accD * K7 + Bsum[v * 8 + s];

    // quantize H1 row to int4 with per-node scale
    float mx = fabsf(h1v);
    mx = fmaxf(mx, __shfl_xor(mx, 1));
    mx = fmaxf(mx, __shfl_xor(mx, 2));
    mx = fmaxf(mx, __shfl_xor(mx, 4));           // max over s within el group
    float si = (mx > 0.0f) ? 7.0f / mx : 0.0f;
    unsigned nib = (unsigned)((int)rintf(h1v * si)) & 0xFu;
    unsigned b1 = __shfl(nib, lane + 1), b2 = __shfl(nib, lane + 2), b3 = __shfl(nib, lane + 3);
    unsigned b4 = __shfl(nib, lane + 4), b5 = __shfl(nib, lane + 5);
    unsigned b6 = __shfl(nib, lane + 6), b7 = __shfl(nib, lane + 7);
    if (lane == 0) {
        unsigned w = nib | (b1 << 4) | (b2 << 8) | (b3 << 12)
                   | (b4 << 16) | (b5 << 20) | (b6 << 24) | (b7 << 28);
        HqOut[v] = make_uint2(w, __float_as_uint(mx * (1.0f / 7.0f)));
    }
}

// ---------------------------------------------------------------------------
// Light step, QUAD-PER-NODE, int4, 4x-UNROLLED (R11-proven). Runs 3x.
// ---------------------------------------------------------------------------
__global__ __launch_bounds__(256) void step_kernel(
    const uint2* __restrict__ HqIn, uint2* __restrict__ HqOut,
    const unsigned* __restrict__ pmeta, const int* __restrict__ rowptr,
    const unsigned* __restrict__ A4, const float* __restrict__ Bsum,
    const float* __restrict__ W1, const float* __restrict__ b1,
    float* __restrict__ logitsOut, float* __restrict__ HfpOut)
{
    int v = blockIdx.x * 64 + (threadIdx.x >> 2);
    if (v >= V) return;
    int q = threadIdx.x & 3;

    int p0 = rowptr[v], p1 = rowptr[v + 1];

    float aE0 = 0.f, aO0 = 0.f, aE1 = 0.f, aO1 = 0.f;
    float aE2 = 0.f, aO2 = 0.f, aE3 = 0.f, aO3 = 0.f;
    int p = p0;
    for (; p + 3 < p1; p += 4) {
        unsigned m0 = pmeta[p],     m1 = pmeta[p + 1];
        unsigned m2 = pmeta[p + 2], m3 = pmeta[p + 3];
        uint2 au0 = *(const uint2*)(A4 + (unsigned)p * 8u + (unsigned)(q * 2));
        uint2 au1 = *(const uint2*)(A4 + (unsigned)(p + 1) * 8u + (unsigned)(q * 2));
        uint2 au2 = *(const uint2*)(A4 + (unsigned)(p + 2) * 8u + (unsigned)(q * 2));
        uint2 au3 = *(const uint2*)(A4 + (unsigned)(p + 3) * 8u + (unsigned)(q * 2));
        uint2 hq0 = HqIn[m0 & 0x1FFFFu];
        uint2 hq1 = HqIn[m1 & 0x1FFFFu];
        uint2 hq2 = HqIn[m2 & 0x1FFFFu];
        uint2 hq3 = HqIn[m3 & 0x1FFFFu];

        float sc0 = __uint_as_float(hq0.y) * __builtin_amdgcn_rcpf((float)((int)(m0 >> 21) + 1));
        aE0 = fmaf((float)dot8i4(au0.x, hq0.x, 0), sc0, aE0);
        aO0 = fmaf((float)dot8i4(au0.y, hq0.x, 0), sc0, aO0);
        float sc1 = __uint_as_float(hq1.y) * __builtin_amdgcn_rcpf((float)((int)(m1 >> 21) + 1));
        aE1 = fmaf((float)dot8i4(au1.x, hq1.x, 0), sc1, aE1);
        aO1 = fmaf((float)dot8i4(au1.y, hq1.x, 0), sc1, aO1);
        float sc2 = __uint_as_float(hq2.y) * __builtin_amdgcn_rcpf((float)((int)(m2 >> 21) + 1));
        aE2 = fmaf((float)dot8i4(au2.x, hq2.x, 0), sc2, aE2);
        aO2 = fmaf((float)dot8i4(au2.y, hq2.x, 0), sc2, aO2);
        float sc3 = __uint_as_float(hq3.y) * __builtin_amdgcn_rcpf((float)((int)(m3 >> 21) + 1));
        aE3 = fmaf((float)dot8i4(au3.x, hq3.x, 0), sc3, aE3);
        aO3 = fmaf((float)dot8i4(au3.y, hq3.x, 0), sc3, aO3);
    }
    for (; p + 1 < p1; p += 2) {
        unsigned m0 = pmeta[p], m1 = pmeta[p + 1];
        uint2 au0 = *(const uint2*)(A4 + (unsigned)p * 8u + (unsigned)(q * 2));
        uint2 au1 = *(const uint2*)(A4 + (unsigned)(p + 1) * 8u + (unsigned)(q * 2));
        uint2 hq0 = HqIn[m0 & 0x1FFFFu];
        uint2 hq1 = HqIn[m1 & 0x1FFFFu];
        float sc0 = __uint_as_float(hq0.y) * __builtin_amdgcn_rcpf((float)((int)(m0 >> 21) + 1));
        aE0 = fmaf((float)dot8i4(au0.x, hq0.x, 0), sc0, aE0);
        aO0 = fmaf((float)dot8i4(au0.y, hq0.x, 0), sc0, aO0);
        float sc1 = __uint_as_float(hq1.y) * __builtin_amdgcn_rcpf((float)((int)(m1 >> 21) + 1));
        aE1 = fmaf((float)dot8i4(au1.x, hq1.x, 0), sc1, aE1);
        aO1 = fmaf((float)dot8i4(au1.y, hq1.x, 0), sc1, aO1);
    }
    if (p < p1) {
        unsigned m = pmeta[p];
        uint2 au = *(const uint2*)(A4 + (unsigned)p * 8u + (unsigned)(q * 2));
        uint2 hq = HqIn[m & 0x1FFFFu];
        float sc = __uint_as_float(hq.y) * __builtin_amdgcn_rcpf((float)((int)(m >> 21) + 1));
        aE0 = fmaf((float)dot8i4(au.x, hq.x, 0), sc, aE0);
        aO0 = fmaf((float)dot8i4(au.y, hq.x, 0), sc, aO0);
    }
    float accE = (aE0 + aE1) + (aE2 + aE3);
    float accO = (aO0 + aO1) + (aO2 + aO3);

    float2 bs = *(const float2*)(Bsum + v * 8 + q * 2);
    float hE = accE * K7 + bs.x;
    float hO = accO * K7 + bs.y;

    // quantize H row to int4 with per-node scale (reduce within quad only)
    float mx = fmaxf(fabsf(hE), fabsf(hO));
    mx = fmaxf(mx, __shfl_xor(mx, 1));
    mx = fmaxf(mx, __shfl_xor(mx, 2));
    float si = (mx > 0.0f) ? 7.0f / mx : 0.0f;
    unsigned nE = (unsigned)((int)rintf(hE * si)) & 0xFu;
    unsigned nO = (unsigned)((int)rintf(hO * si)) & 0xFu;
    unsigned wq = (nE | (nO << 4)) << (8 * q); // nibbles 2q, 2q+1
    wq |= __shfl_xor(wq, 1);
    wq |= __shfl_xor(wq, 2);
    if (q == 0)
        HqOut[v] = make_uint2(wq, __float_as_uint(mx * (1.0f / 7.0f)));
    if (HfpOut != nullptr)
        *(float2*)(HfpOut + v * 8 + q * 2) = make_float2(hE, hO);
    if (logitsOut != nullptr) {
        float t = hE * W1[q * 2] + hO * W1[q * 2 + 1];
        t += __shfl_xor(t, 1); t += __shfl_xor(t, 2);
        if (q == 0) logitsOut[v] = t + b1[0];
    }
}

// ---------------------------------------------------------------------------
// Epilogue: ONLINE-SOFTMAX weighted sum (R10/R11-proven).
// ---------------------------------------------------------------------------
__global__ __launch_bounds__(256) void sum_kernel(
    const float* __restrict__ H, const float* __restrict__ logits,
    float* __restrict__ partial)
{
    float m = -INFINITY, se = 0.0f;
    float sh[8] = {0, 0, 0, 0, 0, 0, 0, 0};
    for (int v = blockIdx.x * 256 + threadIdx.x; v < V; v += 64 * 256) {
        float l = logits[v];
        float mn = fmaxf(m, l);
        float a = __expf(m - mn);          // 0 when m == -inf
        float w = __expf(l - mn);
        se = se * a + w;
        const float4* H4 = (const float4*)(H + (size_t)v * 8);
        float4 h0 = H4[0], h1 = H4[1];
        sh[0] = sh[0] * a + w * h0.x; sh[1] = sh[1] * a + w * h0.y;
        sh[2] = sh[2] * a + w * h0.z; sh[3] = sh[3] * a + w * h0.w;
        sh[4] = sh[4] * a + w * h1.x; sh[5] = sh[5] * a + w * h1.y;
        sh[6] = sh[6] * a + w * h1.z; sh[7] = sh[7] * a + w * h1.w;
        m = mn;
    }
    // butterfly combine across 64 lanes
    #pragma unroll
    for (int o = 1; o < 64; o <<= 1) {
        float mo = __shfl_xor(m, o), seo = __shfl_xor(se, o);
        float sho[8];
        #pragma unroll
        for (int i = 0; i < 8; ++i) sho[i] = __shfl_xor(sh[i], o);
        float mn = fmaxf(m, mo);
        float a = __expf(m - mn), b = __expf(mo - mn);
        se = se * a + seo * b;
        #pragma unroll
        for (int i = 0; i < 8; ++i) sh[i] = sh[i] * a + sho[i] * b;
        m = mn;
    }
    // cross-wave combine via LDS (4 waves)
    __shared__ float sm[4][10];
    int wv = threadIdx.x >> 6;
    if ((threadIdx.x & 63) == 0) {
        sm[wv][0] = m; sm[wv][9] = se;
        #pragma unroll
        for (int i = 0; i < 8; ++i) sm[wv][1 + i] = sh[i];
    }
    __syncthreads();
    if (threadIdx.x == 0) {
        float M = sm[0][0], SE = 0.0f, SH[8] = {0, 0, 0, 0, 0, 0, 0, 0};
        #pragma unroll
        for (int w2 = 1; w2 < 4; ++w2) M = fmaxf(M, sm[w2][0]);
        #pragma unroll
        for (int w2 = 0; w2 < 4; ++w2) {
            float a = __expf(sm[w2][0] - M);
            SE += sm[w2][9] * a;
            #pragma unroll
            for (int i = 0; i < 8; ++i) SH[i] += sm[w2][1 + i] * a;
        }
        partial[blockIdx.x * 12 + 0] = M;
        partial[blockIdx.x * 12 + 9] = SE;
        #pragma unroll
        for (int i = 0; i < 8; ++i) partial[blockIdx.x * 12 + 1 + i] = SH[i];
    }
}

__global__ void final_kernel(const float* __restrict__ partial, float* __restrict__ out)
{
    int lane = threadIdx.x;               // 64 threads
    float m = partial[lane * 12 + 0];
    float se = partial[lane * 12 + 9];
    float sh[8];
    #pragma unroll
    for (int i = 0; i < 8; ++i) sh[i] = partial[lane * 12 + 1 + i];
    #pragma unroll
    for (int o = 1; o < 64; o <<= 1) {
        float mo = __shfl_xor(m, o), seo = __shfl_xor(se, o);
        float sho[8];
        #pragma unroll
        for (int i = 0; i < 8; ++i) sho[i] = __shfl_xor(sh[i], o);
        float mn = fmaxf(m, mo);
        float a = __expf(m - mn), b = __expf(mo - mn);
        se = se * a + seo * b;
        #pragma unroll
        for (int i = 0; i < 8; ++i) sh[i] = sh[i] * a + sho[i] * b;
        m = mn;
    }
    if (lane < 8) out[lane] = tanhf(sh[lane] / se);
}

// ---------------------------------------------------------------------------
extern "C" void kernel_launch(void* const* d_in, const int* in_sizes, int n_in,
                              void* d_out, int out_size, void* d_ws, size_t ws_size,
                              hipStream_t stream)
{
    const float* feat  = (const float*)d_in[0];
    const int*   xnode = (const int*)d_in[1];
    const int*   xneis = (const int*)d_in[2];
    const int*   etype = (const int*)d_in[3];
    const float* dg    = (const float*)d_in[4];
    const float* Hinit = (const float*)d_in[5];
    const float* Wxi   = (const float*)d_in[6];
    const float* bxi   = (const float*)d_in[7];
    const float* Wrou  = (const float*)d_in[8];
    const float* brou  = (const float*)d_in[9];
    const float* W1    = (const float*)d_in[10];
    const float* b1    = (const float*)d_in[11];

    char* ws = (char*)d_ws;
    auto alloc = [&](size_t bytes) -> char* {
        char* p = ws; ws += (bytes + 255) & ~(size_t)255; return p;
    };
    unsigned* A4      = (unsigned*)alloc((size_t)E * 32);      // 51.2 MB int4 A
    uint2*    buc     = (uint2*)alloc((size_t)NEB * 2048 * 8); // 102.4 MB scatter buckets
    unsigned char* P8 = (unsigned char*)alloc((size_t)V * 64); // 6.4 MB int8 P
    ushort*   Qb      = (ushort*)alloc((size_t)V * 64 * 2);    // 12.8 MB bf16 Q
    unsigned* pmeta   = (unsigned*)alloc((size_t)E * 4);       // 6.4 MB CSR meta
    int*      rank0   = (int*)alloc((size_t)E * 4);            // 6.4 MB per-edge rank
    int*      countg  = (int*)alloc((size_t)GN * V * 4);       // 3.2 MB XCD-local counts
    int*      offg    = (int*)alloc((size_t)GN * V * 4);       // 3.2 MB group offsets
    int*      bcnt    = (int*)alloc((size_t)NEB * 8 * 4);      // 0.2 MB bucket counts
    int*      scanned = (int*)alloc((size_t)V * 4);
    int*      rowptr  = (int*)alloc((size_t)(V + 1) * 4);
    int*      bsumT   = (int*)alloc(512 * 4);
    float*    T8      = (float*)alloc((size_t)V * 8 * 4);      // tanh(Wrou.feat+brou)
    uint2*    Hq0     = (uint2*)alloc((size_t)V * 8);          // int4 Hinit + scale
    uint2*    HqA     = (uint2*)alloc((size_t)V * 8);
    uint2*    HqB     = (uint2*)alloc((size_t)V * 8);
    float*    Hfp     = (float*)alloc((size_t)V * 8 * 4);      // fp32 H (last step)
    float*    Bsum    = (float*)alloc((size_t)V * 8 * 4);
    float*    logits  = (float*)alloc((size_t)V * 4);
    float*    spart   = (float*)alloc(64 * 12 * 4);

    hipMemsetAsync(countg, 0, (size_t)GN * V * 4, stream);
    // shadow: histogram+rank || PQ GEMM || T8 + Hq0 quantize
    shadow_kernel<<<NEB + NPQ + NB, 256, 0, stream>>>(
        xneis, countg, rank0, feat, Wxi, P8, Qb,
        Wrou, brou, Hinit, T8, Hq0);
    scanV_kernel<<<NB, 256, 0, stream>>>(countg, offg, scanned, bsumT, T8, Bsum);
    rowptr_kernel<<<NB, 512, 0, stream>>>(bsumT, scanned, rowptr);
    scatterA_kernel<<<NEB, 256, 0, stream>>>(xnode, xneis, etype, dg,
                                             rowptr, offg, rank0, buc, bcnt);
    drain_kernel<<<2048, 256, 0, stream>>>(buc, bcnt, pmeta);
    // amat + fused step 1: writes int4 A and int4 H1 in one pass
    amat_kernel<<<(V + 3) / 4, 256, 0, stream>>>(pmeta, rowptr, P8, Qb, Wxi, bxi,
                                                 Hq0, Bsum, A4, HqA);

    // steps 2..4 (quad-per-node, int4, 4x-unrolled)
    const uint2* Hcur = HqA;
    uint2* bufs[2] = {HqB, HqA};
    for (int t = 0; t < 3; ++t) {
        uint2* Hn = bufs[t & 1];
        float* lg  = (t == 2) ? logits : nullptr;
        float* hf  = (t == 2) ? Hfp : nullptr;
        step_kernel<<<(V + 63) / 64, 256, 0, stream>>>(Hcur, Hn, pmeta, rowptr,
                                                       A4, Bsum, W1, b1, lg, hf);
        Hcur = Hn;
    }

    sum_kernel<<<64, 256, 0, stream>>>(Hfp, logits, spart);
    final_kernel<<<1, 64, 0, stream>>>(spart, (float*)d_out);
}